// Round 2
// baseline (1101.860 us; speedup 1.0000x reference)
//
#include <hip/hip_runtime.h>
#include <hip/hip_bf16.h>

#define N_NODES  50000
#define N_EDGES  50000
#define N_INC    400000
#define N_GRAPHS 1024

typedef __bf16 bf16x8 __attribute__((ext_vector_type(8)));
typedef float  f32x4  __attribute__((ext_vector_type(4)));

__device__ __forceinline__ unsigned short f2bf(float f) {
    __hip_bfloat16 h = __float2bfloat16(f);
    return __builtin_bit_cast(unsigned short, h);
}

// ---------------- int64-vs-int32 index detection ----------------
// If indices arrived as int64 (lo,hi) pairs, all "odd" 32-bit words of the
// first N_INC logical elements are zero (values < 2^31). For genuine int32
// data those words are real indices (nonzero almost surely).
__global__ void detect_kernel(const int* __restrict__ hei, int* __restrict__ flag) {
    int i = blockIdx.x * blockDim.x + threadIdx.x;
    if (i < N_INC && hei[2 * i + 1] != 0) flag[0] = 1;   // 1 => int32 layout
}

__global__ void norm_kernel(const int* __restrict__ hei, const int* __restrict__ braw,
                            const int* __restrict__ flag,
                            int* __restrict__ nidx, int* __restrict__ eidx,
                            int* __restrict__ bidx) {
    int i = blockIdx.x * blockDim.x + threadIdx.x;
    int is32 = flag[0];
    if (i < N_INC) {
        if (is32) { nidx[i] = hei[i];         eidx[i] = hei[N_INC + i]; }
        else      { nidx[i] = hei[2 * i];     eidx[i] = hei[2 * N_INC + 2 * i]; }
    }
    if (i < N_NODES) bidx[i] = is32 ? braw[i] : braw[2 * i];
}

// ---------------- degree histograms ----------------
__global__ void hist_kernel(const int* __restrict__ nidx, const int* __restrict__ eidx,
                            const int* __restrict__ bidx,
                            int* __restrict__ ndeg, int* __restrict__ edeg, int* __restrict__ gcnt) {
    int i = blockIdx.x * blockDim.x + threadIdx.x;
    if (i < N_INC) {
        atomicAdd(&ndeg[nidx[i]], 1);
        atomicAdd(&edeg[eidx[i]], 1);
    }
    if (i < N_NODES) atomicAdd(&gcnt[bidx[i]], 1);
}

// ---------------- single-block exclusive scan (dual output) ----------------
__global__ __launch_bounds__(1024) void scan_kernel(const int* __restrict__ in, int n,
                                                    int* __restrict__ out, int* __restrict__ out2) {
    __shared__ int sums[1024];
    int t = threadIdx.x;
    int c = (n + 1023) >> 10;
    int lo = t * c;
    int hi = min(lo + c, n);
    int s = 0;
    for (int i = lo; i < hi; ++i) s += in[i];
    sums[t] = s;
    __syncthreads();
    for (int off = 1; off < 1024; off <<= 1) {
        int u = (t >= off) ? sums[t - off] : 0;
        __syncthreads();
        sums[t] += u;
        __syncthreads();
    }
    int run = sums[t] - s;
    for (int i = lo; i < hi; ++i) {
        int v = in[i];
        out[i]  = run;
        out2[i] = run;
        run += v;
    }
}

// ---------------- CSR build via atomic cursors ----------------
__global__ void csr_kernel(const int* __restrict__ nidx, const int* __restrict__ eidx,
                           int* __restrict__ ecur, int* __restrict__ ncur,
                           int* __restrict__ csr_e_src, int* __restrict__ csr_n_src) {
    int i = blockIdx.x * blockDim.x + threadIdx.x;
    if (i >= N_INC) return;
    int n = nidx[i], e = eidx[i];
    int p = atomicAdd(&ecur[e], 1);
    csr_e_src[p] = n;
    int q = atomicAdd(&ncur[n], 1);
    csr_n_src[q] = e;
}

// ---------------- f32 -> bf16 plane conversion ----------------
__global__ void convert_kernel(const float* __restrict__ in, unsigned short* __restrict__ out, int n4) {
    int i = blockIdx.x * blockDim.x + threadIdx.x;
    if (i >= n4) return;
    float4 v = *(const float4*)(in + 4 * (size_t)i);
    ushort4 o;
    o.x = f2bf(v.x); o.y = f2bf(v.y); o.z = f2bf(v.z); o.w = f2bf(v.w);
    *(ushort4*)(out + 4 * (size_t)i) = o;
}

// ---------------- W[K][N] f32 -> Wt[N][K] bf16 ----------------
__global__ void wt_kernel(const float* __restrict__ W, unsigned short* __restrict__ Wt, int K, int N) {
    int i = blockIdx.x * blockDim.x + threadIdx.x;
    if (i >= K * N) return;
    int k = i / N, n = i - k * N;
    Wt[(size_t)n * K + k] = f2bf(W[i]);
}

// ---------------- bf16 MFMA GEMM: C(f32)[M][N] = A[M][K] @ W, W as Bt[N][K] ------
__global__ __launch_bounds__(256) void gemm_kernel(const unsigned short* __restrict__ A,
                                                   const unsigned short* __restrict__ Bt,
                                                   float* __restrict__ C,
                                                   int M, int K, int N) {
    __shared__ unsigned short As[64][40];
    __shared__ unsigned short Bs[64][40];
    int tid  = threadIdx.x;
    int wave = tid >> 6, lane = tid & 63;
    int n0 = blockIdx.x * 64, m0 = blockIdx.y * 64;
    int quad = lane >> 4, fr = lane & 15;
    f32x4 acc[4];
#pragma unroll
    for (int c = 0; c < 4; ++c) acc[c] = (f32x4){0.f, 0.f, 0.f, 0.f};
    int lrow   = tid >> 2;
    int lchunk = (tid & 3) * 8;
    for (int k0 = 0; k0 < K; k0 += 32) {
        uint4 av = make_uint4(0u, 0u, 0u, 0u);
        int gm = m0 + lrow;
        if (gm < M) av = *(const uint4*)(A + (size_t)gm * K + k0 + lchunk);
        *(uint4*)&As[lrow][lchunk] = av;
        uint4 bv = *(const uint4*)(Bt + (size_t)(n0 + lrow) * K + k0 + lchunk);
        *(uint4*)&Bs[lrow][lchunk] = bv;
        __syncthreads();
        bf16x8 af = *(const bf16x8*)&As[wave * 16 + fr][quad * 8];
#pragma unroll
        for (int c = 0; c < 4; ++c) {
            bf16x8 bfr = *(const bf16x8*)&Bs[c * 16 + fr][quad * 8];
            acc[c] = __builtin_amdgcn_mfma_f32_16x16x32_bf16(af, bfr, acc[c], 0, 0, 0);
        }
        __syncthreads();
    }
    // C/D layout: col = lane&15, row = quad*4 + reg
#pragma unroll
    for (int c = 0; c < 4; ++c)
#pragma unroll
        for (int r = 0; r < 4; ++r) {
            int gm = m0 + wave * 16 + quad * 4 + r;
            if (gm < M) C[(size_t)gm * N + n0 + c * 16 + fr] = acc[c][r];
        }
}

// ---------------- node->edge: ef[e] = mean over members of xl ----------------
__global__ __launch_bounds__(256) void seg_edge_kernel(const float* __restrict__ xl,
                                                       const int* __restrict__ eoff,
                                                       const int* __restrict__ edeg,
                                                       const int* __restrict__ csr_src,
                                                       float* __restrict__ ef, int C) {
    int w = (blockIdx.x * 256 + threadIdx.x) >> 6;   // one wave per hyperedge
    int lane = threadIdx.x & 63;
    if (w >= N_EDGES) return;
    int deg = edeg[w], start = eoff[w];
    float binv = (deg > 0) ? 1.0f / (float)deg : 0.0f;
    for (int f0 = 0; f0 < C; f0 += 256) {
        int f = f0 + lane * 4;
        float a0 = 0.f, a1 = 0.f, a2 = 0.f, a3 = 0.f;
        for (int j = 0; j < deg; ++j) {
            int src = csr_src[start + j];
            float4 v = *(const float4*)(xl + (size_t)src * C + f);
            a0 += v.x; a1 += v.y; a2 += v.z; a3 += v.w;
        }
        float4 o = make_float4(a0 * binv, a1 * binv, a2 * binv, a3 * binv);
        *(float4*)(ef + (size_t)w * C + f) = o;
    }
}

// ---------------- edge->node + bias + relu ----------------
__global__ __launch_bounds__(256) void seg_node_kernel(const float* __restrict__ ef,
                                                       const int* __restrict__ noff,
                                                       const int* __restrict__ ndeg,
                                                       const int* __restrict__ csr_src,
                                                       const float* __restrict__ bias,
                                                       float* __restrict__ hout, int C) {
    int w = (blockIdx.x * 256 + threadIdx.x) >> 6;   // one wave per node
    int lane = threadIdx.x & 63;
    if (w >= N_NODES) return;
    int deg = ndeg[w], start = noff[w];
    float dinv = (deg > 0) ? 1.0f / (float)deg : 0.0f;
    for (int f0 = 0; f0 < C; f0 += 256) {
        int f = f0 + lane * 4;
        float a0 = 0.f, a1 = 0.f, a2 = 0.f, a3 = 0.f;
        for (int j = 0; j < deg; ++j) {
            int e = csr_src[start + j];
            float4 v = *(const float4*)(ef + (size_t)e * C + f);
            a0 += v.x; a1 += v.y; a2 += v.z; a3 += v.w;
        }
        float4 bv = *(const float4*)(bias + f);
        float4 o;
        o.x = fmaxf(a0 * dinv + bv.x, 0.f);
        o.y = fmaxf(a1 * dinv + bv.y, 0.f);
        o.z = fmaxf(a2 * dinv + bv.z, 0.f);
        o.w = fmaxf(a3 * dinv + bv.w, 0.f);
        *(float4*)(hout + (size_t)w * C + f) = o;
    }
}

// ---------------- mean pool per graph (batch sorted) ----------------
__global__ __launch_bounds__(256) void pool_kernel(const float* __restrict__ h,
                                                   const int* __restrict__ goff,
                                                   const int* __restrict__ gcnt,
                                                   float* __restrict__ pool) {
    int g = blockIdx.x, t = threadIdx.x;
    int s = goff[g], cnt = gcnt[g];
    float acc = 0.f;
    for (int i = 0; i < cnt; ++i) acc += h[(size_t)(s + i) * 256 + t];
    pool[g * 256 + t] = acc / (float)(cnt > 0 ? cnt : 1);
}

// ---------------- head: relu(g@Wl1+bl1)@Wl2 + bl2 (all f32) ----------------
__global__ __launch_bounds__(128) void head_kernel(const float* __restrict__ pool,
                                                   const float* __restrict__ Wl1,
                                                   const float* __restrict__ bl1,
                                                   const float* __restrict__ Wl2,
                                                   const float* __restrict__ bl2,
                                                   float* __restrict__ out) {
    __shared__ float xs[256];
    __shared__ float red[128];
    int g = blockIdx.x, j = threadIdx.x;
    xs[j]       = pool[g * 256 + j];
    xs[j + 128] = pool[g * 256 + 128 + j];
    __syncthreads();
    float s = 0.f;
    for (int f = 0; f < 256; ++f) s += xs[f] * Wl1[f * 128 + j];
    s += bl1[j];
    s = fmaxf(s, 0.f);
    red[j] = s * Wl2[j];
    __syncthreads();
    for (int off = 64; off > 0; off >>= 1) {
        if (j < off) red[j] += red[j + off];
        __syncthreads();
    }
    if (j == 0) out[g] = red[0] + bl2[0];
}

extern "C" void kernel_launch(void* const* d_in, const int* in_sizes, int n_in,
                              void* d_out, int out_size, void* d_ws, size_t ws_size,
                              hipStream_t stream) {
    const float* x     = (const float*)d_in[0];
    const int* hei     = (const int*)d_in[1];
    const int* braw    = (const int*)d_in[2];
    const float* W1    = (const float*)d_in[3];
    const float* b1    = (const float*)d_in[4];
    const float* W2    = (const float*)d_in[5];
    const float* b2    = (const float*)d_in[6];
    const float* W3    = (const float*)d_in[7];
    const float* b3    = (const float*)d_in[8];
    const float* Wl1   = (const float*)d_in[9];
    const float* bl1   = (const float*)d_in[10];
    const float* Wl2   = (const float*)d_in[11];
    const float* bl2   = (const float*)d_in[12];
    float* out         = (float*)d_out;

    char* w = (char*)d_ws;
    size_t off = 0;
    auto alloc = [&](size_t bytes) { size_t p = off; off += (bytes + 255) & ~(size_t)255; return p; };
    size_t o_flag = alloc(4);
    size_t o_ndeg = alloc((size_t)N_NODES * 4);
    size_t o_edeg = alloc((size_t)N_EDGES * 4);
    size_t o_gcnt = alloc((size_t)N_GRAPHS * 4);
    size_t zero_end = off;
    size_t o_noff = alloc((size_t)N_NODES * 4);
    size_t o_eoff = alloc((size_t)N_EDGES * 4);
    size_t o_goff = alloc((size_t)N_GRAPHS * 4);
    size_t o_ncur = alloc((size_t)N_NODES * 4);
    size_t o_ecur = alloc((size_t)N_EDGES * 4);
    size_t o_nidx = alloc((size_t)N_INC * 4);
    size_t o_eidx = alloc((size_t)N_INC * 4);
    size_t o_bidx = alloc((size_t)N_NODES * 4);
    size_t o_csre = alloc((size_t)N_INC * 4);
    size_t o_csrn = alloc((size_t)N_INC * 4);
    size_t o_pool = alloc((size_t)N_GRAPHS * 256 * 4);
    size_t o_wt   = alloc((size_t)512 * 512 * 2);
    size_t o_pln  = alloc((size_t)N_NODES * 512 * 2);   // bf16 A-plane (max K=512)
    size_t o_buf1 = alloc((size_t)N_NODES * 512 * 4);   // f32: XL / H (aliased in time)
    size_t o_ef   = alloc((size_t)N_NODES * 512 * 4);   // f32 edge features

    int* flag = (int*)(w + o_flag);
    int* ndeg = (int*)(w + o_ndeg);
    int* edeg = (int*)(w + o_edeg);
    int* gcnt = (int*)(w + o_gcnt);
    int* noff = (int*)(w + o_noff);
    int* eoff = (int*)(w + o_eoff);
    int* goff = (int*)(w + o_goff);
    int* ncur = (int*)(w + o_ncur);
    int* ecur = (int*)(w + o_ecur);
    int* nidx = (int*)(w + o_nidx);
    int* eidx = (int*)(w + o_eidx);
    int* bidx = (int*)(w + o_bidx);
    int* csre = (int*)(w + o_csre);
    int* csrn = (int*)(w + o_csrn);
    float* pool = (float*)(w + o_pool);
    unsigned short* wt  = (unsigned short*)(w + o_wt);
    unsigned short* pln = (unsigned short*)(w + o_pln);
    float* buf1 = (float*)(w + o_buf1);
    float* ef   = (float*)(w + o_ef);

    hipMemsetAsync(w, 0, zero_end, stream);
    detect_kernel<<<(N_INC + 255) / 256, 256, 0, stream>>>(hei, flag);
    norm_kernel<<<(N_INC + 255) / 256, 256, 0, stream>>>(hei, braw, flag, nidx, eidx, bidx);
    hist_kernel<<<(N_INC + 255) / 256, 256, 0, stream>>>(nidx, eidx, bidx, ndeg, edeg, gcnt);
    scan_kernel<<<1, 1024, 0, stream>>>(edeg, N_EDGES, eoff, ecur);
    scan_kernel<<<1, 1024, 0, stream>>>(ndeg, N_NODES, noff, ncur);
    scan_kernel<<<1, 1024, 0, stream>>>(gcnt, N_GRAPHS, goff, goff);
    csr_kernel<<<(N_INC + 255) / 256, 256, 0, stream>>>(nidx, eidx, ecur, ncur, csre, csrn);

    auto layer = [&](const float* hin, const float* Wmat, const float* bias, int K, int C) {
        int n4 = (N_NODES * K) / 4;
        convert_kernel<<<(n4 + 255) / 256, 256, 0, stream>>>(hin, pln, n4);
        wt_kernel<<<(K * C + 255) / 256, 256, 0, stream>>>(Wmat, wt, K, C);
        dim3 grid(C / 64, (N_NODES + 63) / 64);
        gemm_kernel<<<grid, 256, 0, stream>>>(pln, wt, buf1, N_NODES, K, C);
        seg_edge_kernel<<<(N_EDGES * 64 + 255) / 256, 256, 0, stream>>>(buf1, eoff, edeg, csre, ef, C);
        seg_node_kernel<<<(N_NODES * 64 + 255) / 256, 256, 0, stream>>>(ef, noff, ndeg, csrn, bias, buf1, C);
    };
    layer(x,    W1, b1, 128, 256);
    layer(buf1, W2, b2, 256, 512);
    layer(buf1, W3, b3, 512, 256);

    pool_kernel<<<N_GRAPHS, 256, 0, stream>>>(buf1, goff, gcnt, pool);
    head_kernel<<<N_GRAPHS, 128, 0, stream>>>(pool, Wl1, bl1, Wl2, bl2, out);
}

// Round 3
// 876.723 us; speedup vs baseline: 1.2568x; 1.2568x over previous
//
#include <hip/hip_runtime.h>
#include <hip/hip_bf16.h>

#define N_NODES  50000
#define N_EDGES  50000
#define N_INC    400000
#define N_GRAPHS 1024

typedef __bf16 bf16x8 __attribute__((ext_vector_type(8)));
typedef float  f32x4  __attribute__((ext_vector_type(4)));

__device__ __forceinline__ unsigned short f2bf(float f) {
    __hip_bfloat16 h = __float2bfloat16(f);
    return __builtin_bit_cast(unsigned short, h);
}
__device__ __forceinline__ float bflo(unsigned int u) {   // element 0 (low half)
    return __builtin_bit_cast(float, u << 16);
}
__device__ __forceinline__ float bfhi(unsigned int u) {   // element 1 (high half)
    return __builtin_bit_cast(float, u & 0xffff0000u);
}
__device__ __forceinline__ unsigned int packbf(float a, float b) {
    return (unsigned int)f2bf(a) | ((unsigned int)f2bf(b) << 16);
}

// ---------------- int64-vs-int32 index detection ----------------
__global__ void detect_kernel(const int* __restrict__ hei, int* __restrict__ flag) {
    int i = blockIdx.x * blockDim.x + threadIdx.x;
    if (i < N_INC && hei[2 * i + 1] != 0) flag[0] = 1;   // 1 => int32 layout
}

__global__ void norm_kernel(const int* __restrict__ hei, const int* __restrict__ braw,
                            const int* __restrict__ flag,
                            int* __restrict__ nidx, int* __restrict__ eidx,
                            int* __restrict__ bidx) {
    int i = blockIdx.x * blockDim.x + threadIdx.x;
    int is32 = flag[0];
    if (i < N_INC) {
        if (is32) { nidx[i] = hei[i];     eidx[i] = hei[N_INC + i]; }
        else      { nidx[i] = hei[2 * i]; eidx[i] = hei[2 * N_INC + 2 * i]; }
    }
    if (i < N_NODES) bidx[i] = is32 ? braw[i] : braw[2 * i];
}

// ---------------- degree histograms ----------------
__global__ void hist_kernel(const int* __restrict__ nidx, const int* __restrict__ eidx,
                            const int* __restrict__ bidx,
                            int* __restrict__ ndeg, int* __restrict__ edeg, int* __restrict__ gcnt) {
    int i = blockIdx.x * blockDim.x + threadIdx.x;
    if (i < N_INC) {
        atomicAdd(&ndeg[nidx[i]], 1);
        atomicAdd(&edeg[eidx[i]], 1);
    }
    if (i < N_NODES) atomicAdd(&gcnt[bidx[i]], 1);
}

// ---------------- single-block exclusive scan (dual output) ----------------
__global__ __launch_bounds__(1024) void scan_kernel(const int* __restrict__ in, int n,
                                                    int* __restrict__ out, int* __restrict__ out2) {
    __shared__ int sums[1024];
    int t = threadIdx.x;
    int c = (n + 1023) >> 10;
    int lo = t * c;
    int hi = min(lo + c, n);
    int s = 0;
    for (int i = lo; i < hi; ++i) s += in[i];
    sums[t] = s;
    __syncthreads();
    for (int off = 1; off < 1024; off <<= 1) {
        int u = (t >= off) ? sums[t - off] : 0;
        __syncthreads();
        sums[t] += u;
        __syncthreads();
    }
    int run = sums[t] - s;
    for (int i = lo; i < hi; ++i) {
        int v = in[i];
        out[i]  = run;
        out2[i] = run;
        run += v;
    }
}

// ---------------- CSR build via atomic cursors ----------------
__global__ void csr_kernel(const int* __restrict__ nidx, const int* __restrict__ eidx,
                           int* __restrict__ ecur, int* __restrict__ ncur,
                           int* __restrict__ csr_e_src, int* __restrict__ csr_n_src) {
    int i = blockIdx.x * blockDim.x + threadIdx.x;
    if (i >= N_INC) return;
    int n = nidx[i], e = eidx[i];
    int p = atomicAdd(&ecur[e], 1);
    csr_e_src[p] = n;
    int q = atomicAdd(&ncur[n], 1);
    csr_n_src[q] = e;
}

// ---------------- f32 -> bf16 plane conversion (x only) ----------------
__global__ void convert_kernel(const float* __restrict__ in, unsigned short* __restrict__ out, int n4) {
    int i = blockIdx.x * blockDim.x + threadIdx.x;
    if (i >= n4) return;
    float4 v = *(const float4*)(in + 4 * (size_t)i);
    ushort4 o;
    o.x = f2bf(v.x); o.y = f2bf(v.y); o.z = f2bf(v.z); o.w = f2bf(v.w);
    *(ushort4*)(out + 4 * (size_t)i) = o;
}

// ---------------- W[K][N] f32 -> Wt[N][K] bf16 ----------------
__global__ void wt_kernel(const float* __restrict__ W, unsigned short* __restrict__ Wt, int K, int N) {
    int i = blockIdx.x * blockDim.x + threadIdx.x;
    if (i >= K * N) return;
    int k = i / N, n = i - k * N;
    Wt[(size_t)n * K + k] = f2bf(W[i]);
}

// ---------------- bf16 MFMA GEMM: C(bf16)[M][N] = A[M][K] @ W, W as Bt[N][K] -----
__global__ __launch_bounds__(256) void gemm_kernel(const unsigned short* __restrict__ A,
                                                   const unsigned short* __restrict__ Bt,
                                                   unsigned short* __restrict__ C,
                                                   int M, int K, int N) {
    __shared__ unsigned short As[64][40];
    __shared__ unsigned short Bs[64][40];
    int tid  = threadIdx.x;
    int wave = tid >> 6, lane = tid & 63;
    int n0 = blockIdx.x * 64, m0 = blockIdx.y * 64;
    int quad = lane >> 4, fr = lane & 15;
    f32x4 acc[4];
#pragma unroll
    for (int c = 0; c < 4; ++c) acc[c] = (f32x4){0.f, 0.f, 0.f, 0.f};
    int lrow   = tid >> 2;
    int lchunk = (tid & 3) * 8;
    for (int k0 = 0; k0 < K; k0 += 32) {
        uint4 av = make_uint4(0u, 0u, 0u, 0u);
        int gm = m0 + lrow;
        if (gm < M) av = *(const uint4*)(A + (size_t)gm * K + k0 + lchunk);
        *(uint4*)&As[lrow][lchunk] = av;
        uint4 bv = *(const uint4*)(Bt + (size_t)(n0 + lrow) * K + k0 + lchunk);
        *(uint4*)&Bs[lrow][lchunk] = bv;
        __syncthreads();
        bf16x8 af = *(const bf16x8*)&As[wave * 16 + fr][quad * 8];
#pragma unroll
        for (int c = 0; c < 4; ++c) {
            bf16x8 bfr = *(const bf16x8*)&Bs[c * 16 + fr][quad * 8];
            acc[c] = __builtin_amdgcn_mfma_f32_16x16x32_bf16(af, bfr, acc[c], 0, 0, 0);
        }
        __syncthreads();
    }
    // C/D layout: col = lane&15, row = quad*4 + reg
#pragma unroll
    for (int c = 0; c < 4; ++c)
#pragma unroll
        for (int r = 0; r < 4; ++r) {
            int gm = m0 + wave * 16 + quad * 4 + r;
            if (gm < M) C[(size_t)gm * N + n0 + c * 16 + fr] = f2bf(acc[c][r]);
        }
}

// ---------------- node->edge: ef[e] = mean over members (bf16 in/out, f32 acc) ----
template <int C>
__global__ __launch_bounds__(256) void seg_edge_t(const unsigned short* __restrict__ xl,
                                                  const int* __restrict__ eoff,
                                                  const int* __restrict__ edeg,
                                                  const int* __restrict__ csr_src,
                                                  unsigned short* __restrict__ ef) {
    constexpr int VEC = C / 64;        // bf16 per lane: 4 (C=256) or 8 (C=512)
    constexpr int NW  = VEC / 2;       // 32-bit words per lane
    int w = (blockIdx.x * 256 + threadIdx.x) >> 6;   // one wave per hyperedge
    int lane = threadIdx.x & 63;
    if (w >= N_EDGES) return;
    int deg = edeg[w], start = eoff[w];
    float binv = (deg > 0) ? 1.0f / (float)deg : 0.0f;
    float acc[VEC];
#pragma unroll
    for (int q = 0; q < VEC; ++q) acc[q] = 0.f;
    size_t lbase = (size_t)lane * VEC;
    for (int j = 0; j < deg; ++j) {
        int src = csr_src[start + j];
        const unsigned int* p = (const unsigned int*)(xl + (size_t)src * C + lbase);
        unsigned int v[NW];
        if constexpr (NW == 4) { uint4 t = *(const uint4*)p; v[0] = t.x; v[1] = t.y; v[2] = t.z; v[3] = t.w; }
        else                   { uint2 t = *(const uint2*)p; v[0] = t.x; v[1] = t.y; }
#pragma unroll
        for (int q = 0; q < NW; ++q) { acc[2 * q] += bflo(v[q]); acc[2 * q + 1] += bfhi(v[q]); }
    }
    unsigned int o[NW];
#pragma unroll
    for (int q = 0; q < NW; ++q) o[q] = packbf(acc[2 * q] * binv, acc[2 * q + 1] * binv);
    unsigned int* po = (unsigned int*)(ef + (size_t)w * C + lbase);
    if constexpr (NW == 4) { *(uint4*)po = make_uint4(o[0], o[1], o[2], o[3]); }
    else                   { *(uint2*)po = make_uint2(o[0], o[1]); }
}

// ---------------- edge->node + bias + relu (bf16 in/out, f32 acc) ----------------
template <int C>
__global__ __launch_bounds__(256) void seg_node_t(const unsigned short* __restrict__ ef,
                                                  const int* __restrict__ noff,
                                                  const int* __restrict__ ndeg,
                                                  const int* __restrict__ csr_src,
                                                  const float* __restrict__ bias,
                                                  unsigned short* __restrict__ hout) {
    constexpr int VEC = C / 64;
    constexpr int NW  = VEC / 2;
    int w = (blockIdx.x * 256 + threadIdx.x) >> 6;   // one wave per node
    int lane = threadIdx.x & 63;
    if (w >= N_NODES) return;
    int deg = ndeg[w], start = noff[w];
    float dinv = (deg > 0) ? 1.0f / (float)deg : 0.0f;
    float acc[VEC];
#pragma unroll
    for (int q = 0; q < VEC; ++q) acc[q] = 0.f;
    size_t lbase = (size_t)lane * VEC;
    for (int j = 0; j < deg; ++j) {
        int e = csr_src[start + j];
        const unsigned int* p = (const unsigned int*)(ef + (size_t)e * C + lbase);
        unsigned int v[NW];
        if constexpr (NW == 4) { uint4 t = *(const uint4*)p; v[0] = t.x; v[1] = t.y; v[2] = t.z; v[3] = t.w; }
        else                   { uint2 t = *(const uint2*)p; v[0] = t.x; v[1] = t.y; }
#pragma unroll
        for (int q = 0; q < NW; ++q) { acc[2 * q] += bflo(v[q]); acc[2 * q + 1] += bfhi(v[q]); }
    }
    unsigned int o[NW];
#pragma unroll
    for (int q = 0; q < NW; ++q) {
        float a = fmaxf(acc[2 * q] * dinv + bias[lbase + 2 * q], 0.f);
        float b = fmaxf(acc[2 * q + 1] * dinv + bias[lbase + 2 * q + 1], 0.f);
        o[q] = packbf(a, b);
    }
    unsigned int* po = (unsigned int*)(hout + (size_t)w * C + lbase);
    if constexpr (NW == 4) { *(uint4*)po = make_uint4(o[0], o[1], o[2], o[3]); }
    else                   { *(uint2*)po = make_uint2(o[0], o[1]); }
}

// ---------------- mean pool per graph (batch sorted, bf16 H) ----------------
__global__ __launch_bounds__(256) void pool_kernel(const unsigned short* __restrict__ h,
                                                   const int* __restrict__ goff,
                                                   const int* __restrict__ gcnt,
                                                   float* __restrict__ pool) {
    int g = blockIdx.x, t = threadIdx.x;
    int s = goff[g], cnt = gcnt[g];
    float acc = 0.f;
    for (int i = 0; i < cnt; ++i) {
        unsigned int u = h[(size_t)(s + i) * 256 + t];
        acc += __builtin_bit_cast(float, u << 16);
    }
    pool[g * 256 + t] = acc / (float)(cnt > 0 ? cnt : 1);
}

// ---------------- head: relu(g@Wl1+bl1)@Wl2 + bl2 (all f32) ----------------
__global__ __launch_bounds__(128) void head_kernel(const float* __restrict__ pool,
                                                   const float* __restrict__ Wl1,
                                                   const float* __restrict__ bl1,
                                                   const float* __restrict__ Wl2,
                                                   const float* __restrict__ bl2,
                                                   float* __restrict__ out) {
    __shared__ float xs[256];
    __shared__ float red[128];
    int g = blockIdx.x, j = threadIdx.x;
    xs[j]       = pool[g * 256 + j];
    xs[j + 128] = pool[g * 256 + 128 + j];
    __syncthreads();
    float s = 0.f;
    for (int f = 0; f < 256; ++f) s += xs[f] * Wl1[f * 128 + j];
    s += bl1[j];
    s = fmaxf(s, 0.f);
    red[j] = s * Wl2[j];
    __syncthreads();
    for (int off = 64; off > 0; off >>= 1) {
        if (j < off) red[j] += red[j + off];
        __syncthreads();
    }
    if (j == 0) out[g] = red[0] + bl2[0];
}

extern "C" void kernel_launch(void* const* d_in, const int* in_sizes, int n_in,
                              void* d_out, int out_size, void* d_ws, size_t ws_size,
                              hipStream_t stream) {
    const float* x     = (const float*)d_in[0];
    const int* hei     = (const int*)d_in[1];
    const int* braw    = (const int*)d_in[2];
    const float* W1    = (const float*)d_in[3];
    const float* b1    = (const float*)d_in[4];
    const float* W2    = (const float*)d_in[5];
    const float* b2    = (const float*)d_in[6];
    const float* W3    = (const float*)d_in[7];
    const float* b3    = (const float*)d_in[8];
    const float* Wl1   = (const float*)d_in[9];
    const float* bl1   = (const float*)d_in[10];
    const float* Wl2   = (const float*)d_in[11];
    const float* bl2   = (const float*)d_in[12];
    float* out         = (float*)d_out;

    char* w = (char*)d_ws;
    size_t off = 0;
    auto alloc = [&](size_t bytes) { size_t p = off; off += (bytes + 255) & ~(size_t)255; return p; };
    size_t o_flag = alloc(4);
    size_t o_ndeg = alloc((size_t)N_NODES * 4);
    size_t o_edeg = alloc((size_t)N_EDGES * 4);
    size_t o_gcnt = alloc((size_t)N_GRAPHS * 4);
    size_t zero_end = off;
    size_t o_noff = alloc((size_t)N_NODES * 4);
    size_t o_eoff = alloc((size_t)N_EDGES * 4);
    size_t o_goff = alloc((size_t)N_GRAPHS * 4);
    size_t o_ncur = alloc((size_t)N_NODES * 4);
    size_t o_ecur = alloc((size_t)N_EDGES * 4);
    size_t o_nidx = alloc((size_t)N_INC * 4);
    size_t o_eidx = alloc((size_t)N_INC * 4);
    size_t o_bidx = alloc((size_t)N_NODES * 4);
    size_t o_csre = alloc((size_t)N_INC * 4);
    size_t o_csrn = alloc((size_t)N_INC * 4);
    size_t o_pool = alloc((size_t)N_GRAPHS * 256 * 4);
    size_t o_wt   = alloc((size_t)512 * 512 * 2);
    size_t o_xbf  = alloc((size_t)N_NODES * 128 * 2);   // x in bf16
    size_t o_bufP = alloc((size_t)N_NODES * 512 * 2);   // layer in/out H (bf16)
    size_t o_bufX = alloc((size_t)N_NODES * 512 * 2);   // XL (bf16)
    size_t o_bufE = alloc((size_t)N_EDGES * 512 * 2);   // ef (bf16)

    int* flag = (int*)(w + o_flag);
    int* ndeg = (int*)(w + o_ndeg);
    int* edeg = (int*)(w + o_edeg);
    int* gcnt = (int*)(w + o_gcnt);
    int* noff = (int*)(w + o_noff);
    int* eoff = (int*)(w + o_eoff);
    int* goff = (int*)(w + o_goff);
    int* ncur = (int*)(w + o_ncur);
    int* ecur = (int*)(w + o_ecur);
    int* nidx = (int*)(w + o_nidx);
    int* eidx = (int*)(w + o_eidx);
    int* bidx = (int*)(w + o_bidx);
    int* csre = (int*)(w + o_csre);
    int* csrn = (int*)(w + o_csrn);
    float* pool = (float*)(w + o_pool);
    unsigned short* wt   = (unsigned short*)(w + o_wt);
    unsigned short* xbf  = (unsigned short*)(w + o_xbf);
    unsigned short* bufP = (unsigned short*)(w + o_bufP);
    unsigned short* bufX = (unsigned short*)(w + o_bufX);
    unsigned short* bufE = (unsigned short*)(w + o_bufE);

    hipMemsetAsync(w, 0, zero_end, stream);
    detect_kernel<<<(N_INC + 255) / 256, 256, 0, stream>>>(hei, flag);
    norm_kernel<<<(N_INC + 255) / 256, 256, 0, stream>>>(hei, braw, flag, nidx, eidx, bidx);
    hist_kernel<<<(N_INC + 255) / 256, 256, 0, stream>>>(nidx, eidx, bidx, ndeg, edeg, gcnt);
    scan_kernel<<<1, 1024, 0, stream>>>(edeg, N_EDGES, eoff, ecur);
    scan_kernel<<<1, 1024, 0, stream>>>(ndeg, N_NODES, noff, ncur);
    scan_kernel<<<1, 1024, 0, stream>>>(gcnt, N_GRAPHS, goff, goff);
    csr_kernel<<<(N_INC + 255) / 256, 256, 0, stream>>>(nidx, eidx, ecur, ncur, csre, csrn);

    int n4 = (N_NODES * 128) / 4;
    convert_kernel<<<(n4 + 255) / 256, 256, 0, stream>>>(x, xbf, n4);

    int segGrid = (N_EDGES * 64 + 255) / 256;   // == node grid (N_NODES == N_EDGES)
    auto layer = [&](const unsigned short* hin, const float* Wmat, const float* bias, int K, int C) {
        wt_kernel<<<(K * C + 255) / 256, 256, 0, stream>>>(Wmat, wt, K, C);
        dim3 grid(C / 64, (N_NODES + 63) / 64);
        gemm_kernel<<<grid, 256, 0, stream>>>(hin, wt, bufX, N_NODES, K, C);
        if (C == 512) {
            seg_edge_t<512><<<segGrid, 256, 0, stream>>>(bufX, eoff, edeg, csre, bufE);
            seg_node_t<512><<<segGrid, 256, 0, stream>>>(bufE, noff, ndeg, csrn, bias, bufP);
        } else {
            seg_edge_t<256><<<segGrid, 256, 0, stream>>>(bufX, eoff, edeg, csre, bufE);
            seg_node_t<256><<<segGrid, 256, 0, stream>>>(bufE, noff, ndeg, csrn, bias, bufP);
        }
    };
    layer(xbf,  W1, b1, 128, 256);
    layer(bufP, W2, b2, 256, 512);
    layer(bufP, W3, b3, 512, 256);

    pool_kernel<<<N_GRAPHS, 256, 0, stream>>>(bufP, goff, gcnt, pool);
    head_kernel<<<N_GRAPHS, 128, 0, stream>>>(pool, Wl1, bl1, Wl2, bl2, out);
}

// Round 4
// 677.546 us; speedup vs baseline: 1.6262x; 1.2940x over previous
//
#include <hip/hip_runtime.h>
#include <hip/hip_bf16.h>

#define N_NODES  50000
#define N_EDGES  50000
#define N_INC    400000
#define N_GRAPHS 1024

typedef __bf16 bf16x8 __attribute__((ext_vector_type(8)));
typedef float  f32x4  __attribute__((ext_vector_type(4)));

__device__ __forceinline__ unsigned short f2bf(float f) {
    __hip_bfloat16 h = __float2bfloat16(f);
    return __builtin_bit_cast(unsigned short, h);
}
__device__ __forceinline__ float bflo(unsigned int u) {
    return __builtin_bit_cast(float, u << 16);
}
__device__ __forceinline__ float bfhi(unsigned int u) {
    return __builtin_bit_cast(float, u & 0xffff0000u);
}
__device__ __forceinline__ unsigned int packbf(float a, float b) {
    return (unsigned int)f2bf(a) | ((unsigned int)f2bf(b) << 16);
}

// ---------------- int64-vs-int32 index detection ----------------
__global__ void detect_kernel(const int* __restrict__ hei, int* __restrict__ flag) {
    int i = blockIdx.x * blockDim.x + threadIdx.x;
    if (i < N_INC && hei[2 * i + 1] != 0) flag[0] = 1;   // 1 => int32 layout
}

// ---------------- normalize indices + degree histograms (fused) ----------------
__global__ void normhist_kernel(const int* __restrict__ hei, const int* __restrict__ braw,
                                const int* __restrict__ flag,
                                int* __restrict__ nidx, int* __restrict__ eidx,
                                int* __restrict__ bidx,
                                int* __restrict__ ndeg, int* __restrict__ edeg,
                                int* __restrict__ gcnt) {
    int i = blockIdx.x * blockDim.x + threadIdx.x;
    int is32 = flag[0];
    if (i < N_INC) {
        int n, e;
        if (is32) { n = hei[i];     e = hei[N_INC + i]; }
        else      { n = hei[2 * i]; e = hei[2 * N_INC + 2 * i]; }
        nidx[i] = n; eidx[i] = e;
        atomicAdd(&ndeg[n], 1);
        atomicAdd(&edeg[e], 1);
    }
    if (i < N_NODES) {
        int b = is32 ? braw[i] : braw[2 * i];
        bidx[i] = b;
        atomicAdd(&gcnt[b], 1);
    }
}

// ---------------- hierarchical exclusive scan ----------------
// phase 1: per-block (1024 elems) in-block exclusive scan + block partial
__global__ __launch_bounds__(256) void scan_up(const int* __restrict__ in, int n,
                                               int* __restrict__ out, int* __restrict__ partials) {
    __shared__ int lds[256];
    int t = threadIdx.x;
    int base = blockIdx.x * 1024 + t * 4;
    int4 v = make_int4(0, 0, 0, 0);
    if (base + 3 < n)      v = *(const int4*)(in + base);
    else if (base < n) {
        v.x = in[base];
        if (base + 1 < n) v.y = in[base + 1];
        if (base + 2 < n) v.z = in[base + 2];
    }
    int s = v.x + v.y + v.z + v.w;
    lds[t] = s;
    __syncthreads();
    for (int off = 1; off < 256; off <<= 1) {
        int u = (t >= off) ? lds[t - off] : 0;
        __syncthreads();
        lds[t] += u;
        __syncthreads();
    }
    int excl = lds[t] - s;
    if (t == 255) partials[blockIdx.x] = lds[255];
    int4 o;
    o.x = excl;
    o.y = excl + v.x;
    o.z = o.y + v.y;
    o.w = o.z + v.z;
    if (base + 3 < n) *(int4*)(out + base) = o;
    else if (base < n) {
        out[base] = o.x;
        if (base + 1 < n) out[base + 1] = o.y;
        if (base + 2 < n) out[base + 2] = o.z;
    }
}

// phase 2: scan the (<=256) block partials in one block
__global__ __launch_bounds__(256) void scan_mid(int* __restrict__ partials, int nparts) {
    __shared__ int lds[256];
    int t = threadIdx.x;
    int s = (t < nparts) ? partials[t] : 0;
    lds[t] = s;
    __syncthreads();
    for (int off = 1; off < 256; off <<= 1) {
        int u = (t >= off) ? lds[t - off] : 0;
        __syncthreads();
        lds[t] += u;
        __syncthreads();
    }
    if (t < nparts) partials[t] = lds[t] - s;   // exclusive block prefix
}

// phase 3: add block prefix, emit offsets + cursor copy
__global__ __launch_bounds__(256) void scan_down(int* __restrict__ out, int n,
                                                 const int* __restrict__ partials,
                                                 int* __restrict__ out2) {
    int t = threadIdx.x;
    int base = blockIdx.x * 1024 + t * 4;
    int p = partials[blockIdx.x];
    if (base + 3 < n) {
        int4 v = *(const int4*)(out + base);
        v.x += p; v.y += p; v.z += p; v.w += p;
        *(int4*)(out + base) = v;
        *(int4*)(out2 + base) = v;
    } else if (base < n) {
        for (int k = 0; k < 4 && base + k < n; ++k) {
            int v = out[base + k] + p;
            out[base + k] = v;
            out2[base + k] = v;
        }
    }
}

// ---------------- CSR build via atomic cursors ----------------
__global__ void csr_kernel(const int* __restrict__ nidx, const int* __restrict__ eidx,
                           int* __restrict__ ecur, int* __restrict__ ncur,
                           int* __restrict__ csr_e_src, int* __restrict__ csr_n_src) {
    int i = blockIdx.x * blockDim.x + threadIdx.x;
    if (i >= N_INC) return;
    int n = nidx[i], e = eidx[i];
    int p = atomicAdd(&ecur[e], 1);
    csr_e_src[p] = n;
    int q = atomicAdd(&ncur[n], 1);
    csr_n_src[q] = e;
}

// ---------------- f32 -> bf16 plane conversion (x only) ----------------
__global__ void convert_kernel(const float* __restrict__ in, unsigned short* __restrict__ out, int n4) {
    int i = blockIdx.x * blockDim.x + threadIdx.x;
    if (i >= n4) return;
    float4 v = *(const float4*)(in + 4 * (size_t)i);
    ushort4 o;
    o.x = f2bf(v.x); o.y = f2bf(v.y); o.z = f2bf(v.z); o.w = f2bf(v.w);
    *(ushort4*)(out + 4 * (size_t)i) = o;
}

// ---------------- W[K][N] f32 -> Wt[N][K] bf16 ----------------
__global__ void wt_kernel(const float* __restrict__ W, unsigned short* __restrict__ Wt, int K, int N) {
    int i = blockIdx.x * blockDim.x + threadIdx.x;
    if (i >= K * N) return;
    int k = i / N, n = i - k * N;
    Wt[(size_t)n * K + k] = f2bf(W[i]);
}

// ---------------- bf16 MFMA GEMM: C(bf16)[M][N] = A[M][K] @ W, W as Bt[N][K] -----
__global__ __launch_bounds__(256) void gemm_kernel(const unsigned short* __restrict__ A,
                                                   const unsigned short* __restrict__ Bt,
                                                   unsigned short* __restrict__ C,
                                                   int M, int K, int N) {
    __shared__ unsigned short As[64][40];
    __shared__ unsigned short Bs[64][40];
    int tid  = threadIdx.x;
    int wave = tid >> 6, lane = tid & 63;
    int n0 = blockIdx.x * 64, m0 = blockIdx.y * 64;
    int quad = lane >> 4, fr = lane & 15;
    f32x4 acc[4];
#pragma unroll
    for (int c = 0; c < 4; ++c) acc[c] = (f32x4){0.f, 0.f, 0.f, 0.f};
    int lrow   = tid >> 2;
    int lchunk = (tid & 3) * 8;
    for (int k0 = 0; k0 < K; k0 += 32) {
        uint4 av = make_uint4(0u, 0u, 0u, 0u);
        int gm = m0 + lrow;
        if (gm < M) av = *(const uint4*)(A + (size_t)gm * K + k0 + lchunk);
        *(uint4*)&As[lrow][lchunk] = av;
        uint4 bv = *(const uint4*)(Bt + (size_t)(n0 + lrow) * K + k0 + lchunk);
        *(uint4*)&Bs[lrow][lchunk] = bv;
        __syncthreads();
        bf16x8 af = *(const bf16x8*)&As[wave * 16 + fr][quad * 8];
#pragma unroll
        for (int c = 0; c < 4; ++c) {
            bf16x8 bfr = *(const bf16x8*)&Bs[c * 16 + fr][quad * 8];
            acc[c] = __builtin_amdgcn_mfma_f32_16x16x32_bf16(af, bfr, acc[c], 0, 0, 0);
        }
        __syncthreads();
    }
    // C/D layout: col = lane&15, row = quad*4 + reg
#pragma unroll
    for (int c = 0; c < 4; ++c)
#pragma unroll
        for (int r = 0; r < 4; ++r) {
            int gm = m0 + wave * 16 + quad * 4 + r;
            if (gm < M) C[(size_t)gm * N + n0 + c * 16 + fr] = f2bf(acc[c][r]);
        }
}

// ---------------- node->edge: ef[e] = mean over members (bf16 in/out, f32 acc) ----
template <int C>
__global__ __launch_bounds__(256) void seg_edge_t(const unsigned short* __restrict__ xl,
                                                  const int* __restrict__ eoff,
                                                  const int* __restrict__ edeg,
                                                  const int* __restrict__ csr_src,
                                                  unsigned short* __restrict__ ef) {
    constexpr int VEC = C / 64;
    constexpr int NW  = VEC / 2;
    int w = (blockIdx.x * 256 + threadIdx.x) >> 6;
    int lane = threadIdx.x & 63;
    if (w >= N_EDGES) return;
    int deg = edeg[w], start = eoff[w];
    float binv = (deg > 0) ? 1.0f / (float)deg : 0.0f;
    float acc[VEC];
#pragma unroll
    for (int q = 0; q < VEC; ++q) acc[q] = 0.f;
    size_t lbase = (size_t)lane * VEC;
    for (int j = 0; j < deg; ++j) {
        int src = csr_src[start + j];
        const unsigned int* p = (const unsigned int*)(xl + (size_t)src * C + lbase);
        unsigned int v[NW];
        if constexpr (NW == 4) { uint4 t = *(const uint4*)p; v[0] = t.x; v[1] = t.y; v[2] = t.z; v[3] = t.w; }
        else                   { uint2 t = *(const uint2*)p; v[0] = t.x; v[1] = t.y; }
#pragma unroll
        for (int q = 0; q < NW; ++q) { acc[2 * q] += bflo(v[q]); acc[2 * q + 1] += bfhi(v[q]); }
    }
    unsigned int o[NW];
#pragma unroll
    for (int q = 0; q < NW; ++q) o[q] = packbf(acc[2 * q] * binv, acc[2 * q + 1] * binv);
    unsigned int* po = (unsigned int*)(ef + (size_t)w * C + lbase);
    if constexpr (NW == 4) { *(uint4*)po = make_uint4(o[0], o[1], o[2], o[3]); }
    else                   { *(uint2*)po = make_uint2(o[0], o[1]); }
}

// ---------------- edge->node + bias + relu (bf16 in/out, f32 acc) ----------------
template <int C>
__global__ __launch_bounds__(256) void seg_node_t(const unsigned short* __restrict__ ef,
                                                  const int* __restrict__ noff,
                                                  const int* __restrict__ ndeg,
                                                  const int* __restrict__ csr_src,
                                                  const float* __restrict__ bias,
                                                  unsigned short* __restrict__ hout) {
    constexpr int VEC = C / 64;
    constexpr int NW  = VEC / 2;
    int w = (blockIdx.x * 256 + threadIdx.x) >> 6;
    int lane = threadIdx.x & 63;
    if (w >= N_NODES) return;
    int deg = ndeg[w], start = noff[w];
    float dinv = (deg > 0) ? 1.0f / (float)deg : 0.0f;
    float acc[VEC];
#pragma unroll
    for (int q = 0; q < VEC; ++q) acc[q] = 0.f;
    size_t lbase = (size_t)lane * VEC;
    for (int j = 0; j < deg; ++j) {
        int e = csr_src[start + j];
        const unsigned int* p = (const unsigned int*)(ef + (size_t)e * C + lbase);
        unsigned int v[NW];
        if constexpr (NW == 4) { uint4 t = *(const uint4*)p; v[0] = t.x; v[1] = t.y; v[2] = t.z; v[3] = t.w; }
        else                   { uint2 t = *(const uint2*)p; v[0] = t.x; v[1] = t.y; }
#pragma unroll
        for (int q = 0; q < NW; ++q) { acc[2 * q] += bflo(v[q]); acc[2 * q + 1] += bfhi(v[q]); }
    }
    unsigned int o[NW];
#pragma unroll
    for (int q = 0; q < NW; ++q) {
        float a = fmaxf(acc[2 * q] * dinv + bias[lbase + 2 * q], 0.f);
        float b = fmaxf(acc[2 * q + 1] * dinv + bias[lbase + 2 * q + 1], 0.f);
        o[q] = packbf(a, b);
    }
    unsigned int* po = (unsigned int*)(hout + (size_t)w * C + lbase);
    if constexpr (NW == 4) { *(uint4*)po = make_uint4(o[0], o[1], o[2], o[3]); }
    else                   { *(uint2*)po = make_uint2(o[0], o[1]); }
}

// ---------------- mean pool per graph (batch sorted, bf16 H) ----------------
__global__ __launch_bounds__(256) void pool_kernel(const unsigned short* __restrict__ h,
                                                   const int* __restrict__ goff,
                                                   const int* __restrict__ gcnt,
                                                   float* __restrict__ pool) {
    int g = blockIdx.x, t = threadIdx.x;
    int s = goff[g], cnt = gcnt[g];
    float acc = 0.f;
    for (int i = 0; i < cnt; ++i) {
        unsigned int u = h[(size_t)(s + i) * 256 + t];
        acc += __builtin_bit_cast(float, u << 16);
    }
    pool[g * 256 + t] = acc / (float)(cnt > 0 ? cnt : 1);
}

// ---------------- head: relu(g@Wl1+bl1)@Wl2 + bl2 (all f32) ----------------
__global__ __launch_bounds__(128) void head_kernel(const float* __restrict__ pool,
                                                   const float* __restrict__ Wl1,
                                                   const float* __restrict__ bl1,
                                                   const float* __restrict__ Wl2,
                                                   const float* __restrict__ bl2,
                                                   float* __restrict__ out) {
    __shared__ float xs[256];
    __shared__ float red[128];
    int g = blockIdx.x, j = threadIdx.x;
    xs[j]       = pool[g * 256 + j];
    xs[j + 128] = pool[g * 256 + 128 + j];
    __syncthreads();
    float s = 0.f;
    for (int f = 0; f < 256; ++f) s += xs[f] * Wl1[f * 128 + j];
    s += bl1[j];
    s = fmaxf(s, 0.f);
    red[j] = s * Wl2[j];
    __syncthreads();
    for (int off = 64; off > 0; off >>= 1) {
        if (j < off) red[j] += red[j + off];
        __syncthreads();
    }
    if (j == 0) out[g] = red[0] + bl2[0];
}

extern "C" void kernel_launch(void* const* d_in, const int* in_sizes, int n_in,
                              void* d_out, int out_size, void* d_ws, size_t ws_size,
                              hipStream_t stream) {
    const float* x     = (const float*)d_in[0];
    const int* hei     = (const int*)d_in[1];
    const int* braw    = (const int*)d_in[2];
    const float* W1    = (const float*)d_in[3];
    const float* b1    = (const float*)d_in[4];
    const float* W2    = (const float*)d_in[5];
    const float* b2    = (const float*)d_in[6];
    const float* W3    = (const float*)d_in[7];
    const float* b3    = (const float*)d_in[8];
    const float* Wl1   = (const float*)d_in[9];
    const float* bl1   = (const float*)d_in[10];
    const float* Wl2   = (const float*)d_in[11];
    const float* bl2   = (const float*)d_in[12];
    float* out         = (float*)d_out;

    char* w = (char*)d_ws;
    size_t off = 0;
    auto alloc = [&](size_t bytes) { size_t p = off; off += (bytes + 255) & ~(size_t)255; return p; };
    size_t o_flag = alloc(4);
    size_t o_ndeg = alloc((size_t)N_NODES * 4);
    size_t o_edeg = alloc((size_t)N_EDGES * 4);
    size_t o_gcnt = alloc((size_t)N_GRAPHS * 4);
    size_t zero_end = off;
    size_t o_noff = alloc((size_t)N_NODES * 4);
    size_t o_eoff = alloc((size_t)N_EDGES * 4);
    size_t o_goff = alloc((size_t)N_GRAPHS * 4);
    size_t o_ncur = alloc((size_t)N_NODES * 4);
    size_t o_ecur = alloc((size_t)N_EDGES * 4);
    size_t o_part = alloc(256 * 4);
    size_t o_nidx = alloc((size_t)N_INC * 4);
    size_t o_eidx = alloc((size_t)N_INC * 4);
    size_t o_bidx = alloc((size_t)N_NODES * 4);
    size_t o_csre = alloc((size_t)N_INC * 4);
    size_t o_csrn = alloc((size_t)N_INC * 4);
    size_t o_pool = alloc((size_t)N_GRAPHS * 256 * 4);
    size_t o_wt   = alloc((size_t)512 * 512 * 2);
    size_t o_xbf  = alloc((size_t)N_NODES * 128 * 2);
    size_t o_bufP = alloc((size_t)N_NODES * 512 * 2);
    size_t o_bufX = alloc((size_t)N_NODES * 512 * 2);
    size_t o_bufE = alloc((size_t)N_EDGES * 512 * 2);

    int* flag = (int*)(w + o_flag);
    int* ndeg = (int*)(w + o_ndeg);
    int* edeg = (int*)(w + o_edeg);
    int* gcnt = (int*)(w + o_gcnt);
    int* noff = (int*)(w + o_noff);
    int* eoff = (int*)(w + o_eoff);
    int* goff = (int*)(w + o_goff);
    int* ncur = (int*)(w + o_ncur);
    int* ecur = (int*)(w + o_ecur);
    int* part = (int*)(w + o_part);
    int* nidx = (int*)(w + o_nidx);
    int* eidx = (int*)(w + o_eidx);
    int* bidx = (int*)(w + o_bidx);
    int* csre = (int*)(w + o_csre);
    int* csrn = (int*)(w + o_csrn);
    float* pool = (float*)(w + o_pool);
    unsigned short* wt   = (unsigned short*)(w + o_wt);
    unsigned short* xbf  = (unsigned short*)(w + o_xbf);
    unsigned short* bufP = (unsigned short*)(w + o_bufP);
    unsigned short* bufX = (unsigned short*)(w + o_bufX);
    unsigned short* bufE = (unsigned short*)(w + o_bufE);

    hipMemsetAsync(w, 0, zero_end, stream);
    detect_kernel<<<(N_INC + 255) / 256, 256, 0, stream>>>(hei, flag);
    normhist_kernel<<<(N_INC + 255) / 256, 256, 0, stream>>>(hei, braw, flag, nidx, eidx, bidx,
                                                             ndeg, edeg, gcnt);
    auto scan = [&](int* in, int n, int* outp, int* out2p) {
        int nb = (n + 1023) / 1024;
        scan_up<<<nb, 256, 0, stream>>>(in, n, outp, part);
        scan_mid<<<1, 256, 0, stream>>>(part, nb);
        scan_down<<<nb, 256, 0, stream>>>(outp, n, part, out2p);
    };
    scan(edeg, N_EDGES, eoff, ecur);
    scan(ndeg, N_NODES, noff, ncur);
    scan(gcnt, N_GRAPHS, goff, goff);
    csr_kernel<<<(N_INC + 255) / 256, 256, 0, stream>>>(nidx, eidx, ecur, ncur, csre, csrn);

    int n4 = (N_NODES * 128) / 4;
    convert_kernel<<<(n4 + 255) / 256, 256, 0, stream>>>(x, xbf, n4);

    int segGrid = (N_EDGES * 64 + 255) / 256;
    auto layer = [&](const unsigned short* hin, const float* Wmat, const float* bias, int K, int C) {
        wt_kernel<<<(K * C + 255) / 256, 256, 0, stream>>>(Wmat, wt, K, C);
        dim3 grid(C / 64, (N_NODES + 63) / 64);
        gemm_kernel<<<grid, 256, 0, stream>>>(hin, wt, bufX, N_NODES, K, C);
        if (C == 512) {
            seg_edge_t<512><<<segGrid, 256, 0, stream>>>(bufX, eoff, edeg, csre, bufE);
            seg_node_t<512><<<segGrid, 256, 0, stream>>>(bufE, noff, ndeg, csrn, bias, bufP);
        } else {
            seg_edge_t<256><<<segGrid, 256, 0, stream>>>(bufX, eoff, edeg, csre, bufE);
            seg_node_t<256><<<segGrid, 256, 0, stream>>>(bufE, noff, ndeg, csrn, bias, bufP);
        }
    };
    layer(xbf,  W1, b1, 128, 256);
    layer(bufP, W2, b2, 256, 512);
    layer(bufP, W3, b3, 512, 256);

    pool_kernel<<<N_GRAPHS, 256, 0, stream>>>(bufP, goff, gcnt, pool);
    head_kernel<<<N_GRAPHS, 128, 0, stream>>>(pool, Wl1, bl1, Wl2, bl2, out);
}

// Round 5
// 648.055 us; speedup vs baseline: 1.7003x; 1.0455x over previous
//
#include <hip/hip_runtime.h>
#include <hip/hip_bf16.h>

#define N_NODES  50000
#define N_EDGES  50000
#define N_INC    400000
#define N_GRAPHS 1024
#define M_PAD    50048          // 391 * 128

typedef __bf16 bf16x8 __attribute__((ext_vector_type(8)));
typedef float  f32x4  __attribute__((ext_vector_type(4)));

__device__ __forceinline__ unsigned short f2bf(float f) {
    __hip_bfloat16 h = __float2bfloat16(f);
    return __builtin_bit_cast(unsigned short, h);
}
__device__ __forceinline__ float bflo(unsigned int u) {
    return __builtin_bit_cast(float, u << 16);
}
__device__ __forceinline__ float bfhi(unsigned int u) {
    return __builtin_bit_cast(float, u & 0xffff0000u);
}
__device__ __forceinline__ unsigned int packbf(float a, float b) {
    return (unsigned int)f2bf(a) | ((unsigned int)f2bf(b) << 16);
}
__device__ __forceinline__ void load_lds16(const unsigned short* g, unsigned short* l) {
    __builtin_amdgcn_global_load_lds((const __attribute__((address_space(1))) void*)g,
                                     (__attribute__((address_space(3))) void*)l, 16, 0, 0);
}

// ---------------- int64-vs-int32 index detection ----------------
__global__ void detect_kernel(const int* __restrict__ hei, int* __restrict__ flag) {
    int i = blockIdx.x * blockDim.x + threadIdx.x;
    if (i < N_INC && hei[2 * i + 1] != 0) flag[0] = 1;   // 1 => int32 layout
}

// ---------------- normalize indices + degree histograms (fused) ----------------
__global__ void normhist_kernel(const int* __restrict__ hei, const int* __restrict__ braw,
                                const int* __restrict__ flag,
                                int* __restrict__ nidx, int* __restrict__ eidx,
                                int* __restrict__ bidx,
                                int* __restrict__ ndeg, int* __restrict__ edeg,
                                int* __restrict__ gcnt) {
    int i = blockIdx.x * blockDim.x + threadIdx.x;
    int is32 = flag[0];
    if (i < N_INC) {
        int n, e;
        if (is32) { n = hei[i];     e = hei[N_INC + i]; }
        else      { n = hei[2 * i]; e = hei[2 * N_INC + 2 * i]; }
        nidx[i] = n; eidx[i] = e;
        atomicAdd(&ndeg[n], 1);
        atomicAdd(&edeg[e], 1);
    }
    if (i < N_NODES) {
        int b = is32 ? braw[i] : braw[2 * i];
        bidx[i] = b;
        atomicAdd(&gcnt[b], 1);
    }
}

// ---------------- hierarchical exclusive scan ----------------
__global__ __launch_bounds__(256) void scan_up(const int* __restrict__ in, int n,
                                               int* __restrict__ out, int* __restrict__ partials) {
    __shared__ int lds[256];
    int t = threadIdx.x;
    int base = blockIdx.x * 1024 + t * 4;
    int4 v = make_int4(0, 0, 0, 0);
    if (base + 3 < n)      v = *(const int4*)(in + base);
    else if (base < n) {
        v.x = in[base];
        if (base + 1 < n) v.y = in[base + 1];
        if (base + 2 < n) v.z = in[base + 2];
    }
    int s = v.x + v.y + v.z + v.w;
    lds[t] = s;
    __syncthreads();
    for (int off = 1; off < 256; off <<= 1) {
        int u = (t >= off) ? lds[t - off] : 0;
        __syncthreads();
        lds[t] += u;
        __syncthreads();
    }
    int excl = lds[t] - s;
    if (t == 255) partials[blockIdx.x] = lds[255];
    int4 o;
    o.x = excl;
    o.y = excl + v.x;
    o.z = o.y + v.y;
    o.w = o.z + v.z;
    if (base + 3 < n) *(int4*)(out + base) = o;
    else if (base < n) {
        out[base] = o.x;
        if (base + 1 < n) out[base + 1] = o.y;
        if (base + 2 < n) out[base + 2] = o.z;
    }
}

__global__ __launch_bounds__(256) void scan_mid(int* __restrict__ partials, int nparts) {
    __shared__ int lds[256];
    int t = threadIdx.x;
    int s = (t < nparts) ? partials[t] : 0;
    lds[t] = s;
    __syncthreads();
    for (int off = 1; off < 256; off <<= 1) {
        int u = (t >= off) ? lds[t - off] : 0;
        __syncthreads();
        lds[t] += u;
        __syncthreads();
    }
    if (t < nparts) partials[t] = lds[t] - s;
}

__global__ __launch_bounds__(256) void scan_down(int* __restrict__ out, int n,
                                                 const int* __restrict__ partials,
                                                 int* __restrict__ out2) {
    int t = threadIdx.x;
    int base = blockIdx.x * 1024 + t * 4;
    int p = partials[blockIdx.x];
    if (base + 3 < n) {
        int4 v = *(const int4*)(out + base);
        v.x += p; v.y += p; v.z += p; v.w += p;
        *(int4*)(out + base) = v;
        *(int4*)(out2 + base) = v;
    } else if (base < n) {
        for (int k = 0; k < 4 && base + k < n; ++k) {
            int v = out[base + k] + p;
            out[base + k] = v;
            out2[base + k] = v;
        }
    }
}

// ---------------- CSR build via atomic cursors ----------------
__global__ void csr_kernel(const int* __restrict__ nidx, const int* __restrict__ eidx,
                           int* __restrict__ ecur, int* __restrict__ ncur,
                           int* __restrict__ csr_e_src, int* __restrict__ csr_n_src) {
    int i = blockIdx.x * blockDim.x + threadIdx.x;
    if (i >= N_INC) return;
    int n = nidx[i], e = eidx[i];
    int p = atomicAdd(&ecur[e], 1);
    csr_e_src[p] = n;
    int q = atomicAdd(&ncur[n], 1);
    csr_n_src[q] = e;
}

// ---------------- f32 -> bf16 plane conversion (x only) ----------------
__global__ void convert_kernel(const float* __restrict__ in, unsigned short* __restrict__ out, int n4) {
    int i = blockIdx.x * blockDim.x + threadIdx.x;
    if (i >= n4) return;
    float4 v = *(const float4*)(in + 4 * (size_t)i);
    ushort4 o;
    o.x = f2bf(v.x); o.y = f2bf(v.y); o.z = f2bf(v.z); o.w = f2bf(v.w);
    *(ushort4*)(out + 4 * (size_t)i) = o;
}

// ---------------- W[K][N] f32 -> Wt[N][K] bf16 ----------------
__global__ void wt_kernel(const float* __restrict__ W, unsigned short* __restrict__ Wt, int K, int N) {
    int i = blockIdx.x * blockDim.x + threadIdx.x;
    if (i >= K * N) return;
    int k = i / N, n = i - k * N;
    Wt[(size_t)n * K + k] = f2bf(W[i]);
}

// ---------------- 128x128 MFMA GEMM (m97 pattern), optional bias+relu epilogue ----
// A[M_PAD][K] bf16 (rows >= M garbage but in-bounds), Bt[N][K] bf16, C[M][N] bf16.
template <bool EPI>
__global__ __launch_bounds__(256) void gemm128_kernel(const unsigned short* __restrict__ A,
                                                      const unsigned short* __restrict__ Bt,
                                                      const float* __restrict__ bias,
                                                      unsigned short* __restrict__ C,
                                                      int M, int K, int N) {
    __shared__ unsigned short As[128 * 32];
    __shared__ unsigned short Bs[128 * 32];
    int tid  = threadIdx.x;
    int wave = tid >> 6, lane = tid & 63;
    int n0 = blockIdx.x * 128, m0 = blockIdx.y * 128;
    int quad = lane >> 4, fr = lane & 15;
    int wr = wave >> 1, wc = wave & 1;          // wave's 64x64 quadrant
    int lrow16 = lane >> 2;                     // 0..15 staging row within group
    int lchunk = (lane & 3) * 8;                // element offset within 32-wide K slab

    const unsigned short* gsrc;
    unsigned short* ldst;
    if (wave < 2) { gsrc = A  + (size_t)(m0 + wave * 64) * K;       ldst = As + wave * 64 * 32; }
    else          { gsrc = Bt + (size_t)(n0 + (wave - 2) * 64) * K; ldst = Bs + (wave - 2) * 64 * 32; }

    f32x4 acc[4][4];
#pragma unroll
    for (int s = 0; s < 4; ++s)
#pragma unroll
        for (int c = 0; c < 4; ++c) acc[s][c] = (f32x4){0.f, 0.f, 0.f, 0.f};

    for (int k0 = 0; k0 < K; k0 += 32) {
#pragma unroll
        for (int l = 0; l < 4; ++l) {
            const unsigned short* g = gsrc + (size_t)(l * 16 + lrow16) * K + k0 + lchunk;
            load_lds16(g, ldst + l * 16 * 32);
        }
        __syncthreads();
        bf16x8 af[4], bfr[4];
#pragma unroll
        for (int s = 0; s < 4; ++s)
            af[s] = *(const bf16x8*)&As[(wr * 64 + s * 16 + fr) * 32 + quad * 8];
#pragma unroll
        for (int c = 0; c < 4; ++c)
            bfr[c] = *(const bf16x8*)&Bs[(wc * 64 + c * 16 + fr) * 32 + quad * 8];
#pragma unroll
        for (int s = 0; s < 4; ++s)
#pragma unroll
            for (int c = 0; c < 4; ++c)
                acc[s][c] = __builtin_amdgcn_mfma_f32_16x16x32_bf16(af[s], bfr[c], acc[s][c], 0, 0, 0);
        __syncthreads();
    }
    // C/D layout: col = lane&15, row = quad*4 + reg
#pragma unroll
    for (int c = 0; c < 4; ++c) {
        int gn = n0 + wc * 64 + c * 16 + fr;
        float bv = EPI ? bias[gn] : 0.f;
#pragma unroll
        for (int s = 0; s < 4; ++s)
#pragma unroll
            for (int r = 0; r < 4; ++r) {
                int gm = m0 + wr * 64 + s * 16 + quad * 4 + r;
                if (gm < M) {
                    float v = acc[s][c][r];
                    if (EPI) v = fmaxf(v + bv, 0.f);
                    C[(size_t)gm * N + gn] = f2bf(v);
                }
            }
    }
}

// ---------------- node->edge: ef[e] = mean over members (bf16 in/out, f32 acc) ----
template <int C>
__global__ __launch_bounds__(256) void seg_edge_t(const unsigned short* __restrict__ xl,
                                                  const int* __restrict__ eoff,
                                                  const int* __restrict__ edeg,
                                                  const int* __restrict__ csr_src,
                                                  unsigned short* __restrict__ ef) {
    constexpr int VEC = C / 64;
    constexpr int NW  = VEC / 2;
    int w = (blockIdx.x * 256 + threadIdx.x) >> 6;
    int lane = threadIdx.x & 63;
    if (w >= N_EDGES) return;
    int deg = edeg[w], start = eoff[w];
    float binv = (deg > 0) ? 1.0f / (float)deg : 0.0f;
    float acc[VEC];
#pragma unroll
    for (int q = 0; q < VEC; ++q) acc[q] = 0.f;
    size_t lbase = (size_t)lane * VEC;
    for (int j = 0; j < deg; ++j) {
        int src = csr_src[start + j];
        const unsigned int* p = (const unsigned int*)(xl + (size_t)src * C + lbase);
        unsigned int v[NW];
        if constexpr (NW == 4)      { uint4 t = *(const uint4*)p; v[0] = t.x; v[1] = t.y; v[2] = t.z; v[3] = t.w; }
        else if constexpr (NW == 2) { uint2 t = *(const uint2*)p; v[0] = t.x; v[1] = t.y; }
        else                        { v[0] = *p; }
#pragma unroll
        for (int q = 0; q < NW; ++q) { acc[2 * q] += bflo(v[q]); acc[2 * q + 1] += bfhi(v[q]); }
    }
    unsigned int o[NW];
#pragma unroll
    for (int q = 0; q < NW; ++q) o[q] = packbf(acc[2 * q] * binv, acc[2 * q + 1] * binv);
    unsigned int* po = (unsigned int*)(ef + (size_t)w * C + lbase);
    if constexpr (NW == 4)      { *(uint4*)po = make_uint4(o[0], o[1], o[2], o[3]); }
    else if constexpr (NW == 2) { *(uint2*)po = make_uint2(o[0], o[1]); }
    else                        { *po = o[0]; }
}

// ---------------- edge->node: mean, optional +bias+relu (bf16 in/out, f32 acc) ----
template <int C, bool BIAS>
__global__ __launch_bounds__(256) void seg_node_t(const unsigned short* __restrict__ ef,
                                                  const int* __restrict__ noff,
                                                  const int* __restrict__ ndeg,
                                                  const int* __restrict__ csr_src,
                                                  const float* __restrict__ bias,
                                                  unsigned short* __restrict__ hout) {
    constexpr int VEC = C / 64;
    constexpr int NW  = VEC / 2;
    int w = (blockIdx.x * 256 + threadIdx.x) >> 6;
    int lane = threadIdx.x & 63;
    if (w >= N_NODES) return;
    int deg = ndeg[w], start = noff[w];
    float dinv = (deg > 0) ? 1.0f / (float)deg : 0.0f;
    float acc[VEC];
#pragma unroll
    for (int q = 0; q < VEC; ++q) acc[q] = 0.f;
    size_t lbase = (size_t)lane * VEC;
    for (int j = 0; j < deg; ++j) {
        int e = csr_src[start + j];
        const unsigned int* p = (const unsigned int*)(ef + (size_t)e * C + lbase);
        unsigned int v[NW];
        if constexpr (NW == 4)      { uint4 t = *(const uint4*)p; v[0] = t.x; v[1] = t.y; v[2] = t.z; v[3] = t.w; }
        else if constexpr (NW == 2) { uint2 t = *(const uint2*)p; v[0] = t.x; v[1] = t.y; }
        else                        { v[0] = *p; }
#pragma unroll
        for (int q = 0; q < NW; ++q) { acc[2 * q] += bflo(v[q]); acc[2 * q + 1] += bfhi(v[q]); }
    }
    unsigned int o[NW];
#pragma unroll
    for (int q = 0; q < NW; ++q) {
        float a = acc[2 * q] * dinv;
        float b = acc[2 * q + 1] * dinv;
        if constexpr (BIAS) {
            a = fmaxf(a + bias[lbase + 2 * q], 0.f);
            b = fmaxf(b + bias[lbase + 2 * q + 1], 0.f);
        }
        o[q] = packbf(a, b);
    }
    unsigned int* po = (unsigned int*)(hout + (size_t)w * C + lbase);
    if constexpr (NW == 4)      { *(uint4*)po = make_uint4(o[0], o[1], o[2], o[3]); }
    else if constexpr (NW == 2) { *(uint2*)po = make_uint2(o[0], o[1]); }
    else                        { *po = o[0]; }
}

// ---------------- mean pool per graph (batch sorted, bf16 H) ----------------
__global__ __launch_bounds__(256) void pool_kernel(const unsigned short* __restrict__ h,
                                                   const int* __restrict__ goff,
                                                   const int* __restrict__ gcnt,
                                                   float* __restrict__ pool) {
    int g = blockIdx.x, t = threadIdx.x;
    int s = goff[g], cnt = gcnt[g];
    float acc = 0.f;
    for (int i = 0; i < cnt; ++i) {
        unsigned int u = h[(size_t)(s + i) * 256 + t];
        acc += __builtin_bit_cast(float, u << 16);
    }
    pool[g * 256 + t] = acc / (float)(cnt > 0 ? cnt : 1);
}

// ---------------- head: relu(g@Wl1+bl1)@Wl2 + bl2 (all f32) ----------------
__global__ __launch_bounds__(128) void head_kernel(const float* __restrict__ pool,
                                                   const float* __restrict__ Wl1,
                                                   const float* __restrict__ bl1,
                                                   const float* __restrict__ Wl2,
                                                   const float* __restrict__ bl2,
                                                   float* __restrict__ out) {
    __shared__ float xs[256];
    __shared__ float red[128];
    int g = blockIdx.x, j = threadIdx.x;
    xs[j]       = pool[g * 256 + j];
    xs[j + 128] = pool[g * 256 + 128 + j];
    __syncthreads();
    float s = 0.f;
    for (int f = 0; f < 256; ++f) s += xs[f] * Wl1[f * 128 + j];
    s += bl1[j];
    s = fmaxf(s, 0.f);
    red[j] = s * Wl2[j];
    __syncthreads();
    for (int off = 64; off > 0; off >>= 1) {
        if (j < off) red[j] += red[j + off];
        __syncthreads();
    }
    if (j == 0) out[g] = red[0] + bl2[0];
}

extern "C" void kernel_launch(void* const* d_in, const int* in_sizes, int n_in,
                              void* d_out, int out_size, void* d_ws, size_t ws_size,
                              hipStream_t stream) {
    const float* x     = (const float*)d_in[0];
    const int* hei     = (const int*)d_in[1];
    const int* braw    = (const int*)d_in[2];
    const float* W1    = (const float*)d_in[3];
    const float* b1    = (const float*)d_in[4];
    const float* W2    = (const float*)d_in[5];
    const float* b2    = (const float*)d_in[6];
    const float* W3    = (const float*)d_in[7];
    const float* b3    = (const float*)d_in[8];
    const float* Wl1   = (const float*)d_in[9];
    const float* bl1   = (const float*)d_in[10];
    const float* Wl2   = (const float*)d_in[11];
    const float* bl2   = (const float*)d_in[12];
    float* out         = (float*)d_out;

    char* w = (char*)d_ws;
    size_t off = 0;
    auto alloc = [&](size_t bytes) { size_t p = off; off += (bytes + 255) & ~(size_t)255; return p; };
    size_t o_flag = alloc(4);
    size_t o_ndeg = alloc((size_t)N_NODES * 4);
    size_t o_edeg = alloc((size_t)N_EDGES * 4);
    size_t o_gcnt = alloc((size_t)N_GRAPHS * 4);
    size_t zero_end = off;
    size_t o_noff = alloc((size_t)N_NODES * 4);
    size_t o_eoff = alloc((size_t)N_EDGES * 4);
    size_t o_goff = alloc((size_t)N_GRAPHS * 4);
    size_t o_ncur = alloc((size_t)N_NODES * 4);
    size_t o_ecur = alloc((size_t)N_EDGES * 4);
    size_t o_part = alloc(256 * 4);
    size_t o_nidx = alloc((size_t)N_INC * 4);
    size_t o_eidx = alloc((size_t)N_INC * 4);
    size_t o_bidx = alloc((size_t)N_NODES * 4);
    size_t o_csre = alloc((size_t)N_INC * 4);
    size_t o_csrn = alloc((size_t)N_INC * 4);
    size_t o_pool = alloc((size_t)N_GRAPHS * 256 * 4);
    size_t o_wt   = alloc((size_t)512 * 512 * 2);
    size_t o_xbf  = alloc((size_t)M_PAD * 128 * 2);   // x bf16 (padded rows)
    size_t o_Y    = alloc((size_t)M_PAD * 256 * 2);   // aggregated feats / XL (padded)
    size_t o_H1   = alloc((size_t)M_PAD * 256 * 2);   // layer1 out + final H (padded)
    size_t o_H2   = alloc((size_t)M_PAD * 512 * 2);   // layer2 out (padded)
    size_t o_bufE = alloc((size_t)N_EDGES * 256 * 2); // edge features (max width 256)

    int* flag = (int*)(w + o_flag);
    int* ndeg = (int*)(w + o_ndeg);
    int* edeg = (int*)(w + o_edeg);
    int* gcnt = (int*)(w + o_gcnt);
    int* noff = (int*)(w + o_noff);
    int* eoff = (int*)(w + o_eoff);
    int* goff = (int*)(w + o_goff);
    int* ncur = (int*)(w + o_ncur);
    int* ecur = (int*)(w + o_ecur);
    int* part = (int*)(w + o_part);
    int* nidx = (int*)(w + o_nidx);
    int* eidx = (int*)(w + o_eidx);
    int* bidx = (int*)(w + o_bidx);
    int* csre = (int*)(w + o_csre);
    int* csrn = (int*)(w + o_csrn);
    float* pool = (float*)(w + o_pool);
    unsigned short* wt   = (unsigned short*)(w + o_wt);
    unsigned short* xbf  = (unsigned short*)(w + o_xbf);
    unsigned short* Y    = (unsigned short*)(w + o_Y);
    unsigned short* H1   = (unsigned short*)(w + o_H1);
    unsigned short* H2   = (unsigned short*)(w + o_H2);
    unsigned short* bufE = (unsigned short*)(w + o_bufE);

    hipMemsetAsync(w, 0, zero_end, stream);
    detect_kernel<<<(N_INC + 255) / 256, 256, 0, stream>>>(hei, flag);
    normhist_kernel<<<(N_INC + 255) / 256, 256, 0, stream>>>(hei, braw, flag, nidx, eidx, bidx,
                                                             ndeg, edeg, gcnt);
    auto scan = [&](int* in, int n, int* outp, int* out2p) {
        int nb = (n + 1023) / 1024;
        scan_up<<<nb, 256, 0, stream>>>(in, n, outp, part);
        scan_mid<<<1, 256, 0, stream>>>(part, nb);
        scan_down<<<nb, 256, 0, stream>>>(outp, n, part, out2p);
    };
    scan(edeg, N_EDGES, eoff, ecur);
    scan(ndeg, N_NODES, noff, ncur);
    scan(gcnt, N_GRAPHS, goff, goff);
    csr_kernel<<<(N_INC + 255) / 256, 256, 0, stream>>>(nidx, eidx, ecur, ncur, csre, csrn);

    int n4 = (N_NODES * 128) / 4;
    convert_kernel<<<(n4 + 255) / 256, 256, 0, stream>>>(x, xbf, n4);

    int segGrid = (N_NODES * 64 + 255) / 256;   // one wave per segment (N_NODES == N_EDGES)

    // ---- layer 1 (aggregate-first at 128): Y = D^-1 H B^-1 H^T x ; H1 = relu(Y@W1+b1)
    seg_edge_t<128><<<segGrid, 256, 0, stream>>>(xbf, eoff, edeg, csre, bufE);
    seg_node_t<128, false><<<segGrid, 256, 0, stream>>>(bufE, noff, ndeg, csrn, nullptr, Y);
    wt_kernel<<<(128 * 256 + 255) / 256, 256, 0, stream>>>(W1, wt, 128, 256);
    {
        dim3 grid(256 / 128, M_PAD / 128);
        gemm128_kernel<true><<<grid, 256, 0, stream>>>(Y, wt, b1, H1, N_NODES, 128, 256);
    }
    // ---- layer 2 (aggregate-first at 256): Y = agg(H1) ; H2 = relu(Y@W2+b2)
    seg_edge_t<256><<<segGrid, 256, 0, stream>>>(H1, eoff, edeg, csre, bufE);
    seg_node_t<256, false><<<segGrid, 256, 0, stream>>>(bufE, noff, ndeg, csrn, nullptr, Y);
    wt_kernel<<<(256 * 512 + 255) / 256, 256, 0, stream>>>(W2, wt, 256, 512);
    {
        dim3 grid(512 / 128, M_PAD / 128);
        gemm128_kernel<true><<<grid, 256, 0, stream>>>(Y, wt, b2, H2, N_NODES, 256, 512);
    }
    // ---- layer 3 (gemm-first at 256): XL = H2@W3 ; H = relu(agg(XL)+b3)
    wt_kernel<<<(512 * 256 + 255) / 256, 256, 0, stream>>>(W3, wt, 512, 256);
    {
        dim3 grid(256 / 128, M_PAD / 128);
        gemm128_kernel<false><<<grid, 256, 0, stream>>>(H2, wt, nullptr, Y, N_NODES, 512, 256);
    }
    seg_edge_t<256><<<segGrid, 256, 0, stream>>>(Y, eoff, edeg, csre, bufE);
    seg_node_t<256, true><<<segGrid, 256, 0, stream>>>(bufE, noff, ndeg, csrn, b3, H1);

    pool_kernel<<<N_GRAPHS, 256, 0, stream>>>(H1, goff, gcnt, pool);
    head_kernel<<<N_GRAPHS, 128, 0, stream>>>(pool, Wl1, bl1, Wl2, bl2, out);
}

// Round 6
// 611.778 us; speedup vs baseline: 1.8011x; 1.0593x over previous
//
#include <hip/hip_runtime.h>
#include <hip/hip_bf16.h>

#define N_NODES  50000
#define N_EDGES  50000
#define N_INC    400000
#define N_GRAPHS 1024
#define M_PAD    50048          // 391 * 128

typedef __bf16 bf16x8 __attribute__((ext_vector_type(8)));
typedef float  f32x4  __attribute__((ext_vector_type(4)));

__device__ __forceinline__ unsigned short f2bf(float f) {
    __hip_bfloat16 h = __float2bfloat16(f);
    return __builtin_bit_cast(unsigned short, h);
}
__device__ __forceinline__ float bflo(unsigned int u) {
    return __builtin_bit_cast(float, u << 16);
}
__device__ __forceinline__ float bfhi(unsigned int u) {
    return __builtin_bit_cast(float, u & 0xffff0000u);
}
__device__ __forceinline__ unsigned int packbf(float a, float b) {
    return (unsigned int)f2bf(a) | ((unsigned int)f2bf(b) << 16);
}
__device__ __forceinline__ void load_lds16(const unsigned short* g, unsigned short* l) {
    __builtin_amdgcn_global_load_lds((const __attribute__((address_space(1))) void*)g,
                                     (__attribute__((address_space(3))) void*)l, 16, 0, 0);
}

// ---------------- int64-vs-int32 index detection ----------------
__global__ void detect_kernel(const int* __restrict__ hei, int* __restrict__ flag) {
    int i = blockIdx.x * blockDim.x + threadIdx.x;
    if (i < N_INC && hei[2 * i + 1] != 0) flag[0] = 1;   // 1 => int32 layout
}

// ---------------- normalize indices + degree histograms (fused) ----------------
__global__ void normhist_kernel(const int* __restrict__ hei, const int* __restrict__ braw,
                                const int* __restrict__ flag,
                                int* __restrict__ nidx, int* __restrict__ eidx,
                                int* __restrict__ bidx,
                                int* __restrict__ ndeg, int* __restrict__ edeg,
                                int* __restrict__ gcnt) {
    int i = blockIdx.x * blockDim.x + threadIdx.x;
    int is32 = flag[0];
    if (i < N_INC) {
        int n, e;
        if (is32) { n = hei[i];     e = hei[N_INC + i]; }
        else      { n = hei[2 * i]; e = hei[2 * N_INC + 2 * i]; }
        nidx[i] = n; eidx[i] = e;
        atomicAdd(&ndeg[n], 1);
        atomicAdd(&edeg[e], 1);
    }
    if (i < N_NODES) {
        int b = is32 ? braw[i] : braw[2 * i];
        bidx[i] = b;
        atomicAdd(&gcnt[b], 1);
    }
}

// ---------------- hierarchical exclusive scan ----------------
__global__ __launch_bounds__(256) void scan_up(const int* __restrict__ in, int n,
                                               int* __restrict__ out, int* __restrict__ partials) {
    __shared__ int lds[256];
    int t = threadIdx.x;
    int base = blockIdx.x * 1024 + t * 4;
    int4 v = make_int4(0, 0, 0, 0);
    if (base + 3 < n)      v = *(const int4*)(in + base);
    else if (base < n) {
        v.x = in[base];
        if (base + 1 < n) v.y = in[base + 1];
        if (base + 2 < n) v.z = in[base + 2];
    }
    int s = v.x + v.y + v.z + v.w;
    lds[t] = s;
    __syncthreads();
    for (int off = 1; off < 256; off <<= 1) {
        int u = (t >= off) ? lds[t - off] : 0;
        __syncthreads();
        lds[t] += u;
        __syncthreads();
    }
    int excl = lds[t] - s;
    if (t == 255) partials[blockIdx.x] = lds[255];
    int4 o;
    o.x = excl;
    o.y = excl + v.x;
    o.z = o.y + v.y;
    o.w = o.z + v.z;
    if (base + 3 < n) *(int4*)(out + base) = o;
    else if (base < n) {
        out[base] = o.x;
        if (base + 1 < n) out[base + 1] = o.y;
        if (base + 2 < n) out[base + 2] = o.z;
    }
}

__global__ __launch_bounds__(256) void scan_mid(int* __restrict__ partials, int nparts) {
    __shared__ int lds[256];
    int t = threadIdx.x;
    int s = (t < nparts) ? partials[t] : 0;
    lds[t] = s;
    __syncthreads();
    for (int off = 1; off < 256; off <<= 1) {
        int u = (t >= off) ? lds[t - off] : 0;
        __syncthreads();
        lds[t] += u;
        __syncthreads();
    }
    if (t < nparts) partials[t] = lds[t] - s;
}

__global__ __launch_bounds__(256) void scan_down(int* __restrict__ out, int n,
                                                 const int* __restrict__ partials,
                                                 int* __restrict__ out2) {
    int t = threadIdx.x;
    int base = blockIdx.x * 1024 + t * 4;
    int p = partials[blockIdx.x];
    if (base + 3 < n) {
        int4 v = *(const int4*)(out + base);
        v.x += p; v.y += p; v.z += p; v.w += p;
        *(int4*)(out + base) = v;
        *(int4*)(out2 + base) = v;
    } else if (base < n) {
        for (int k = 0; k < 4 && base + k < n; ++k) {
            int v = out[base + k] + p;
            out[base + k] = v;
            out2[base + k] = v;
        }
    }
}

// ---------------- CSR build via atomic cursors ----------------
__global__ void csr_kernel(const int* __restrict__ nidx, const int* __restrict__ eidx,
                           int* __restrict__ ecur, int* __restrict__ ncur,
                           int* __restrict__ csr_e_src, int* __restrict__ csr_n_src) {
    int i = blockIdx.x * blockDim.x + threadIdx.x;
    if (i >= N_INC) return;
    int n = nidx[i], e = eidx[i];
    int p = atomicAdd(&ecur[e], 1);
    csr_e_src[p] = n;
    int q = atomicAdd(&ncur[n], 1);
    csr_n_src[q] = e;
}

// ---------------- f32 -> bf16 plane conversion (x only) ----------------
__global__ void convert_kernel(const float* __restrict__ in, unsigned short* __restrict__ out, int n4) {
    int i = blockIdx.x * blockDim.x + threadIdx.x;
    if (i >= n4) return;
    float4 v = *(const float4*)(in + 4 * (size_t)i);
    ushort4 o;
    o.x = f2bf(v.x); o.y = f2bf(v.y); o.z = f2bf(v.z); o.w = f2bf(v.w);
    *(ushort4*)(out + 4 * (size_t)i) = o;
}

// ---------------- W[K][N] f32 -> Wt[N][K] bf16 ----------------
__global__ void wt_kernel(const float* __restrict__ W, unsigned short* __restrict__ Wt, int K, int N) {
    int i = blockIdx.x * blockDim.x + threadIdx.x;
    if (i >= K * N) return;
    int k = i / N, n = i - k * N;
    Wt[(size_t)n * K + k] = f2bf(W[i]);
}

// ---------------- 128x128 MFMA GEMM (m97 pattern) + LDS-staged epilogue ----------
// A[M_PAD][K] bf16 (rows >= M garbage but in-bounds), Bt[N][K] bf16, C[M][N] bf16.
template <bool EPI>
__global__ __launch_bounds__(256) void gemm128_kernel(const unsigned short* __restrict__ A,
                                                      const unsigned short* __restrict__ Bt,
                                                      const float* __restrict__ bias,
                                                      unsigned short* __restrict__ C,
                                                      int M, int K, int N) {
    __shared__ unsigned short As[128 * 32];
    __shared__ unsigned short Bs[128 * 32];
    __shared__ unsigned short Cs[32][140];   // pad 128->140: quad row-stride hits distinct banks
    int tid  = threadIdx.x;
    int wave = tid >> 6, lane = tid & 63;
    int n0 = blockIdx.x * 128, m0 = blockIdx.y * 128;
    int quad = lane >> 4, fr = lane & 15;
    int wr = wave >> 1, wc = wave & 1;          // wave's 64x64 quadrant
    int lrow16 = lane >> 2;                     // 0..15 staging row within group
    int lchunk = (lane & 3) * 8;                // element offset within 32-wide K slab

    const unsigned short* gsrc;
    unsigned short* ldst;
    if (wave < 2) { gsrc = A  + (size_t)(m0 + wave * 64) * K;       ldst = As + wave * 64 * 32; }
    else          { gsrc = Bt + (size_t)(n0 + (wave - 2) * 64) * K; ldst = Bs + (wave - 2) * 64 * 32; }

    f32x4 acc[4][4];
#pragma unroll
    for (int s = 0; s < 4; ++s)
#pragma unroll
        for (int c = 0; c < 4; ++c) acc[s][c] = (f32x4){0.f, 0.f, 0.f, 0.f};

    for (int k0 = 0; k0 < K; k0 += 32) {
#pragma unroll
        for (int l = 0; l < 4; ++l) {
            const unsigned short* g = gsrc + (size_t)(l * 16 + lrow16) * K + k0 + lchunk;
            load_lds16(g, ldst + l * 16 * 32);
        }
        __syncthreads();
        bf16x8 af[4], bfr[4];
#pragma unroll
        for (int s = 0; s < 4; ++s)
            af[s] = *(const bf16x8*)&As[(wr * 64 + s * 16 + fr) * 32 + quad * 8];
#pragma unroll
        for (int c = 0; c < 4; ++c)
            bfr[c] = *(const bf16x8*)&Bs[(wc * 64 + c * 16 + fr) * 32 + quad * 8];
#pragma unroll
        for (int s = 0; s < 4; ++s)
#pragma unroll
            for (int c = 0; c < 4; ++c)
                acc[s][c] = __builtin_amdgcn_mfma_f32_16x16x32_bf16(af[s], bfr[c], acc[s][c], 0, 0, 0);
        __syncthreads();
    }

    // Epilogue: per 16-row chunk s, stage 32 rows x 128 cols in LDS, then store
    // coalesced 16B/lane (256B contiguous per output row -> full HBM sectors).
    float bv[4];
#pragma unroll
    for (int c = 0; c < 4; ++c) bv[c] = EPI ? bias[n0 + wc * 64 + c * 16 + fr] : 0.f;
#pragma unroll
    for (int s = 0; s < 4; ++s) {
        // write fragments: wave (wr,wc) owns rows wr*16+quad*4+r, cols wc*64+c*16+fr
#pragma unroll
        for (int c = 0; c < 4; ++c)
#pragma unroll
            for (int r = 0; r < 4; ++r) {
                float v = acc[s][c][r];
                if (EPI) v = fmaxf(v + bv[c], 0.f);
                Cs[wr * 16 + quad * 4 + r][wc * 64 + c * 16 + fr] = f2bf(v);
            }
        __syncthreads();
        // cooperative store: 2 iters x (16 rows x 16 threads x 16B)
#pragma unroll
        for (int i = 0; i < 2; ++i) {
            int rl  = i * 16 + (tid >> 4);          // 0..31
            int col = (tid & 15) * 8;               // 0..120
            int gm  = m0 + (rl >> 4) * 64 + s * 16 + (rl & 15);
            if (gm < M) {
                uint4 v = *(const uint4*)&Cs[rl][col];
                *(uint4*)&C[(size_t)gm * N + n0 + col] = v;
            }
        }
        __syncthreads();
    }
}

// ---------------- node->edge: ef[e] = mean over members (bf16 in/out, f32 acc) ----
template <int C>
__global__ __launch_bounds__(256) void seg_edge_t(const unsigned short* __restrict__ xl,
                                                  const int* __restrict__ eoff,
                                                  const int* __restrict__ edeg,
                                                  const int* __restrict__ csr_src,
                                                  unsigned short* __restrict__ ef) {
    constexpr int VEC = C / 64;
    constexpr int NW  = VEC / 2;
    int w = (blockIdx.x * 256 + threadIdx.x) >> 6;
    int lane = threadIdx.x & 63;
    if (w >= N_EDGES) return;
    int deg = edeg[w], start = eoff[w];
    float binv = (deg > 0) ? 1.0f / (float)deg : 0.0f;
    float acc[VEC];
#pragma unroll
    for (int q = 0; q < VEC; ++q) acc[q] = 0.f;
    size_t lbase = (size_t)lane * VEC;
    for (int j = 0; j < deg; ++j) {
        int src = csr_src[start + j];
        const unsigned int* p = (const unsigned int*)(xl + (size_t)src * C + lbase);
        unsigned int v[NW];
        if constexpr (NW == 4)      { uint4 t = *(const uint4*)p; v[0] = t.x; v[1] = t.y; v[2] = t.z; v[3] = t.w; }
        else if constexpr (NW == 2) { uint2 t = *(const uint2*)p; v[0] = t.x; v[1] = t.y; }
        else                        { v[0] = *p; }
#pragma unroll
        for (int q = 0; q < NW; ++q) { acc[2 * q] += bflo(v[q]); acc[2 * q + 1] += bfhi(v[q]); }
    }
    unsigned int o[NW];
#pragma unroll
    for (int q = 0; q < NW; ++q) o[q] = packbf(acc[2 * q] * binv, acc[2 * q + 1] * binv);
    unsigned int* po = (unsigned int*)(ef + (size_t)w * C + lbase);
    if constexpr (NW == 4)      { *(uint4*)po = make_uint4(o[0], o[1], o[2], o[3]); }
    else if constexpr (NW == 2) { *(uint2*)po = make_uint2(o[0], o[1]); }
    else                        { *po = o[0]; }
}

// ---------------- edge->node: mean, optional +bias+relu (bf16 in/out, f32 acc) ----
template <int C, bool BIAS>
__global__ __launch_bounds__(256) void seg_node_t(const unsigned short* __restrict__ ef,
                                                  const int* __restrict__ noff,
                                                  const int* __restrict__ ndeg,
                                                  const int* __restrict__ csr_src,
                                                  const float* __restrict__ bias,
                                                  unsigned short* __restrict__ hout) {
    constexpr int VEC = C / 64;
    constexpr int NW  = VEC / 2;
    int w = (blockIdx.x * 256 + threadIdx.x) >> 6;
    int lane = threadIdx.x & 63;
    if (w >= N_NODES) return;
    int deg = ndeg[w], start = noff[w];
    float dinv = (deg > 0) ? 1.0f / (float)deg : 0.0f;
    float acc[VEC];
#pragma unroll
    for (int q = 0; q < VEC; ++q) acc[q] = 0.f;
    size_t lbase = (size_t)lane * VEC;
    for (int j = 0; j < deg; ++j) {
        int e = csr_src[start + j];
        const unsigned int* p = (const unsigned int*)(ef + (size_t)e * C + lbase);
        unsigned int v[NW];
        if constexpr (NW == 4)      { uint4 t = *(const uint4*)p; v[0] = t.x; v[1] = t.y; v[2] = t.z; v[3] = t.w; }
        else if constexpr (NW == 2) { uint2 t = *(const uint2*)p; v[0] = t.x; v[1] = t.y; }
        else                        { v[0] = *p; }
#pragma unroll
        for (int q = 0; q < NW; ++q) { acc[2 * q] += bflo(v[q]); acc[2 * q + 1] += bfhi(v[q]); }
    }
    unsigned int o[NW];
#pragma unroll
    for (int q = 0; q < NW; ++q) {
        float a = acc[2 * q] * dinv;
        float b = acc[2 * q + 1] * dinv;
        if constexpr (BIAS) {
            a = fmaxf(a + bias[lbase + 2 * q], 0.f);
            b = fmaxf(b + bias[lbase + 2 * q + 1], 0.f);
        }
        o[q] = packbf(a, b);
    }
    unsigned int* po = (unsigned int*)(hout + (size_t)w * C + lbase);
    if constexpr (NW == 4)      { *(uint4*)po = make_uint4(o[0], o[1], o[2], o[3]); }
    else if constexpr (NW == 2) { *(uint2*)po = make_uint2(o[0], o[1]); }
    else                        { *po = o[0]; }
}

// ---------------- mean pool per graph (batch sorted, bf16 H) ----------------
__global__ __launch_bounds__(256) void pool_kernel(const unsigned short* __restrict__ h,
                                                   const int* __restrict__ goff,
                                                   const int* __restrict__ gcnt,
                                                   float* __restrict__ pool) {
    int g = blockIdx.x, t = threadIdx.x;
    int s = goff[g], cnt = gcnt[g];
    float acc = 0.f;
    for (int i = 0; i < cnt; ++i) {
        unsigned int u = h[(size_t)(s + i) * 256 + t];
        acc += __builtin_bit_cast(float, u << 16);
    }
    pool[g * 256 + t] = acc / (float)(cnt > 0 ? cnt : 1);
}

// ---------------- head: relu(g@Wl1+bl1)@Wl2 + bl2 (all f32) ----------------
__global__ __launch_bounds__(128) void head_kernel(const float* __restrict__ pool,
                                                   const float* __restrict__ Wl1,
                                                   const float* __restrict__ bl1,
                                                   const float* __restrict__ Wl2,
                                                   const float* __restrict__ bl2,
                                                   float* __restrict__ out) {
    __shared__ float xs[256];
    __shared__ float red[128];
    int g = blockIdx.x, j = threadIdx.x;
    xs[j]       = pool[g * 256 + j];
    xs[j + 128] = pool[g * 256 + 128 + j];
    __syncthreads();
    float s = 0.f;
    for (int f = 0; f < 256; ++f) s += xs[f] * Wl1[f * 128 + j];
    s += bl1[j];
    s = fmaxf(s, 0.f);
    red[j] = s * Wl2[j];
    __syncthreads();
    for (int off = 64; off > 0; off >>= 1) {
        if (j < off) red[j] += red[j + off];
        __syncthreads();
    }
    if (j == 0) out[g] = red[0] + bl2[0];
}

extern "C" void kernel_launch(void* const* d_in, const int* in_sizes, int n_in,
                              void* d_out, int out_size, void* d_ws, size_t ws_size,
                              hipStream_t stream) {
    const float* x     = (const float*)d_in[0];
    const int* hei     = (const int*)d_in[1];
    const int* braw    = (const int*)d_in[2];
    const float* W1    = (const float*)d_in[3];
    const float* b1    = (const float*)d_in[4];
    const float* W2    = (const float*)d_in[5];
    const float* b2    = (const float*)d_in[6];
    const float* W3    = (const float*)d_in[7];
    const float* b3    = (const float*)d_in[8];
    const float* Wl1   = (const float*)d_in[9];
    const float* bl1   = (const float*)d_in[10];
    const float* Wl2   = (const float*)d_in[11];
    const float* bl2   = (const float*)d_in[12];
    float* out         = (float*)d_out;

    char* w = (char*)d_ws;
    size_t off = 0;
    auto alloc = [&](size_t bytes) { size_t p = off; off += (bytes + 255) & ~(size_t)255; return p; };
    size_t o_flag = alloc(4);
    size_t o_ndeg = alloc((size_t)N_NODES * 4);
    size_t o_edeg = alloc((size_t)N_EDGES * 4);
    size_t o_gcnt = alloc((size_t)N_GRAPHS * 4);
    size_t zero_end = off;
    size_t o_noff = alloc((size_t)N_NODES * 4);
    size_t o_eoff = alloc((size_t)N_EDGES * 4);
    size_t o_goff = alloc((size_t)N_GRAPHS * 4);
    size_t o_ncur = alloc((size_t)N_NODES * 4);
    size_t o_ecur = alloc((size_t)N_EDGES * 4);
    size_t o_part = alloc(256 * 4);
    size_t o_nidx = alloc((size_t)N_INC * 4);
    size_t o_eidx = alloc((size_t)N_INC * 4);
    size_t o_bidx = alloc((size_t)N_NODES * 4);
    size_t o_csre = alloc((size_t)N_INC * 4);
    size_t o_csrn = alloc((size_t)N_INC * 4);
    size_t o_pool = alloc((size_t)N_GRAPHS * 256 * 4);
    size_t o_wt   = alloc((size_t)512 * 512 * 2);
    size_t o_xbf  = alloc((size_t)M_PAD * 128 * 2);   // x bf16 (padded rows)
    size_t o_Y    = alloc((size_t)M_PAD * 256 * 2);   // aggregated feats / XL (padded)
    size_t o_H1   = alloc((size_t)M_PAD * 256 * 2);   // layer1 out + final H (padded)
    size_t o_H2   = alloc((size_t)M_PAD * 512 * 2);   // layer2 out (padded)
    size_t o_bufE = alloc((size_t)N_EDGES * 256 * 2); // edge features (max width 256)

    int* flag = (int*)(w + o_flag);
    int* ndeg = (int*)(w + o_ndeg);
    int* edeg = (int*)(w + o_edeg);
    int* gcnt = (int*)(w + o_gcnt);
    int* noff = (int*)(w + o_noff);
    int* eoff = (int*)(w + o_eoff);
    int* goff = (int*)(w + o_goff);
    int* ncur = (int*)(w + o_ncur);
    int* ecur = (int*)(w + o_ecur);
    int* part = (int*)(w + o_part);
    int* nidx = (int*)(w + o_nidx);
    int* eidx = (int*)(w + o_eidx);
    int* bidx = (int*)(w + o_bidx);
    int* csre = (int*)(w + o_csre);
    int* csrn = (int*)(w + o_csrn);
    float* pool = (float*)(w + o_pool);
    unsigned short* wt   = (unsigned short*)(w + o_wt);
    unsigned short* xbf  = (unsigned short*)(w + o_xbf);
    unsigned short* Y    = (unsigned short*)(w + o_Y);
    unsigned short* H1   = (unsigned short*)(w + o_H1);
    unsigned short* H2   = (unsigned short*)(w + o_H2);
    unsigned short* bufE = (unsigned short*)(w + o_bufE);

    hipMemsetAsync(w, 0, zero_end, stream);
    detect_kernel<<<(N_INC + 255) / 256, 256, 0, stream>>>(hei, flag);
    normhist_kernel<<<(N_INC + 255) / 256, 256, 0, stream>>>(hei, braw, flag, nidx, eidx, bidx,
                                                             ndeg, edeg, gcnt);
    auto scan = [&](int* in, int n, int* outp, int* out2p) {
        int nb = (n + 1023) / 1024;
        scan_up<<<nb, 256, 0, stream>>>(in, n, outp, part);
        scan_mid<<<1, 256, 0, stream>>>(part, nb);
        scan_down<<<nb, 256, 0, stream>>>(outp, n, part, out2p);
    };
    scan(edeg, N_EDGES, eoff, ecur);
    scan(ndeg, N_NODES, noff, ncur);
    scan(gcnt, N_GRAPHS, goff, goff);
    csr_kernel<<<(N_INC + 255) / 256, 256, 0, stream>>>(nidx, eidx, ecur, ncur, csre, csrn);

    int n4 = (N_NODES * 128) / 4;
    convert_kernel<<<(n4 + 255) / 256, 256, 0, stream>>>(x, xbf, n4);

    int segGrid = (N_NODES * 64 + 255) / 256;   // one wave per segment (N_NODES == N_EDGES)

    // ---- layer 1 (aggregate-first at 128): Y = D^-1 H B^-1 H^T x ; H1 = relu(Y@W1+b1)
    seg_edge_t<128><<<segGrid, 256, 0, stream>>>(xbf, eoff, edeg, csre, bufE);
    seg_node_t<128, false><<<segGrid, 256, 0, stream>>>(bufE, noff, ndeg, csrn, nullptr, Y);
    wt_kernel<<<(128 * 256 + 255) / 256, 256, 0, stream>>>(W1, wt, 128, 256);
    {
        dim3 grid(256 / 128, M_PAD / 128);
        gemm128_kernel<true><<<grid, 256, 0, stream>>>(Y, wt, b1, H1, N_NODES, 128, 256);
    }
    // ---- layer 2 (aggregate-first at 256): Y = agg(H1) ; H2 = relu(Y@W2+b2)
    seg_edge_t<256><<<segGrid, 256, 0, stream>>>(H1, eoff, edeg, csre, bufE);
    seg_node_t<256, false><<<segGrid, 256, 0, stream>>>(bufE, noff, ndeg, csrn, nullptr, Y);
    wt_kernel<<<(256 * 512 + 255) / 256, 256, 0, stream>>>(W2, wt, 256, 512);
    {
        dim3 grid(512 / 128, M_PAD / 128);
        gemm128_kernel<true><<<grid, 256, 0, stream>>>(Y, wt, b2, H2, N_NODES, 256, 512);
    }
    // ---- layer 3 (gemm-first at 256): XL = H2@W3 ; H = relu(agg(XL)+b3)
    wt_kernel<<<(512 * 256 + 255) / 256, 256, 0, stream>>>(W3, wt, 512, 256);
    {
        dim3 grid(256 / 128, M_PAD / 128);
        gemm128_kernel<false><<<grid, 256, 0, stream>>>(H2, wt, nullptr, Y, N_NODES, 512, 256);
    }
    seg_edge_t<256><<<segGrid, 256, 0, stream>>>(Y, eoff, edeg, csre, bufE);
    seg_node_t<256, true><<<segGrid, 256, 0, stream>>>(bufE, noff, ndeg, csrn, b3, H1);

    pool_kernel<<<N_GRAPHS, 256, 0, stream>>>(H1, goff, gcnt, pool);
    head_kernel<<<N_GRAPHS, 128, 0, stream>>>(pool, Wl1, bl1, Wl2, bl2, out);
}

// Round 7
// 496.832 us; speedup vs baseline: 2.2178x; 1.2314x over previous
//
#include <hip/hip_runtime.h>
#include <hip/hip_bf16.h>

#define N_NODES  50000
#define N_EDGES  50000
#define N_INC    400000
#define N_GRAPHS 1024
#define M_PAD    50048          // 391 * 128

typedef __bf16 bf16x8 __attribute__((ext_vector_type(8)));
typedef float  f32x4  __attribute__((ext_vector_type(4)));

__device__ __forceinline__ unsigned short f2bf(float f) {
    __hip_bfloat16 h = __float2bfloat16(f);
    return __builtin_bit_cast(unsigned short, h);
}
__device__ __forceinline__ float bflo(unsigned int u) {
    return __builtin_bit_cast(float, u << 16);
}
__device__ __forceinline__ float bfhi(unsigned int u) {
    return __builtin_bit_cast(float, u & 0xffff0000u);
}
__device__ __forceinline__ unsigned int packbf(float a, float b) {
    return (unsigned int)f2bf(a) | ((unsigned int)f2bf(b) << 16);
}
__device__ __forceinline__ void load_lds16(const unsigned short* g, unsigned short* l) {
    __builtin_amdgcn_global_load_lds((const __attribute__((address_space(1))) void*)g,
                                     (__attribute__((address_space(3))) void*)l, 16, 0, 0);
}

// ---------------- int64-vs-int32 index detection ----------------
__global__ void detect_kernel(const int* __restrict__ hei, int* __restrict__ flag) {
    int i = blockIdx.x * blockDim.x + threadIdx.x;
    if (i < N_INC && hei[2 * i + 1] != 0) flag[0] = 1;   // 1 => int32 layout
}

// ---------------- normalize indices + degree histograms (fused) ----------------
__global__ void normhist_kernel(const int* __restrict__ hei, const int* __restrict__ braw,
                                const int* __restrict__ flag,
                                int* __restrict__ nidx, int* __restrict__ eidx,
                                int* __restrict__ bidx,
                                int* __restrict__ ndeg, int* __restrict__ edeg,
                                int* __restrict__ gcnt) {
    int i = blockIdx.x * blockDim.x + threadIdx.x;
    int is32 = flag[0];
    if (i < N_INC) {
        int n, e;
        if (is32) { n = hei[i];     e = hei[N_INC + i]; }
        else      { n = hei[2 * i]; e = hei[2 * N_INC + 2 * i]; }
        nidx[i] = n; eidx[i] = e;
        atomicAdd(&ndeg[n], 1);
        atomicAdd(&edeg[e], 1);
    }
    if (i < N_NODES) {
        int b = is32 ? braw[i] : braw[2 * i];
        bidx[i] = b;
        atomicAdd(&gcnt[b], 1);
    }
}

// ---------------- hierarchical exclusive scan ----------------
__global__ __launch_bounds__(256) void scan_up(const int* __restrict__ in, int n,
                                               int* __restrict__ out, int* __restrict__ partials) {
    __shared__ int lds[256];
    int t = threadIdx.x;
    int base = blockIdx.x * 1024 + t * 4;
    int4 v = make_int4(0, 0, 0, 0);
    if (base + 3 < n)      v = *(const int4*)(in + base);
    else if (base < n) {
        v.x = in[base];
        if (base + 1 < n) v.y = in[base + 1];
        if (base + 2 < n) v.z = in[base + 2];
    }
    int s = v.x + v.y + v.z + v.w;
    lds[t] = s;
    __syncthreads();
    for (int off = 1; off < 256; off <<= 1) {
        int u = (t >= off) ? lds[t - off] : 0;
        __syncthreads();
        lds[t] += u;
        __syncthreads();
    }
    int excl = lds[t] - s;
    if (t == 255) partials[blockIdx.x] = lds[255];
    int4 o;
    o.x = excl;
    o.y = excl + v.x;
    o.z = o.y + v.y;
    o.w = o.z + v.z;
    if (base + 3 < n) *(int4*)(out + base) = o;
    else if (base < n) {
        out[base] = o.x;
        if (base + 1 < n) out[base + 1] = o.y;
        if (base + 2 < n) out[base + 2] = o.z;
    }
}

__global__ __launch_bounds__(256) void scan_mid(int* __restrict__ partials, int nparts) {
    __shared__ int lds[256];
    int t = threadIdx.x;
    int s = (t < nparts) ? partials[t] : 0;
    lds[t] = s;
    __syncthreads();
    for (int off = 1; off < 256; off <<= 1) {
        int u = (t >= off) ? lds[t - off] : 0;
        __syncthreads();
        lds[t] += u;
        __syncthreads();
    }
    if (t < nparts) partials[t] = lds[t] - s;
}

__global__ __launch_bounds__(256) void scan_down(int* __restrict__ out, int n,
                                                 const int* __restrict__ partials,
                                                 int* __restrict__ out2) {
    int t = threadIdx.x;
    int base = blockIdx.x * 1024 + t * 4;
    int p = partials[blockIdx.x];
    if (base + 3 < n) {
        int4 v = *(const int4*)(out + base);
        v.x += p; v.y += p; v.z += p; v.w += p;
        *(int4*)(out + base) = v;
        *(int4*)(out2 + base) = v;
    } else if (base < n) {
        for (int k = 0; k < 4 && base + k < n; ++k) {
            int v = out[base + k] + p;
            out[base + k] = v;
            out2[base + k] = v;
        }
    }
}

// ---------------- CSR build via atomic cursors ----------------
__global__ void csr_kernel(const int* __restrict__ nidx, const int* __restrict__ eidx,
                           int* __restrict__ ecur, int* __restrict__ ncur,
                           int* __restrict__ csr_e_src, int* __restrict__ csr_n_src) {
    int i = blockIdx.x * blockDim.x + threadIdx.x;
    if (i >= N_INC) return;
    int n = nidx[i], e = eidx[i];
    int p = atomicAdd(&ecur[e], 1);
    csr_e_src[p] = n;
    int q = atomicAdd(&ncur[n], 1);
    csr_n_src[q] = e;
}

// ---------------- f32 -> bf16 plane conversion (x only) ----------------
__global__ void convert_kernel(const float* __restrict__ in, unsigned short* __restrict__ out, int n4) {
    int i = blockIdx.x * blockDim.x + threadIdx.x;
    if (i >= n4) return;
    float4 v = *(const float4*)(in + 4 * (size_t)i);
    ushort4 o;
    o.x = f2bf(v.x); o.y = f2bf(v.y); o.z = f2bf(v.z); o.w = f2bf(v.w);
    *(ushort4*)(out + 4 * (size_t)i) = o;
}

// ---------------- W[K][N] f32 -> Wt[N][K] bf16 ----------------
__global__ void wt_kernel(const float* __restrict__ W, unsigned short* __restrict__ Wt, int K, int N) {
    int i = blockIdx.x * blockDim.x + threadIdx.x;
    if (i >= K * N) return;
    int k = i / N, n = i - k * N;
    Wt[(size_t)n * K + k] = f2bf(W[i]);
}

// ---------------- 128x128 MFMA GEMM (m97 pattern) + LDS-staged epilogue ----------
template <bool EPI>
__global__ __launch_bounds__(256) void gemm128_kernel(const unsigned short* __restrict__ A,
                                                      const unsigned short* __restrict__ Bt,
                                                      const float* __restrict__ bias,
                                                      unsigned short* __restrict__ C,
                                                      int M, int K, int N) {
    __shared__ unsigned short As[128 * 32];
    __shared__ unsigned short Bs[128 * 32];
    __shared__ unsigned short Cs[32][140];   // pad: quad row-stride hits distinct banks
    int tid  = threadIdx.x;
    int wave = tid >> 6, lane = tid & 63;
    int n0 = blockIdx.x * 128, m0 = blockIdx.y * 128;
    int quad = lane >> 4, fr = lane & 15;
    int wr = wave >> 1, wc = wave & 1;
    int lrow16 = lane >> 2;
    int lchunk = (lane & 3) * 8;

    const unsigned short* gsrc;
    unsigned short* ldst;
    if (wave < 2) { gsrc = A  + (size_t)(m0 + wave * 64) * K;       ldst = As + wave * 64 * 32; }
    else          { gsrc = Bt + (size_t)(n0 + (wave - 2) * 64) * K; ldst = Bs + (wave - 2) * 64 * 32; }

    f32x4 acc[4][4];
#pragma unroll
    for (int s = 0; s < 4; ++s)
#pragma unroll
        for (int c = 0; c < 4; ++c) acc[s][c] = (f32x4){0.f, 0.f, 0.f, 0.f};

    for (int k0 = 0; k0 < K; k0 += 32) {
#pragma unroll
        for (int l = 0; l < 4; ++l) {
            const unsigned short* g = gsrc + (size_t)(l * 16 + lrow16) * K + k0 + lchunk;
            load_lds16(g, ldst + l * 16 * 32);
        }
        __syncthreads();
        bf16x8 af[4], bfr[4];
#pragma unroll
        for (int s = 0; s < 4; ++s)
            af[s] = *(const bf16x8*)&As[(wr * 64 + s * 16 + fr) * 32 + quad * 8];
#pragma unroll
        for (int c = 0; c < 4; ++c)
            bfr[c] = *(const bf16x8*)&Bs[(wc * 64 + c * 16 + fr) * 32 + quad * 8];
#pragma unroll
        for (int s = 0; s < 4; ++s)
#pragma unroll
            for (int c = 0; c < 4; ++c)
                acc[s][c] = __builtin_amdgcn_mfma_f32_16x16x32_bf16(af[s], bfr[c], acc[s][c], 0, 0, 0);
        __syncthreads();
    }

    float bv[4];
#pragma unroll
    for (int c = 0; c < 4; ++c) bv[c] = EPI ? bias[n0 + wc * 64 + c * 16 + fr] : 0.f;
#pragma unroll
    for (int s = 0; s < 4; ++s) {
#pragma unroll
        for (int c = 0; c < 4; ++c)
#pragma unroll
            for (int r = 0; r < 4; ++r) {
                float v = acc[s][c][r];
                if (EPI) v = fmaxf(v + bv[c], 0.f);
                Cs[wr * 16 + quad * 4 + r][wc * 64 + c * 16 + fr] = f2bf(v);
            }
        __syncthreads();
#pragma unroll
        for (int i = 0; i < 2; ++i) {
            int rl  = i * 16 + (tid >> 4);
            int col = (tid & 15) * 8;
            int gm  = m0 + (rl >> 4) * 64 + s * 16 + (rl & 15);
            if (gm < M) {
                uint4 v = *(const uint4*)&Cs[rl][col];
                *(uint4*)&C[(size_t)gm * N + n0 + col] = v;
            }
        }
        __syncthreads();
    }
}

// ---------------- generic segment-mean gather (4x unrolled, scalarized CSR) ------
// acc[VEC] f32 accumulate of rows src[j] from in[.][C]; out = mean (+bias+relu).
template <int C, bool BIAS>
__device__ __forceinline__ void seg_body(const unsigned short* __restrict__ in,
                                         const int* __restrict__ offs,
                                         const int* __restrict__ degs,
                                         const int* __restrict__ csr_src,
                                         const float* __restrict__ bias,
                                         unsigned short* __restrict__ outp,
                                         int nseg) {
    constexpr int VEC = C / 64;
    constexpr int NW  = VEC / 2;
    int w = (blockIdx.x * 256 + threadIdx.x) >> 6;   // one wave per segment
    int lane = threadIdx.x & 63;
    if (w >= nseg) return;
    int deg   = __builtin_amdgcn_readfirstlane(degs[w]);
    int start = __builtin_amdgcn_readfirstlane(offs[w]);
    float dinv = (deg > 0) ? 1.0f / (float)deg : 0.0f;
    const int* cs = csr_src + start;
    float acc[VEC];
#pragma unroll
    for (int q = 0; q < VEC; ++q) acc[q] = 0.f;
    size_t lbase = (size_t)lane * VEC;

    auto accum = [&](unsigned int* v) {
#pragma unroll
        for (int q = 0; q < NW; ++q) { acc[2 * q] += bflo(v[q]); acc[2 * q + 1] += bfhi(v[q]); }
    };
    auto loadrow = [&](int src, unsigned int* v) {
        const unsigned int* p = (const unsigned int*)(in + (size_t)src * C + lbase);
        if constexpr (NW == 4)      { uint4 t = *(const uint4*)p; v[0] = t.x; v[1] = t.y; v[2] = t.z; v[3] = t.w; }
        else if constexpr (NW == 2) { uint2 t = *(const uint2*)p; v[0] = t.x; v[1] = t.y; }
        else                        { v[0] = *p; }
    };

    int j = 0;
    for (; j + 4 <= deg; j += 4) {
        int s0 = __builtin_amdgcn_readfirstlane(cs[j]);
        int s1 = __builtin_amdgcn_readfirstlane(cs[j + 1]);
        int s2 = __builtin_amdgcn_readfirstlane(cs[j + 2]);
        int s3 = __builtin_amdgcn_readfirstlane(cs[j + 3]);
        unsigned int v0[NW], v1[NW], v2[NW], v3[NW];
        loadrow(s0, v0); loadrow(s1, v1); loadrow(s2, v2); loadrow(s3, v3);
        accum(v0); accum(v1); accum(v2); accum(v3);
    }
    for (; j < deg; ++j) {
        int s0 = __builtin_amdgcn_readfirstlane(cs[j]);
        unsigned int v0[NW];
        loadrow(s0, v0);
        accum(v0);
    }

    unsigned int o[NW];
#pragma unroll
    for (int q = 0; q < NW; ++q) {
        float a = acc[2 * q] * dinv;
        float b = acc[2 * q + 1] * dinv;
        if constexpr (BIAS) {
            a = fmaxf(a + bias[lbase + 2 * q], 0.f);
            b = fmaxf(b + bias[lbase + 2 * q + 1], 0.f);
        }
        o[q] = packbf(a, b);
    }
    unsigned int* po = (unsigned int*)(outp + (size_t)w * C + lbase);
    if constexpr (NW == 4)      { *(uint4*)po = make_uint4(o[0], o[1], o[2], o[3]); }
    else if constexpr (NW == 2) { *(uint2*)po = make_uint2(o[0], o[1]); }
    else                        { *po = o[0]; }
}

template <int C>
__global__ __launch_bounds__(256) void seg_edge_t(const unsigned short* __restrict__ xl,
                                                  const int* __restrict__ eoff,
                                                  const int* __restrict__ edeg,
                                                  const int* __restrict__ csr_src,
                                                  unsigned short* __restrict__ ef) {
    seg_body<C, false>(xl, eoff, edeg, csr_src, nullptr, ef, N_EDGES);
}

template <int C, bool BIAS>
__global__ __launch_bounds__(256) void seg_node_t(const unsigned short* __restrict__ ef,
                                                  const int* __restrict__ noff,
                                                  const int* __restrict__ ndeg,
                                                  const int* __restrict__ csr_src,
                                                  const float* __restrict__ bias,
                                                  unsigned short* __restrict__ hout) {
    seg_body<C, BIAS>(ef, noff, ndeg, csr_src, bias, hout, N_NODES);
}

// ---------------- mean pool per graph (batch sorted, bf16 H) ----------------
__global__ __launch_bounds__(256) void pool_kernel(const unsigned short* __restrict__ h,
                                                   const int* __restrict__ goff,
                                                   const int* __restrict__ gcnt,
                                                   float* __restrict__ pool) {
    int g = blockIdx.x, t = threadIdx.x;
    int s = goff[g], cnt = gcnt[g];
    float acc = 0.f;
    for (int i = 0; i < cnt; ++i) {
        unsigned int u = h[(size_t)(s + i) * 256 + t];
        acc += __builtin_bit_cast(float, u << 16);
    }
    pool[g * 256 + t] = acc / (float)(cnt > 0 ? cnt : 1);
}

// ---------------- head: relu(g@Wl1+bl1)@Wl2 + bl2 (all f32) ----------------
__global__ __launch_bounds__(128) void head_kernel(const float* __restrict__ pool,
                                                   const float* __restrict__ Wl1,
                                                   const float* __restrict__ bl1,
                                                   const float* __restrict__ Wl2,
                                                   const float* __restrict__ bl2,
                                                   float* __restrict__ out) {
    __shared__ float xs[256];
    __shared__ float red[128];
    int g = blockIdx.x, j = threadIdx.x;
    xs[j]       = pool[g * 256 + j];
    xs[j + 128] = pool[g * 256 + 128 + j];
    __syncthreads();
    float s = 0.f;
    for (int f = 0; f < 256; ++f) s += xs[f] * Wl1[f * 128 + j];
    s += bl1[j];
    s = fmaxf(s, 0.f);
    red[j] = s * Wl2[j];
    __syncthreads();
    for (int off = 64; off > 0; off >>= 1) {
        if (j < off) red[j] += red[j + off];
        __syncthreads();
    }
    if (j == 0) out[g] = red[0] + bl2[0];
}

extern "C" void kernel_launch(void* const* d_in, const int* in_sizes, int n_in,
                              void* d_out, int out_size, void* d_ws, size_t ws_size,
                              hipStream_t stream) {
    const float* x     = (const float*)d_in[0];
    const int* hei     = (const int*)d_in[1];
    const int* braw    = (const int*)d_in[2];
    const float* W1    = (const float*)d_in[3];
    const float* b1    = (const float*)d_in[4];
    const float* W2    = (const float*)d_in[5];
    const float* b2    = (const float*)d_in[6];
    const float* W3    = (const float*)d_in[7];
    const float* b3    = (const float*)d_in[8];
    const float* Wl1   = (const float*)d_in[9];
    const float* bl1   = (const float*)d_in[10];
    const float* Wl2   = (const float*)d_in[11];
    const float* bl2   = (const float*)d_in[12];
    float* out         = (float*)d_out;

    char* w = (char*)d_ws;
    size_t off = 0;
    auto alloc = [&](size_t bytes) { size_t p = off; off += (bytes + 255) & ~(size_t)255; return p; };
    size_t o_flag = alloc(4);
    size_t o_ndeg = alloc((size_t)N_NODES * 4);
    size_t o_edeg = alloc((size_t)N_EDGES * 4);
    size_t o_gcnt = alloc((size_t)N_GRAPHS * 4);
    size_t zero_end = off;
    size_t o_noff = alloc((size_t)N_NODES * 4);
    size_t o_eoff = alloc((size_t)N_EDGES * 4);
    size_t o_goff = alloc((size_t)N_GRAPHS * 4);
    size_t o_ncur = alloc((size_t)N_NODES * 4);
    size_t o_ecur = alloc((size_t)N_EDGES * 4);
    size_t o_part = alloc(256 * 4);
    size_t o_nidx = alloc((size_t)N_INC * 4);
    size_t o_eidx = alloc((size_t)N_INC * 4);
    size_t o_bidx = alloc((size_t)N_NODES * 4);
    size_t o_csre = alloc((size_t)N_INC * 4);
    size_t o_csrn = alloc((size_t)N_INC * 4);
    size_t o_pool = alloc((size_t)N_GRAPHS * 256 * 4);
    size_t o_wt   = alloc((size_t)512 * 512 * 2);
    size_t o_xbf  = alloc((size_t)M_PAD * 128 * 2);
    size_t o_Y    = alloc((size_t)M_PAD * 256 * 2);
    size_t o_H1   = alloc((size_t)M_PAD * 256 * 2);
    size_t o_H2   = alloc((size_t)M_PAD * 512 * 2);
    size_t o_bufE = alloc((size_t)N_EDGES * 256 * 2);

    int* flag = (int*)(w + o_flag);
    int* ndeg = (int*)(w + o_ndeg);
    int* edeg = (int*)(w + o_edeg);
    int* gcnt = (int*)(w + o_gcnt);
    int* noff = (int*)(w + o_noff);
    int* eoff = (int*)(w + o_eoff);
    int* goff = (int*)(w + o_goff);
    int* ncur = (int*)(w + o_ncur);
    int* ecur = (int*)(w + o_ecur);
    int* part = (int*)(w + o_part);
    int* nidx = (int*)(w + o_nidx);
    int* eidx = (int*)(w + o_eidx);
    int* bidx = (int*)(w + o_bidx);
    int* csre = (int*)(w + o_csre);
    int* csrn = (int*)(w + o_csrn);
    float* pool = (float*)(w + o_pool);
    unsigned short* wt   = (unsigned short*)(w + o_wt);
    unsigned short* xbf  = (unsigned short*)(w + o_xbf);
    unsigned short* Y    = (unsigned short*)(w + o_Y);
    unsigned short* H1   = (unsigned short*)(w + o_H1);
    unsigned short* H2   = (unsigned short*)(w + o_H2);
    unsigned short* bufE = (unsigned short*)(w + o_bufE);

    hipMemsetAsync(w, 0, zero_end, stream);
    detect_kernel<<<(N_INC + 255) / 256, 256, 0, stream>>>(hei, flag);
    normhist_kernel<<<(N_INC + 255) / 256, 256, 0, stream>>>(hei, braw, flag, nidx, eidx, bidx,
                                                             ndeg, edeg, gcnt);
    auto scan = [&](int* in, int n, int* outp, int* out2p) {
        int nb = (n + 1023) / 1024;
        scan_up<<<nb, 256, 0, stream>>>(in, n, outp, part);
        scan_mid<<<1, 256, 0, stream>>>(part, nb);
        scan_down<<<nb, 256, 0, stream>>>(outp, n, part, out2p);
    };
    scan(edeg, N_EDGES, eoff, ecur);
    scan(ndeg, N_NODES, noff, ncur);
    scan(gcnt, N_GRAPHS, goff, goff);
    csr_kernel<<<(N_INC + 255) / 256, 256, 0, stream>>>(nidx, eidx, ecur, ncur, csre, csrn);

    int n4 = (N_NODES * 128) / 4;
    convert_kernel<<<(n4 + 255) / 256, 256, 0, stream>>>(x, xbf, n4);

    int segGrid = (N_NODES * 64 + 255) / 256;   // one wave per segment (N_NODES == N_EDGES)

    // ---- layer 1 (aggregate-first at 128)
    seg_edge_t<128><<<segGrid, 256, 0, stream>>>(xbf, eoff, edeg, csre, bufE);
    seg_node_t<128, false><<<segGrid, 256, 0, stream>>>(bufE, noff, ndeg, csrn, nullptr, Y);
    wt_kernel<<<(128 * 256 + 255) / 256, 256, 0, stream>>>(W1, wt, 128, 256);
    {
        dim3 grid(256 / 128, M_PAD / 128);
        gemm128_kernel<true><<<grid, 256, 0, stream>>>(Y, wt, b1, H1, N_NODES, 128, 256);
    }
    // ---- layer 2 (aggregate-first at 256)
    seg_edge_t<256><<<segGrid, 256, 0, stream>>>(H1, eoff, edeg, csre, bufE);
    seg_node_t<256, false><<<segGrid, 256, 0, stream>>>(bufE, noff, ndeg, csrn, nullptr, Y);
    wt_kernel<<<(256 * 512 + 255) / 256, 256, 0, stream>>>(W2, wt, 256, 512);
    {
        dim3 grid(512 / 128, M_PAD / 128);
        gemm128_kernel<true><<<grid, 256, 0, stream>>>(Y, wt, b2, H2, N_NODES, 256, 512);
    }
    // ---- layer 3 (gemm-first at 256)
    wt_kernel<<<(512 * 256 + 255) / 256, 256, 0, stream>>>(W3, wt, 512, 256);
    {
        dim3 grid(256 / 128, M_PAD / 128);
        gemm128_kernel<false><<<grid, 256, 0, stream>>>(H2, wt, nullptr, Y, N_NODES, 512, 256);
    }
    seg_edge_t<256><<<segGrid, 256, 0, stream>>>(Y, eoff, edeg, csre, bufE);
    seg_node_t<256, true><<<segGrid, 256, 0, stream>>>(bufE, noff, ndeg, csrn, b3, H1);

    pool_kernel<<<N_GRAPHS, 256, 0, stream>>>(H1, goff, gcnt, pool);
    head_kernel<<<N_GRAPHS, 128, 0, stream>>>(pool, Wl1, bl1, Wl2, bl2, out);
}

// Round 8
// 462.527 us; speedup vs baseline: 2.3823x; 1.0742x over previous
//
#include <hip/hip_runtime.h>
#include <hip/hip_bf16.h>

#define N_NODES  50000
#define N_EDGES  50000
#define N_INC    400000
#define N_GRAPHS 1024
#define M_PAD    50048          // 391 * 128
#define SEG_CAP  50176          // 49 * 1024 (scan padding)

typedef __bf16 bf16x8 __attribute__((ext_vector_type(8)));
typedef float  f32x4  __attribute__((ext_vector_type(4)));

__device__ __forceinline__ unsigned short f2bf(float f) {
    __hip_bfloat16 h = __float2bfloat16(f);
    return __builtin_bit_cast(unsigned short, h);
}
__device__ __forceinline__ float bflo(unsigned int u) {
    return __builtin_bit_cast(float, u << 16);
}
__device__ __forceinline__ float bfhi(unsigned int u) {
    return __builtin_bit_cast(float, u & 0xffff0000u);
}
__device__ __forceinline__ unsigned int packbf(float a, float b) {
    return (unsigned int)f2bf(a) | ((unsigned int)f2bf(b) << 16);
}
__device__ __forceinline__ void load_lds16(const unsigned short* g, unsigned short* l) {
    __builtin_amdgcn_global_load_lds((const __attribute__((address_space(1))) void*)g,
                                     (__attribute__((address_space(3))) void*)l, 16, 0, 0);
}

// ---------------- normalize indices + histograms, inline int64 detection ----------
__global__ __launch_bounds__(256) void normhist_kernel(const int* __restrict__ hei,
                                                       const int* __restrict__ braw,
                                                       int* __restrict__ nidx, int* __restrict__ eidx,
                                                       int* __restrict__ bidx,
                                                       int* __restrict__ ndeg, int* __restrict__ edeg,
                                                       int* __restrict__ gcnt) {
    __shared__ int s32;
    int t = threadIdx.x;
    if (t == 0) s32 = 0;
    __syncthreads();
    // int64 layout => odd 32-bit words are zero. Check first 512 odd words.
    int probe = hei[4 * t + 1] | hei[4 * t + 3];
    if (probe) s32 = 1;               // benign race
    __syncthreads();
    int is32 = s32;
    int i = blockIdx.x * 256 + t;
    if (i < N_INC) {
        int n, e;
        if (is32) { n = hei[i];     e = hei[N_INC + i]; }
        else      { n = hei[2 * i]; e = hei[2 * N_INC + 2 * i]; }
        nidx[i] = n; eidx[i] = e;
        atomicAdd(&ndeg[n], 1);
        atomicAdd(&edeg[e], 1);
    }
    if (i < N_NODES) {
        int b = is32 ? braw[i] : braw[2 * i];
        bidx[i] = b;
        atomicAdd(&gcnt[b], 1);
    }
}

// ---------------- fused segmented hierarchical scan (edeg | ndeg | gcnt) ----------
// All arrays zero-padded to block multiples -> no bounds checks.
__global__ __launch_bounds__(256) void scan_up_f(const int* __restrict__ edeg,
                                                 const int* __restrict__ ndeg,
                                                 const int* __restrict__ gcnt,
                                                 int* __restrict__ eoff, int* __restrict__ noff,
                                                 int* __restrict__ goff,
                                                 int* __restrict__ partials) {
    __shared__ int lds[256];
    int b = blockIdx.x, t = threadIdx.x;
    const int* in; int* outp; int lb;
    if (b < 49)      { in = edeg; outp = eoff; lb = b; }
    else if (b < 98) { in = ndeg; outp = noff; lb = b - 49; }
    else             { in = gcnt; outp = goff; lb = 0; }
    int base = lb * 1024 + t * 4;
    int4 v = *(const int4*)(in + base);
    int s = v.x + v.y + v.z + v.w;
    lds[t] = s;
    __syncthreads();
    for (int off = 1; off < 256; off <<= 1) {
        int u = (t >= off) ? lds[t - off] : 0;
        __syncthreads();
        lds[t] += u;
        __syncthreads();
    }
    int excl = lds[t] - s;
    if (t == 255) partials[b] = lds[255];
    int4 o;
    o.x = excl;
    o.y = excl + v.x;
    o.z = o.y + v.y;
    o.w = o.z + v.z;
    *(int4*)(outp + base) = o;
}

__global__ __launch_bounds__(128) void scan_mid_f(int* __restrict__ partials) {
    __shared__ int lds[99];
    int t = threadIdx.x;
    if (t < 99) lds[t] = partials[t];
    __syncthreads();
    if (t < 3) {
        int lo = (t == 0) ? 0 : (t == 1 ? 49 : 98);
        int hi = (t == 0) ? 49 : (t == 1 ? 98 : 99);
        int run = 0;
        for (int i = lo; i < hi; ++i) { int x = lds[i]; lds[i] = run; run += x; }
    }
    __syncthreads();
    if (t < 99) partials[t] = lds[t];
}

__global__ __launch_bounds__(256) void scan_down_f(int* __restrict__ eoff, int* __restrict__ ecur,
                                                   int* __restrict__ noff, int* __restrict__ ncur,
                                                   int* __restrict__ goff,
                                                   const int* __restrict__ partials) {
    int b = blockIdx.x, t = threadIdx.x;
    int* outp; int* out2; int lb;
    if (b < 49)      { outp = eoff; out2 = ecur; lb = b; }
    else if (b < 98) { outp = noff; out2 = ncur; lb = b - 49; }
    else             { outp = goff; out2 = goff; lb = 0; }
    int base = lb * 1024 + t * 4;
    int p = partials[b];
    int4 v = *(const int4*)(outp + base);
    v.x += p; v.y += p; v.z += p; v.w += p;
    *(int4*)(outp + base) = v;
    *(int4*)(out2 + base) = v;
}

// ---------------- mega prep: CSR scatter + x->bf16 + 3 weight transposes ----------
#define NB_CSR  1563
#define NB_CONV 6250
#define NB_W1   128
#define NB_W2   512
#define NB_W3   512
__global__ __launch_bounds__(256) void prep_kernel(const int* __restrict__ nidx,
                                                   const int* __restrict__ eidx,
                                                   int* __restrict__ ecur, int* __restrict__ ncur,
                                                   int* __restrict__ csre, int* __restrict__ csrn,
                                                   const float* __restrict__ x,
                                                   unsigned short* __restrict__ xbf,
                                                   const float* __restrict__ W1, unsigned short* __restrict__ wt1,
                                                   const float* __restrict__ W2, unsigned short* __restrict__ wt2,
                                                   const float* __restrict__ W3, unsigned short* __restrict__ wt3) {
    int b = blockIdx.x, t = threadIdx.x;
    if (b < NB_CSR) {
        int i = b * 256 + t;
        if (i < N_INC) {
            int n = nidx[i], e = eidx[i];
            int p = atomicAdd(&ecur[e], 1);
            csre[p] = n;
            int q = atomicAdd(&ncur[n], 1);
            csrn[q] = e;
        }
    } else if (b < NB_CSR + NB_CONV) {
        int i = (b - NB_CSR) * 256 + t;      // exactly 1.6M quads
        float4 v = *(const float4*)(x + 4 * (size_t)i);
        ushort4 o;
        o.x = f2bf(v.x); o.y = f2bf(v.y); o.z = f2bf(v.z); o.w = f2bf(v.w);
        *(ushort4*)(xbf + 4 * (size_t)i) = o;
    } else if (b < NB_CSR + NB_CONV + NB_W1) {
        int i = (b - NB_CSR - NB_CONV) * 256 + t;   // < 128*256
        int k = i >> 8, n = i & 255;
        wt1[n * 128 + k] = f2bf(W1[i]);
    } else if (b < NB_CSR + NB_CONV + NB_W1 + NB_W2) {
        int i = (b - NB_CSR - NB_CONV - NB_W1) * 256 + t;   // < 256*512
        int k = i >> 9, n = i & 511;
        wt2[n * 256 + k] = f2bf(W2[i]);
    } else {
        int i = (b - NB_CSR - NB_CONV - NB_W1 - NB_W2) * 256 + t;   // < 512*256
        int k = i >> 8, n = i & 255;
        wt3[n * 512 + k] = f2bf(W3[i]);
    }
}

// ---------------- 128x128 MFMA GEMM (m97 pattern) + LDS-staged epilogue ----------
template <bool EPI>
__global__ __launch_bounds__(256) void gemm128_kernel(const unsigned short* __restrict__ A,
                                                      const unsigned short* __restrict__ Bt,
                                                      const float* __restrict__ bias,
                                                      unsigned short* __restrict__ C,
                                                      int M, int K, int N) {
    __shared__ unsigned short As[128 * 32];
    __shared__ unsigned short Bs[128 * 32];
    __shared__ unsigned short Cs[32][140];
    int tid  = threadIdx.x;
    int wave = tid >> 6, lane = tid & 63;
    int n0 = blockIdx.x * 128, m0 = blockIdx.y * 128;
    int quad = lane >> 4, fr = lane & 15;
    int wr = wave >> 1, wc = wave & 1;
    int lrow16 = lane >> 2;
    int lchunk = (lane & 3) * 8;

    const unsigned short* gsrc;
    unsigned short* ldst;
    if (wave < 2) { gsrc = A  + (size_t)(m0 + wave * 64) * K;       ldst = As + wave * 64 * 32; }
    else          { gsrc = Bt + (size_t)(n0 + (wave - 2) * 64) * K; ldst = Bs + (wave - 2) * 64 * 32; }

    f32x4 acc[4][4];
#pragma unroll
    for (int s = 0; s < 4; ++s)
#pragma unroll
        for (int c = 0; c < 4; ++c) acc[s][c] = (f32x4){0.f, 0.f, 0.f, 0.f};

    for (int k0 = 0; k0 < K; k0 += 32) {
#pragma unroll
        for (int l = 0; l < 4; ++l) {
            const unsigned short* g = gsrc + (size_t)(l * 16 + lrow16) * K + k0 + lchunk;
            load_lds16(g, ldst + l * 16 * 32);
        }
        __syncthreads();
        bf16x8 af[4], bfr[4];
#pragma unroll
        for (int s = 0; s < 4; ++s)
            af[s] = *(const bf16x8*)&As[(wr * 64 + s * 16 + fr) * 32 + quad * 8];
#pragma unroll
        for (int c = 0; c < 4; ++c)
            bfr[c] = *(const bf16x8*)&Bs[(wc * 64 + c * 16 + fr) * 32 + quad * 8];
#pragma unroll
        for (int s = 0; s < 4; ++s)
#pragma unroll
            for (int c = 0; c < 4; ++c)
                acc[s][c] = __builtin_amdgcn_mfma_f32_16x16x32_bf16(af[s], bfr[c], acc[s][c], 0, 0, 0);
        __syncthreads();
    }

    float bv[4];
#pragma unroll
    for (int c = 0; c < 4; ++c) bv[c] = EPI ? bias[n0 + wc * 64 + c * 16 + fr] : 0.f;
#pragma unroll
    for (int s = 0; s < 4; ++s) {
#pragma unroll
        for (int c = 0; c < 4; ++c)
#pragma unroll
            for (int r = 0; r < 4; ++r) {
                float v = acc[s][c][r];
                if (EPI) v = fmaxf(v + bv[c], 0.f);
                Cs[wr * 16 + quad * 4 + r][wc * 64 + c * 16 + fr] = f2bf(v);
            }
        __syncthreads();
#pragma unroll
        for (int i = 0; i < 2; ++i) {
            int rl  = i * 16 + (tid >> 4);
            int col = (tid & 15) * 8;
            int gm  = m0 + (rl >> 4) * 64 + s * 16 + (rl & 15);
            if (gm < M) {
                uint4 v = *(const uint4*)&Cs[rl][col];
                *(uint4*)&C[(size_t)gm * N + n0 + col] = v;
            }
        }
        __syncthreads();
    }
}

// ---------------- generic segment-mean gather (8x unrolled, scalarized CSR) ------
template <int C, bool BIAS>
__device__ __forceinline__ void seg_body(const unsigned short* __restrict__ in,
                                         const int* __restrict__ offs,
                                         const int* __restrict__ degs,
                                         const int* __restrict__ csr_src,
                                         const float* __restrict__ bias,
                                         unsigned short* __restrict__ outp,
                                         int nseg) {
    constexpr int VEC = C / 64;
    constexpr int NW  = VEC / 2;
    int w = (blockIdx.x * 256 + threadIdx.x) >> 6;   // one wave per segment
    int lane = threadIdx.x & 63;
    if (w >= nseg) return;
    int deg   = __builtin_amdgcn_readfirstlane(degs[w]);
    int start = __builtin_amdgcn_readfirstlane(offs[w]);
    float dinv = (deg > 0) ? 1.0f / (float)deg : 0.0f;
    const int* cs = csr_src + start;
    float acc[VEC];
#pragma unroll
    for (int q = 0; q < VEC; ++q) acc[q] = 0.f;
    size_t lbase = (size_t)lane * VEC;

    auto accum = [&](unsigned int* v) {
#pragma unroll
        for (int q = 0; q < NW; ++q) { acc[2 * q] += bflo(v[q]); acc[2 * q + 1] += bfhi(v[q]); }
    };
    auto loadrow = [&](int src, unsigned int* v) {
        const unsigned int* p = (const unsigned int*)(in + (size_t)src * C + lbase);
        if constexpr (NW == 4)      { uint4 t = *(const uint4*)p; v[0] = t.x; v[1] = t.y; v[2] = t.z; v[3] = t.w; }
        else if constexpr (NW == 2) { uint2 t = *(const uint2*)p; v[0] = t.x; v[1] = t.y; }
        else                        { v[0] = *p; }
    };

    int j = 0;
    for (; j + 8 <= deg; j += 8) {
        int s[8];
        unsigned int v[8][NW];
#pragma unroll
        for (int u = 0; u < 8; ++u) s[u] = __builtin_amdgcn_readfirstlane(cs[j + u]);
#pragma unroll
        for (int u = 0; u < 8; ++u) loadrow(s[u], v[u]);
#pragma unroll
        for (int u = 0; u < 8; ++u) accum(v[u]);
    }
    for (; j + 4 <= deg; j += 4) {
        int s[4];
        unsigned int v[4][NW];
#pragma unroll
        for (int u = 0; u < 4; ++u) s[u] = __builtin_amdgcn_readfirstlane(cs[j + u]);
#pragma unroll
        for (int u = 0; u < 4; ++u) loadrow(s[u], v[u]);
#pragma unroll
        for (int u = 0; u < 4; ++u) accum(v[u]);
    }
    for (; j < deg; ++j) {
        int s0 = __builtin_amdgcn_readfirstlane(cs[j]);
        unsigned int v0[NW];
        loadrow(s0, v0);
        accum(v0);
    }

    unsigned int o[NW];
#pragma unroll
    for (int q = 0; q < NW; ++q) {
        float a = acc[2 * q] * dinv;
        float b = acc[2 * q + 1] * dinv;
        if constexpr (BIAS) {
            a = fmaxf(a + bias[lbase + 2 * q], 0.f);
            b = fmaxf(b + bias[lbase + 2 * q + 1], 0.f);
        }
        o[q] = packbf(a, b);
    }
    unsigned int* po = (unsigned int*)(outp + (size_t)w * C + lbase);
    if constexpr (NW == 4)      { *(uint4*)po = make_uint4(o[0], o[1], o[2], o[3]); }
    else if constexpr (NW == 2) { *(uint2*)po = make_uint2(o[0], o[1]); }
    else                        { *po = o[0]; }
}

template <int C>
__global__ __launch_bounds__(256) void seg_edge_t(const unsigned short* __restrict__ xl,
                                                  const int* __restrict__ eoff,
                                                  const int* __restrict__ edeg,
                                                  const int* __restrict__ csr_src,
                                                  unsigned short* __restrict__ ef) {
    seg_body<C, false>(xl, eoff, edeg, csr_src, nullptr, ef, N_EDGES);
}

template <int C, bool BIAS>
__global__ __launch_bounds__(256) void seg_node_t(const unsigned short* __restrict__ ef,
                                                  const int* __restrict__ noff,
                                                  const int* __restrict__ ndeg,
                                                  const int* __restrict__ csr_src,
                                                  const float* __restrict__ bias,
                                                  unsigned short* __restrict__ hout) {
    seg_body<C, BIAS>(ef, noff, ndeg, csr_src, bias, hout, N_NODES);
}

// ---------------- fused mean pool + MLP head (one block per graph) ----------------
__global__ __launch_bounds__(256) void pool_head_kernel(const unsigned short* __restrict__ h,
                                                        const int* __restrict__ goff,
                                                        const int* __restrict__ gcnt,
                                                        const float* __restrict__ Wl1,
                                                        const float* __restrict__ bl1,
                                                        const float* __restrict__ Wl2,
                                                        const float* __restrict__ bl2,
                                                        float* __restrict__ out) {
    __shared__ float xs[256];
    __shared__ float red[128];
    int g = blockIdx.x, t = threadIdx.x;
    int s = goff[g], cnt = gcnt[g];
    float acc = 0.f;
    for (int i = 0; i < cnt; ++i) {
        unsigned int u = h[(size_t)(s + i) * 256 + t];
        acc += __builtin_bit_cast(float, u << 16);
    }
    xs[t] = acc / (float)(cnt > 0 ? cnt : 1);
    __syncthreads();
    if (t < 128) {
        float s2 = 0.f;
        for (int f = 0; f < 256; ++f) s2 += xs[f] * Wl1[f * 128 + t];
        s2 = fmaxf(s2 + bl1[t], 0.f);
        red[t] = s2 * Wl2[t];
    }
    __syncthreads();
    for (int off = 64; off > 0; off >>= 1) {
        if (t < off) red[t] += red[t + off];
        __syncthreads();
    }
    if (t == 0) out[g] = red[0] + bl2[0];
}

extern "C" void kernel_launch(void* const* d_in, const int* in_sizes, int n_in,
                              void* d_out, int out_size, void* d_ws, size_t ws_size,
                              hipStream_t stream) {
    const float* x     = (const float*)d_in[0];
    const int* hei     = (const int*)d_in[1];
    const int* braw    = (const int*)d_in[2];
    const float* W1    = (const float*)d_in[3];
    const float* b1    = (const float*)d_in[4];
    const float* W2    = (const float*)d_in[5];
    const float* b2    = (const float*)d_in[6];
    const float* W3    = (const float*)d_in[7];
    const float* b3    = (const float*)d_in[8];
    const float* Wl1   = (const float*)d_in[9];
    const float* bl1   = (const float*)d_in[10];
    const float* Wl2   = (const float*)d_in[11];
    const float* bl2   = (const float*)d_in[12];
    float* out         = (float*)d_out;

    char* w = (char*)d_ws;
    size_t off = 0;
    auto alloc = [&](size_t bytes) { size_t p = off; off += (bytes + 255) & ~(size_t)255; return p; };
    // zeroed region first: padded histograms
    size_t o_edeg = alloc((size_t)SEG_CAP * 4);
    size_t o_ndeg = alloc((size_t)SEG_CAP * 4);
    size_t o_gcnt = alloc((size_t)1024 * 4);
    size_t zero_end = off;
    size_t o_eoff = alloc((size_t)SEG_CAP * 4);
    size_t o_noff = alloc((size_t)SEG_CAP * 4);
    size_t o_goff = alloc((size_t)1024 * 4);
    size_t o_ecur = alloc((size_t)SEG_CAP * 4);
    size_t o_ncur = alloc((size_t)SEG_CAP * 4);
    size_t o_part = alloc(128 * 4);
    size_t o_nidx = alloc((size_t)N_INC * 4);
    size_t o_eidx = alloc((size_t)N_INC * 4);
    size_t o_bidx = alloc((size_t)N_NODES * 4);
    size_t o_csre = alloc((size_t)N_INC * 4);
    size_t o_csrn = alloc((size_t)N_INC * 4);
    size_t o_wt1  = alloc((size_t)128 * 256 * 2);
    size_t o_wt2  = alloc((size_t)256 * 512 * 2);
    size_t o_wt3  = alloc((size_t)512 * 256 * 2);
    size_t o_xbf  = alloc((size_t)M_PAD * 128 * 2);
    size_t o_Y    = alloc((size_t)M_PAD * 256 * 2);
    size_t o_H1   = alloc((size_t)M_PAD * 256 * 2);
    size_t o_H2   = alloc((size_t)M_PAD * 512 * 2);
    size_t o_bufE = alloc((size_t)N_EDGES * 256 * 2);

    int* edeg = (int*)(w + o_edeg);
    int* ndeg = (int*)(w + o_ndeg);
    int* gcnt = (int*)(w + o_gcnt);
    int* eoff = (int*)(w + o_eoff);
    int* noff = (int*)(w + o_noff);
    int* goff = (int*)(w + o_goff);
    int* ecur = (int*)(w + o_ecur);
    int* ncur = (int*)(w + o_ncur);
    int* part = (int*)(w + o_part);
    int* nidx = (int*)(w + o_nidx);
    int* eidx = (int*)(w + o_eidx);
    int* bidx = (int*)(w + o_bidx);
    int* csre = (int*)(w + o_csre);
    int* csrn = (int*)(w + o_csrn);
    unsigned short* wt1  = (unsigned short*)(w + o_wt1);
    unsigned short* wt2  = (unsigned short*)(w + o_wt2);
    unsigned short* wt3  = (unsigned short*)(w + o_wt3);
    unsigned short* xbf  = (unsigned short*)(w + o_xbf);
    unsigned short* Y    = (unsigned short*)(w + o_Y);
    unsigned short* H1   = (unsigned short*)(w + o_H1);
    unsigned short* H2   = (unsigned short*)(w + o_H2);
    unsigned short* bufE = (unsigned short*)(w + o_bufE);

    hipMemsetAsync(w, 0, zero_end, stream);
    normhist_kernel<<<(N_INC + 255) / 256, 256, 0, stream>>>(hei, braw, nidx, eidx, bidx,
                                                             ndeg, edeg, gcnt);
    scan_up_f<<<99, 256, 0, stream>>>(edeg, ndeg, gcnt, eoff, noff, goff, part);
    scan_mid_f<<<1, 128, 0, stream>>>(part);
    scan_down_f<<<99, 256, 0, stream>>>(eoff, ecur, noff, ncur, goff, part);
    prep_kernel<<<NB_CSR + NB_CONV + NB_W1 + NB_W2 + NB_W3, 256, 0, stream>>>(
        nidx, eidx, ecur, ncur, csre, csrn, x, xbf, W1, wt1, W2, wt2, W3, wt3);

    int segGrid = (N_NODES * 64 + 255) / 256;

    // ---- layer 1 (aggregate-first at 128)
    seg_edge_t<128><<<segGrid, 256, 0, stream>>>(xbf, eoff, edeg, csre, bufE);
    seg_node_t<128, false><<<segGrid, 256, 0, stream>>>(bufE, noff, ndeg, csrn, nullptr, Y);
    {
        dim3 grid(256 / 128, M_PAD / 128);
        gemm128_kernel<true><<<grid, 256, 0, stream>>>(Y, wt1, b1, H1, N_NODES, 128, 256);
    }
    // ---- layer 2 (aggregate-first at 256)
    seg_edge_t<256><<<segGrid, 256, 0, stream>>>(H1, eoff, edeg, csre, bufE);
    seg_node_t<256, false><<<segGrid, 256, 0, stream>>>(bufE, noff, ndeg, csrn, nullptr, Y);
    {
        dim3 grid(512 / 128, M_PAD / 128);
        gemm128_kernel<true><<<grid, 256, 0, stream>>>(Y, wt2, b2, H2, N_NODES, 256, 512);
    }
    // ---- layer 3 (gemm-first at 256)
    {
        dim3 grid(256 / 128, M_PAD / 128);
        gemm128_kernel<false><<<grid, 256, 0, stream>>>(H2, wt3, nullptr, Y, N_NODES, 512, 256);
    }
    seg_edge_t<256><<<segGrid, 256, 0, stream>>>(Y, eoff, edeg, csre, bufE);
    seg_node_t<256, true><<<segGrid, 256, 0, stream>>>(bufE, noff, ndeg, csrn, b3, H1);

    pool_head_kernel<<<N_GRAPHS, 256, 0, stream>>>(H1, goff, gcnt, Wl1, bl1, Wl2, bl2, out);
}

// Round 9
// 442.313 us; speedup vs baseline: 2.4911x; 1.0457x over previous
//
#include <hip/hip_runtime.h>
#include <hip/hip_bf16.h>

#define N_NODES  50000
#define N_EDGES  50000
#define N_INC    400000
#define N_GRAPHS 1024
#define M_PAD    50048          // 391 * 128
#define SEG_CAP  50176          // 49 * 1024 (scan padding)

typedef __bf16 bf16x8 __attribute__((ext_vector_type(8)));
typedef float  f32x4  __attribute__((ext_vector_type(4)));

__device__ __forceinline__ unsigned short f2bf(float f) {
    __hip_bfloat16 h = __float2bfloat16(f);
    return __builtin_bit_cast(unsigned short, h);
}
__device__ __forceinline__ float bflo(unsigned int u) {
    return __builtin_bit_cast(float, u << 16);
}
__device__ __forceinline__ float bfhi(unsigned int u) {
    return __builtin_bit_cast(float, u & 0xffff0000u);
}
__device__ __forceinline__ unsigned int packbf(float a, float b) {
    return (unsigned int)f2bf(a) | ((unsigned int)f2bf(b) << 16);
}
__device__ __forceinline__ void load_lds16(const unsigned short* g, unsigned short* l) {
    __builtin_amdgcn_global_load_lds((const __attribute__((address_space(1))) void*)g,
                                     (__attribute__((address_space(3))) void*)l, 16, 0, 0);
}

// -------- normalize indices + histograms (atomic returns = within-segment rank) ----
__global__ __launch_bounds__(256) void normhist_kernel(const int* __restrict__ hei,
                                                       const int* __restrict__ braw,
                                                       int* __restrict__ nidx, int* __restrict__ eidx,
                                                       unsigned short* __restrict__ rn,
                                                       unsigned short* __restrict__ re,
                                                       int* __restrict__ ndeg, int* __restrict__ edeg,
                                                       int* __restrict__ gcnt,
                                                       int* __restrict__ goff_src) {
    __shared__ int s32;
    int t = threadIdx.x;
    if (t == 0) s32 = 0;
    __syncthreads();
    int probe = hei[4 * t + 1] | hei[4 * t + 3];   // int64 layout => odd words zero
    if (probe) s32 = 1;
    __syncthreads();
    int is32 = s32;
    int i = blockIdx.x * 256 + t;
    if (i < N_INC) {
        int n, e;
        if (is32) { n = hei[i];     e = hei[N_INC + i]; }
        else      { n = hei[2 * i]; e = hei[2 * N_INC + 2 * i]; }
        nidx[i] = n; eidx[i] = e;
        rn[i] = (unsigned short)atomicAdd(&ndeg[n], 1);
        re[i] = (unsigned short)atomicAdd(&edeg[e], 1);
    }
    if (i < N_NODES) {
        int b = is32 ? braw[i] : braw[2 * i];
        (void)goff_src;
        atomicAdd(&gcnt[b], 1);
    }
}

// ---------------- fused segmented hierarchical scan (edeg | ndeg | gcnt) ----------
__global__ __launch_bounds__(256) void scan_up_f(const int* __restrict__ edeg,
                                                 const int* __restrict__ ndeg,
                                                 const int* __restrict__ gcnt,
                                                 int* __restrict__ eoff, int* __restrict__ noff,
                                                 int* __restrict__ goff,
                                                 int* __restrict__ partials) {
    __shared__ int lds[256];
    int b = blockIdx.x, t = threadIdx.x;
    const int* in; int* outp; int lb;
    if (b < 49)      { in = edeg; outp = eoff; lb = b; }
    else if (b < 98) { in = ndeg; outp = noff; lb = b - 49; }
    else             { in = gcnt; outp = goff; lb = 0; }
    int base = lb * 1024 + t * 4;
    int4 v = *(const int4*)(in + base);
    int s = v.x + v.y + v.z + v.w;
    lds[t] = s;
    __syncthreads();
    for (int off = 1; off < 256; off <<= 1) {
        int u = (t >= off) ? lds[t - off] : 0;
        __syncthreads();
        lds[t] += u;
        __syncthreads();
    }
    int excl = lds[t] - s;
    if (t == 255) partials[b] = lds[255];
    int4 o;
    o.x = excl;
    o.y = excl + v.x;
    o.z = o.y + v.y;
    o.w = o.z + v.z;
    *(int4*)(outp + base) = o;
}

__global__ __launch_bounds__(128) void scan_mid_f(int* __restrict__ partials) {
    __shared__ int lds[99];
    int t = threadIdx.x;
    if (t < 99) lds[t] = partials[t];
    __syncthreads();
    if (t < 3) {
        int lo = (t == 0) ? 0 : (t == 1 ? 49 : 98);
        int hi = (t == 0) ? 49 : (t == 1 ? 98 : 99);
        int run = 0;
        for (int i = lo; i < hi; ++i) { int x = lds[i]; lds[i] = run; run += x; }
    }
    __syncthreads();
    if (t < 99) partials[t] = lds[t];
}

__global__ __launch_bounds__(256) void scan_down_f(int* __restrict__ eoff,
                                                   int* __restrict__ noff,
                                                   int* __restrict__ goff,
                                                   const int* __restrict__ partials) {
    int b = blockIdx.x, t = threadIdx.x;
    int* outp; int lb;
    if (b < 49)      { outp = eoff; lb = b; }
    else if (b < 98) { outp = noff; lb = b - 49; }
    else             { outp = goff; lb = 0; }
    int base = lb * 1024 + t * 4;
    int p = partials[b];
    int4 v = *(const int4*)(outp + base);
    v.x += p; v.y += p; v.z += p; v.w += p;
    *(int4*)(outp + base) = v;
}

// -------- mega prep: atomic-free CSR scatter + x->bf16 + 3 weight transposes ------
#define NB_CSR  1563
#define NB_CONV 6250
#define NB_W1   128
#define NB_W2   512
#define NB_W3   512
__global__ __launch_bounds__(256) void prep_kernel(const int* __restrict__ nidx,
                                                   const int* __restrict__ eidx,
                                                   const unsigned short* __restrict__ rn,
                                                   const unsigned short* __restrict__ re,
                                                   const int* __restrict__ eoff,
                                                   const int* __restrict__ noff,
                                                   unsigned short* __restrict__ csre,
                                                   unsigned short* __restrict__ csrn,
                                                   const float* __restrict__ x,
                                                   unsigned short* __restrict__ xbf,
                                                   const float* __restrict__ W1, unsigned short* __restrict__ wt1,
                                                   const float* __restrict__ W2, unsigned short* __restrict__ wt2,
                                                   const float* __restrict__ W3, unsigned short* __restrict__ wt3) {
    int b = blockIdx.x, t = threadIdx.x;
    if (b < NB_CSR) {
        int i = b * 256 + t;
        if (i < N_INC) {
            int n = nidx[i], e = eidx[i];
            csre[eoff[e] + re[i]] = (unsigned short)n;
            csrn[noff[n] + rn[i]] = (unsigned short)e;
        }
    } else if (b < NB_CSR + NB_CONV) {
        int i = (b - NB_CSR) * 256 + t;
        float4 v = *(const float4*)(x + 4 * (size_t)i);
        ushort4 o;
        o.x = f2bf(v.x); o.y = f2bf(v.y); o.z = f2bf(v.z); o.w = f2bf(v.w);
        *(ushort4*)(xbf + 4 * (size_t)i) = o;
    } else if (b < NB_CSR + NB_CONV + NB_W1) {
        int i = (b - NB_CSR - NB_CONV) * 256 + t;
        int k = i >> 8, n = i & 255;
        wt1[n * 128 + k] = f2bf(W1[i]);
    } else if (b < NB_CSR + NB_CONV + NB_W1 + NB_W2) {
        int i = (b - NB_CSR - NB_CONV - NB_W1) * 256 + t;
        int k = i >> 9, n = i & 511;
        wt2[n * 256 + k] = f2bf(W2[i]);
    } else {
        int i = (b - NB_CSR - NB_CONV - NB_W1 - NB_W2) * 256 + t;
        int k = i >> 8, n = i & 255;
        wt3[n * 512 + k] = f2bf(W3[i]);
    }
}

// ---------------- 128x128 MFMA GEMM (m97 pattern) + LDS-staged epilogue ----------
template <bool EPI>
__global__ __launch_bounds__(256) void gemm128_kernel(const unsigned short* __restrict__ A,
                                                      const unsigned short* __restrict__ Bt,
                                                      const float* __restrict__ bias,
                                                      unsigned short* __restrict__ C,
                                                      int M, int K, int N) {
    __shared__ unsigned short As[128 * 32];
    __shared__ unsigned short Bs[128 * 32];
    __shared__ unsigned short Cs[32][140];
    int tid  = threadIdx.x;
    int wave = tid >> 6, lane = tid & 63;
    int n0 = blockIdx.x * 128, m0 = blockIdx.y * 128;
    int quad = lane >> 4, fr = lane & 15;
    int wr = wave >> 1, wc = wave & 1;
    int lrow16 = lane >> 2;
    int lchunk = (lane & 3) * 8;

    const unsigned short* gsrc;
    unsigned short* ldst;
    if (wave < 2) { gsrc = A  + (size_t)(m0 + wave * 64) * K;       ldst = As + wave * 64 * 32; }
    else          { gsrc = Bt + (size_t)(n0 + (wave - 2) * 64) * K; ldst = Bs + (wave - 2) * 64 * 32; }

    f32x4 acc[4][4];
#pragma unroll
    for (int s = 0; s < 4; ++s)
#pragma unroll
        for (int c = 0; c < 4; ++c) acc[s][c] = (f32x4){0.f, 0.f, 0.f, 0.f};

    for (int k0 = 0; k0 < K; k0 += 32) {
#pragma unroll
        for (int l = 0; l < 4; ++l) {
            const unsigned short* g = gsrc + (size_t)(l * 16 + lrow16) * K + k0 + lchunk;
            load_lds16(g, ldst + l * 16 * 32);
        }
        __syncthreads();
        bf16x8 af[4], bfr[4];
#pragma unroll
        for (int s = 0; s < 4; ++s)
            af[s] = *(const bf16x8*)&As[(wr * 64 + s * 16 + fr) * 32 + quad * 8];
#pragma unroll
        for (int c = 0; c < 4; ++c)
            bfr[c] = *(const bf16x8*)&Bs[(wc * 64 + c * 16 + fr) * 32 + quad * 8];
#pragma unroll
        for (int s = 0; s < 4; ++s)
#pragma unroll
            for (int c = 0; c < 4; ++c)
                acc[s][c] = __builtin_amdgcn_mfma_f32_16x16x32_bf16(af[s], bfr[c], acc[s][c], 0, 0, 0);
        __syncthreads();
    }

    float bv[4];
#pragma unroll
    for (int c = 0; c < 4; ++c) bv[c] = EPI ? bias[n0 + wc * 64 + c * 16 + fr] : 0.f;
#pragma unroll
    for (int s = 0; s < 4; ++s) {
#pragma unroll
        for (int c = 0; c < 4; ++c)
#pragma unroll
            for (int r = 0; r < 4; ++r) {
                float v = acc[s][c][r];
                if (EPI) v = fmaxf(v + bv[c], 0.f);
                Cs[wr * 16 + quad * 4 + r][wc * 64 + c * 16 + fr] = f2bf(v);
            }
        __syncthreads();
#pragma unroll
        for (int i = 0; i < 2; ++i) {
            int rl  = i * 16 + (tid >> 4);
            int col = (tid & 15) * 8;
            int gm  = m0 + (rl >> 4) * 64 + s * 16 + (rl & 15);
            if (gm < M) {
                uint4 v = *(const uint4*)&Cs[rl][col];
                *(uint4*)&C[(size_t)gm * N + n0 + col] = v;
            }
        }
        __syncthreads();
    }
}

// -------- segment-mean gather: 8x batch, barrier-enforced MLP, ushort CSR ---------
template <int C, bool BIAS>
__device__ __forceinline__ void seg_body(const unsigned short* __restrict__ in,
                                         const int* __restrict__ offs,
                                         const int* __restrict__ degs,
                                         const unsigned short* __restrict__ csr_src,
                                         const float* __restrict__ bias,
                                         unsigned short* __restrict__ outp,
                                         int nseg) {
    constexpr int VEC = C / 64;
    constexpr int NW  = VEC / 2;
    int w = (blockIdx.x * 256 + threadIdx.x) >> 6;   // one wave per segment
    int lane = threadIdx.x & 63;
    if (w >= nseg) return;
    int deg   = __builtin_amdgcn_readfirstlane(degs[w]);
    int start = __builtin_amdgcn_readfirstlane(offs[w]);
    float dinv = (deg > 0) ? 1.0f / (float)deg : 0.0f;
    const unsigned short* cs = csr_src + start;
    float acc[VEC];
#pragma unroll
    for (int q = 0; q < VEC; ++q) acc[q] = 0.f;
    size_t lbase = (size_t)lane * VEC;

    auto accum = [&](unsigned int* v) {
#pragma unroll
        for (int q = 0; q < NW; ++q) { acc[2 * q] += bflo(v[q]); acc[2 * q + 1] += bfhi(v[q]); }
    };
    auto loadrow = [&](int src, unsigned int* v) {
        const unsigned int* p = (const unsigned int*)(in + (size_t)src * C + lbase);
        if constexpr (NW == 4)      { uint4 t = *(const uint4*)p; v[0] = t.x; v[1] = t.y; v[2] = t.z; v[3] = t.w; }
        else if constexpr (NW == 2) { uint2 t = *(const uint2*)p; v[0] = t.x; v[1] = t.y; }
        else                        { v[0] = *p; }
    };

    int j = 0;
    for (; j + 8 <= deg; j += 8) {
        int s[8];
        unsigned int v[8][NW];
#pragma unroll
        for (int u = 0; u < 8; ++u) s[u] = __builtin_amdgcn_readfirstlane((int)cs[j + u]);
#pragma unroll
        for (int u = 0; u < 8; ++u) loadrow(s[u], v[u]);
        __asm__ __volatile__("" ::: "memory");   // keep all 8 loads in flight
#pragma unroll
        for (int u = 0; u < 8; ++u) accum(v[u]);
    }
    for (; j + 4 <= deg; j += 4) {
        int s[4];
        unsigned int v[4][NW];
#pragma unroll
        for (int u = 0; u < 4; ++u) s[u] = __builtin_amdgcn_readfirstlane((int)cs[j + u]);
#pragma unroll
        for (int u = 0; u < 4; ++u) loadrow(s[u], v[u]);
        __asm__ __volatile__("" ::: "memory");
#pragma unroll
        for (int u = 0; u < 4; ++u) accum(v[u]);
    }
    for (; j < deg; ++j) {
        int s0 = __builtin_amdgcn_readfirstlane((int)cs[j]);
        unsigned int v0[NW];
        loadrow(s0, v0);
        accum(v0);
    }

    unsigned int o[NW];
#pragma unroll
    for (int q = 0; q < NW; ++q) {
        float a = acc[2 * q] * dinv;
        float b = acc[2 * q + 1] * dinv;
        if constexpr (BIAS) {
            a = fmaxf(a + bias[lbase + 2 * q], 0.f);
            b = fmaxf(b + bias[lbase + 2 * q + 1], 0.f);
        }
        o[q] = packbf(a, b);
    }
    unsigned int* po = (unsigned int*)(outp + (size_t)w * C + lbase);
    if constexpr (NW == 4)      { *(uint4*)po = make_uint4(o[0], o[1], o[2], o[3]); }
    else if constexpr (NW == 2) { *(uint2*)po = make_uint2(o[0], o[1]); }
    else                        { *po = o[0]; }
}

template <int C>
__global__ __launch_bounds__(256) void seg_edge_t(const unsigned short* __restrict__ xl,
                                                  const int* __restrict__ eoff,
                                                  const int* __restrict__ edeg,
                                                  const unsigned short* __restrict__ csr_src,
                                                  unsigned short* __restrict__ ef) {
    seg_body<C, false>(xl, eoff, edeg, csr_src, nullptr, ef, N_EDGES);
}

template <int C, bool BIAS>
__global__ __launch_bounds__(256) void seg_node_t(const unsigned short* __restrict__ ef,
                                                  const int* __restrict__ noff,
                                                  const int* __restrict__ ndeg,
                                                  const unsigned short* __restrict__ csr_src,
                                                  const float* __restrict__ bias,
                                                  unsigned short* __restrict__ hout) {
    seg_body<C, BIAS>(ef, noff, ndeg, csr_src, bias, hout, N_NODES);
}

// ---------------- fused mean pool + MLP head (one block per graph) ----------------
__global__ __launch_bounds__(256) void pool_head_kernel(const unsigned short* __restrict__ h,
                                                        const int* __restrict__ goff,
                                                        const int* __restrict__ gcnt,
                                                        const float* __restrict__ Wl1,
                                                        const float* __restrict__ bl1,
                                                        const float* __restrict__ Wl2,
                                                        const float* __restrict__ bl2,
                                                        float* __restrict__ out) {
    __shared__ float xs[256];
    __shared__ float red[128];
    int g = blockIdx.x, t = threadIdx.x;
    int s = goff[g], cnt = gcnt[g];
    float acc = 0.f;
    for (int i = 0; i < cnt; ++i) {
        unsigned int u = h[(size_t)(s + i) * 256 + t];
        acc += __builtin_bit_cast(float, u << 16);
    }
    xs[t] = acc / (float)(cnt > 0 ? cnt : 1);
    __syncthreads();
    if (t < 128) {
        float s2 = 0.f;
        for (int f = 0; f < 256; ++f) s2 += xs[f] * Wl1[f * 128 + t];
        s2 = fmaxf(s2 + bl1[t], 0.f);
        red[t] = s2 * Wl2[t];
    }
    __syncthreads();
    for (int off = 64; off > 0; off >>= 1) {
        if (t < off) red[t] += red[t + off];
        __syncthreads();
    }
    if (t == 0) out[g] = red[0] + bl2[0];
}

extern "C" void kernel_launch(void* const* d_in, const int* in_sizes, int n_in,
                              void* d_out, int out_size, void* d_ws, size_t ws_size,
                              hipStream_t stream) {
    const float* x     = (const float*)d_in[0];
    const int* hei     = (const int*)d_in[1];
    const int* braw    = (const int*)d_in[2];
    const float* W1    = (const float*)d_in[3];
    const float* b1    = (const float*)d_in[4];
    const float* W2    = (const float*)d_in[5];
    const float* b2    = (const float*)d_in[6];
    const float* W3    = (const float*)d_in[7];
    const float* b3    = (const float*)d_in[8];
    const float* Wl1   = (const float*)d_in[9];
    const float* bl1   = (const float*)d_in[10];
    const float* Wl2   = (const float*)d_in[11];
    const float* bl2   = (const float*)d_in[12];
    float* out         = (float*)d_out;

    char* w = (char*)d_ws;
    size_t off = 0;
    auto alloc = [&](size_t bytes) { size_t p = off; off += (bytes + 255) & ~(size_t)255; return p; };
    size_t o_edeg = alloc((size_t)SEG_CAP * 4);
    size_t o_ndeg = alloc((size_t)SEG_CAP * 4);
    size_t o_gcnt = alloc((size_t)1024 * 4);
    size_t zero_end = off;
    size_t o_eoff = alloc((size_t)SEG_CAP * 4);
    size_t o_noff = alloc((size_t)SEG_CAP * 4);
    size_t o_goff = alloc((size_t)1024 * 4);
    size_t o_part = alloc(128 * 4);
    size_t o_nidx = alloc((size_t)N_INC * 4);
    size_t o_eidx = alloc((size_t)N_INC * 4);
    size_t o_rn   = alloc((size_t)N_INC * 2);
    size_t o_re   = alloc((size_t)N_INC * 2);
    size_t o_csre = alloc((size_t)N_INC * 2);
    size_t o_csrn = alloc((size_t)N_INC * 2);
    size_t o_wt1  = alloc((size_t)128 * 256 * 2);
    size_t o_wt2  = alloc((size_t)256 * 512 * 2);
    size_t o_wt3  = alloc((size_t)512 * 256 * 2);
    size_t o_xbf  = alloc((size_t)M_PAD * 128 * 2);
    size_t o_Y    = alloc((size_t)M_PAD * 256 * 2);
    size_t o_H1   = alloc((size_t)M_PAD * 256 * 2);
    size_t o_H2   = alloc((size_t)M_PAD * 512 * 2);
    size_t o_bufE = alloc((size_t)N_EDGES * 256 * 2);

    int* edeg = (int*)(w + o_edeg);
    int* ndeg = (int*)(w + o_ndeg);
    int* gcnt = (int*)(w + o_gcnt);
    int* eoff = (int*)(w + o_eoff);
    int* noff = (int*)(w + o_noff);
    int* goff = (int*)(w + o_goff);
    int* part = (int*)(w + o_part);
    int* nidx = (int*)(w + o_nidx);
    int* eidx = (int*)(w + o_eidx);
    unsigned short* rn   = (unsigned short*)(w + o_rn);
    unsigned short* re   = (unsigned short*)(w + o_re);
    unsigned short* csre = (unsigned short*)(w + o_csre);
    unsigned short* csrn = (unsigned short*)(w + o_csrn);
    unsigned short* wt1  = (unsigned short*)(w + o_wt1);
    unsigned short* wt2  = (unsigned short*)(w + o_wt2);
    unsigned short* wt3  = (unsigned short*)(w + o_wt3);
    unsigned short* xbf  = (unsigned short*)(w + o_xbf);
    unsigned short* Y    = (unsigned short*)(w + o_Y);
    unsigned short* H1   = (unsigned short*)(w + o_H1);
    unsigned short* H2   = (unsigned short*)(w + o_H2);
    unsigned short* bufE = (unsigned short*)(w + o_bufE);

    hipMemsetAsync(w, 0, zero_end, stream);
    normhist_kernel<<<(N_INC + 255) / 256, 256, 0, stream>>>(hei, braw, nidx, eidx, rn, re,
                                                             ndeg, edeg, gcnt, goff);
    scan_up_f<<<99, 256, 0, stream>>>(edeg, ndeg, gcnt, eoff, noff, goff, part);
    scan_mid_f<<<1, 128, 0, stream>>>(part);
    scan_down_f<<<99, 256, 0, stream>>>(eoff, noff, goff, part);
    prep_kernel<<<NB_CSR + NB_CONV + NB_W1 + NB_W2 + NB_W3, 256, 0, stream>>>(
        nidx, eidx, rn, re, eoff, noff, csre, csrn, x, xbf, W1, wt1, W2, wt2, W3, wt3);

    int segGrid = (N_NODES * 64 + 255) / 256;

    // ---- layer 1 (aggregate-first at 128)
    seg_edge_t<128><<<segGrid, 256, 0, stream>>>(xbf, eoff, edeg, csre, bufE);
    seg_node_t<128, false><<<segGrid, 256, 0, stream>>>(bufE, noff, ndeg, csrn, nullptr, Y);
    {
        dim3 grid(256 / 128, M_PAD / 128);
        gemm128_kernel<true><<<grid, 256, 0, stream>>>(Y, wt1, b1, H1, N_NODES, 128, 256);
    }
    // ---- layer 2 (aggregate-first at 256)
    seg_edge_t<256><<<segGrid, 256, 0, stream>>>(H1, eoff, edeg, csre, bufE);
    seg_node_t<256, false><<<segGrid, 256, 0, stream>>>(bufE, noff, ndeg, csrn, nullptr, Y);
    {
        dim3 grid(512 / 128, M_PAD / 128);
        gemm128_kernel<true><<<grid, 256, 0, stream>>>(Y, wt2, b2, H2, N_NODES, 256, 512);
    }
    // ---- layer 3 (gemm-first at 256)
    {
        dim3 grid(256 / 128, M_PAD / 128);
        gemm128_kernel<false><<<grid, 256, 0, stream>>>(H2, wt3, nullptr, Y, N_NODES, 512, 256);
    }
    seg_edge_t<256><<<segGrid, 256, 0, stream>>>(Y, eoff, edeg, csre, bufE);
    seg_node_t<256, true><<<segGrid, 256, 0, stream>>>(bufE, noff, ndeg, csrn, b3, H1);

    pool_head_kernel<<<N_GRAPHS, 256, 0, stream>>>(H1, goff, gcnt, Wl1, bl1, Wl2, bl2, out);
}

// Round 10
// 429.238 us; speedup vs baseline: 2.5670x; 1.0305x over previous
//
#include <hip/hip_runtime.h>
#include <hip/hip_bf16.h>

#define N_NODES  50000
#define N_EDGES  50000
#define N_INC    400000
#define N_GRAPHS 1024
#define M_PAD    50048          // 391 * 128
#define SEG_CAP  50176          // 49 * 1024 (scan padding)

typedef __bf16 bf16x8 __attribute__((ext_vector_type(8)));
typedef float  f32x4  __attribute__((ext_vector_type(4)));

__device__ __forceinline__ unsigned short f2bf(float f) {
    __hip_bfloat16 h = __float2bfloat16(f);
    return __builtin_bit_cast(unsigned short, h);
}
__device__ __forceinline__ float bflo(unsigned int u) {
    return __builtin_bit_cast(float, u << 16);
}
__device__ __forceinline__ float bfhi(unsigned int u) {
    return __builtin_bit_cast(float, u & 0xffff0000u);
}
__device__ __forceinline__ unsigned int packbf(float a, float b) {
    return (unsigned int)f2bf(a) | ((unsigned int)f2bf(b) << 16);
}
__device__ __forceinline__ void load_lds16(const unsigned short* g, unsigned short* l) {
    __builtin_amdgcn_global_load_lds((const __attribute__((address_space(1))) void*)g,
                                     (__attribute__((address_space(3))) void*)l, 16, 0, 0);
}

// ---- mega normhist: incidence hist (padded counters) + x->bf16 + weight transposes
// Counters padded to 1 int per 64B line: deg_pad[seg*16].
#define NB_INC  1563
#define NB_CONV 6250
#define NB_W1   128
#define NB_W2   512
#define NB_W3   512
__global__ __launch_bounds__(256) void normhist_kernel(const int* __restrict__ hei,
                                                       int* __restrict__ nidx, int* __restrict__ eidx,
                                                       unsigned short* __restrict__ rn,
                                                       unsigned short* __restrict__ re,
                                                       int* __restrict__ ndeg_p, int* __restrict__ edeg_p,
                                                       const float* __restrict__ x,
                                                       unsigned short* __restrict__ xbf,
                                                       const float* __restrict__ W1, unsigned short* __restrict__ wt1,
                                                       const float* __restrict__ W2, unsigned short* __restrict__ wt2,
                                                       const float* __restrict__ W3, unsigned short* __restrict__ wt3) {
    int b = blockIdx.x, t = threadIdx.x;
    if (b < NB_INC) {
        __shared__ int s32;
        if (t == 0) s32 = 0;
        __syncthreads();
        int probe = hei[4 * t + 1] | hei[4 * t + 3];   // int64 layout => odd words zero
        if (probe) s32 = 1;
        __syncthreads();
        int is32 = s32;
        int i = b * 256 + t;
        if (i < N_INC) {
            int n, e;
            if (is32) { n = hei[i];     e = hei[N_INC + i]; }
            else      { n = hei[2 * i]; e = hei[2 * N_INC + 2 * i]; }
            nidx[i] = n; eidx[i] = e;
            rn[i] = (unsigned short)atomicAdd(&ndeg_p[n << 4], 1);
            re[i] = (unsigned short)atomicAdd(&edeg_p[e << 4], 1);
        }
    } else if (b < NB_INC + NB_CONV) {
        int i = (b - NB_INC) * 256 + t;
        float4 v = *(const float4*)(x + 4 * (size_t)i);
        ushort4 o;
        o.x = f2bf(v.x); o.y = f2bf(v.y); o.z = f2bf(v.z); o.w = f2bf(v.w);
        *(ushort4*)(xbf + 4 * (size_t)i) = o;
    } else if (b < NB_INC + NB_CONV + NB_W1) {
        int i = (b - NB_INC - NB_CONV) * 256 + t;
        int k = i >> 8, n = i & 255;
        wt1[n * 128 + k] = f2bf(W1[i]);
    } else if (b < NB_INC + NB_CONV + NB_W1 + NB_W2) {
        int i = (b - NB_INC - NB_CONV - NB_W1) * 256 + t;
        int k = i >> 9, n = i & 511;
        wt2[n * 256 + k] = f2bf(W2[i]);
    } else {
        int i = (b - NB_INC - NB_CONV - NB_W1 - NB_W2) * 256 + t;
        int k = i >> 8, n = i & 255;
        wt3[n * 512 + k] = f2bf(W3[i]);
    }
}

// ---- fused scan over padded degree arrays + goff via binary search on sorted batch
// blocks 0..48: edeg_p -> eoff ; 49..97: ndeg_p -> noff ; 98..101: goff binsearch
__global__ __launch_bounds__(256) void scan_up_f(const int* __restrict__ edeg_p,
                                                 const int* __restrict__ ndeg_p,
                                                 const int* __restrict__ hei,
                                                 const int* __restrict__ braw,
                                                 int* __restrict__ eoff, int* __restrict__ noff,
                                                 int* __restrict__ goff,
                                                 int* __restrict__ partials) {
    int b = blockIdx.x, t = threadIdx.x;
    if (b >= 98) {
        __shared__ int s32;
        if (t == 0) s32 = 0;
        __syncthreads();
        int probe = hei[4 * t + 1] | hei[4 * t + 3];
        if (probe) s32 = 1;
        __syncthreads();
        int is32 = s32;
        int g = (b - 98) * 256 + t;
        int lo = 0, hi = N_NODES;
        while (lo < hi) {
            int mid = (lo + hi) >> 1;
            int v = is32 ? braw[mid] : braw[2 * mid];
            if (v < g) lo = mid + 1; else hi = mid;
        }
        goff[g] = lo;
        if (g == 1023) goff[1024] = N_NODES;
        return;
    }
    __shared__ int lds[256];
    const int* in; int* outp; int lb;
    if (b < 49) { in = edeg_p; outp = eoff; lb = b; }
    else        { in = ndeg_p; outp = noff; lb = b - 49; }
    int base = lb * 1024 + t * 4;
    int4 v;
    v.x = in[(size_t)(base + 0) << 4];
    v.y = in[(size_t)(base + 1) << 4];
    v.z = in[(size_t)(base + 2) << 4];
    v.w = in[(size_t)(base + 3) << 4];
    int s = v.x + v.y + v.z + v.w;
    lds[t] = s;
    __syncthreads();
    for (int off = 1; off < 256; off <<= 1) {
        int u = (t >= off) ? lds[t - off] : 0;
        __syncthreads();
        lds[t] += u;
        __syncthreads();
    }
    int excl = lds[t] - s;
    if (t == 255) partials[b] = lds[255];
    int4 o;
    o.x = excl;
    o.y = excl + v.x;
    o.z = o.y + v.y;
    o.w = o.z + v.z;
    *(int4*)(outp + base) = o;
}

__global__ __launch_bounds__(128) void scan_mid_f(int* __restrict__ partials) {
    __shared__ int lds[98];
    int t = threadIdx.x;
    if (t < 98) lds[t] = partials[t];
    __syncthreads();
    if (t < 2) {
        int lo = t * 49, hi = lo + 49;
        int run = 0;
        for (int i = lo; i < hi; ++i) { int x = lds[i]; lds[i] = run; run += x; }
    }
    __syncthreads();
    if (t < 98) partials[t] = lds[t];
}

__global__ __launch_bounds__(256) void scan_down_f(int* __restrict__ eoff,
                                                   int* __restrict__ noff,
                                                   const int* __restrict__ partials) {
    int b = blockIdx.x, t = threadIdx.x;
    int* outp; int lb;
    if (b < 49) { outp = eoff; lb = b; }
    else        { outp = noff; lb = b - 49; }
    int base = lb * 1024 + t * 4;
    int p = partials[b];
    int4 v = *(const int4*)(outp + base);
    v.x += p; v.y += p; v.z += p; v.w += p;
    *(int4*)(outp + base) = v;
}

// ---------------- prep: atomic-free CSR scatter only ----------------
__global__ __launch_bounds__(256) void prep_kernel(const int* __restrict__ nidx,
                                                   const int* __restrict__ eidx,
                                                   const unsigned short* __restrict__ rn,
                                                   const unsigned short* __restrict__ re,
                                                   const int* __restrict__ eoff,
                                                   const int* __restrict__ noff,
                                                   unsigned short* __restrict__ csre,
                                                   unsigned short* __restrict__ csrn) {
    int i = blockIdx.x * 256 + threadIdx.x;
    if (i >= N_INC) return;
    int n = nidx[i], e = eidx[i];
    csre[eoff[e] + re[i]] = (unsigned short)n;
    csrn[noff[n] + rn[i]] = (unsigned short)e;
}

// ---------------- 128x128 MFMA GEMM (m97 pattern) + LDS-staged epilogue ----------
template <bool EPI>
__global__ __launch_bounds__(256) void gemm128_kernel(const unsigned short* __restrict__ A,
                                                      const unsigned short* __restrict__ Bt,
                                                      const float* __restrict__ bias,
                                                      unsigned short* __restrict__ C,
                                                      int M, int K, int N) {
    __shared__ unsigned short As[128 * 32];
    __shared__ unsigned short Bs[128 * 32];
    __shared__ unsigned short Cs[32][140];
    int tid  = threadIdx.x;
    int wave = tid >> 6, lane = tid & 63;
    int n0 = blockIdx.x * 128, m0 = blockIdx.y * 128;
    int quad = lane >> 4, fr = lane & 15;
    int wr = wave >> 1, wc = wave & 1;
    int lrow16 = lane >> 2;
    int lchunk = (lane & 3) * 8;

    const unsigned short* gsrc;
    unsigned short* ldst;
    if (wave < 2) { gsrc = A  + (size_t)(m0 + wave * 64) * K;       ldst = As + wave * 64 * 32; }
    else          { gsrc = Bt + (size_t)(n0 + (wave - 2) * 64) * K; ldst = Bs + (wave - 2) * 64 * 32; }

    f32x4 acc[4][4];
#pragma unroll
    for (int s = 0; s < 4; ++s)
#pragma unroll
        for (int c = 0; c < 4; ++c) acc[s][c] = (f32x4){0.f, 0.f, 0.f, 0.f};

    for (int k0 = 0; k0 < K; k0 += 32) {
#pragma unroll
        for (int l = 0; l < 4; ++l) {
            const unsigned short* g = gsrc + (size_t)(l * 16 + lrow16) * K + k0 + lchunk;
            load_lds16(g, ldst + l * 16 * 32);
        }
        __syncthreads();
        bf16x8 af[4], bfr[4];
#pragma unroll
        for (int s = 0; s < 4; ++s)
            af[s] = *(const bf16x8*)&As[(wr * 64 + s * 16 + fr) * 32 + quad * 8];
#pragma unroll
        for (int c = 0; c < 4; ++c)
            bfr[c] = *(const bf16x8*)&Bs[(wc * 64 + c * 16 + fr) * 32 + quad * 8];
#pragma unroll
        for (int s = 0; s < 4; ++s)
#pragma unroll
            for (int c = 0; c < 4; ++c)
                acc[s][c] = __builtin_amdgcn_mfma_f32_16x16x32_bf16(af[s], bfr[c], acc[s][c], 0, 0, 0);
        __syncthreads();
    }

    float bv[4];
#pragma unroll
    for (int c = 0; c < 4; ++c) bv[c] = EPI ? bias[n0 + wc * 64 + c * 16 + fr] : 0.f;
#pragma unroll
    for (int s = 0; s < 4; ++s) {
#pragma unroll
        for (int c = 0; c < 4; ++c)
#pragma unroll
            for (int r = 0; r < 4; ++r) {
                float v = acc[s][c][r];
                if (EPI) v = fmaxf(v + bv[c], 0.f);
                Cs[wr * 16 + quad * 4 + r][wc * 64 + c * 16 + fr] = f2bf(v);
            }
        __syncthreads();
#pragma unroll
        for (int i = 0; i < 2; ++i) {
            int rl  = i * 16 + (tid >> 4);
            int col = (tid & 15) * 8;
            int gm  = m0 + (rl >> 4) * 64 + s * 16 + (rl & 15);
            if (gm < M) {
                uint4 v = *(const uint4*)&Cs[rl][col];
                *(uint4*)&C[(size_t)gm * N + n0 + col] = v;
            }
        }
        __syncthreads();
    }
}

// -------- segment-mean gather: 8x batch, barrier-enforced MLP, padded deg ---------
template <int C, bool BIAS>
__device__ __forceinline__ void seg_body(const unsigned short* __restrict__ in,
                                         const int* __restrict__ offs,
                                         const int* __restrict__ degs_p,
                                         const unsigned short* __restrict__ csr_src,
                                         const float* __restrict__ bias,
                                         unsigned short* __restrict__ outp,
                                         int nseg) {
    constexpr int VEC = C / 64;
    constexpr int NW  = VEC / 2;
    int w = (blockIdx.x * 256 + threadIdx.x) >> 6;   // one wave per segment
    int lane = threadIdx.x & 63;
    if (w >= nseg) return;
    int deg   = __builtin_amdgcn_readfirstlane(degs_p[(size_t)w << 4]);
    int start = __builtin_amdgcn_readfirstlane(offs[w]);
    float dinv = (deg > 0) ? 1.0f / (float)deg : 0.0f;
    const unsigned short* cs = csr_src + start;
    float acc[VEC];
#pragma unroll
    for (int q = 0; q < VEC; ++q) acc[q] = 0.f;
    size_t lbase = (size_t)lane * VEC;

    auto accum = [&](unsigned int* v) {
#pragma unroll
        for (int q = 0; q < NW; ++q) { acc[2 * q] += bflo(v[q]); acc[2 * q + 1] += bfhi(v[q]); }
    };
    auto loadrow = [&](int src, unsigned int* v) {
        const unsigned int* p = (const unsigned int*)(in + (size_t)src * C + lbase);
        if constexpr (NW == 4)      { uint4 t = *(const uint4*)p; v[0] = t.x; v[1] = t.y; v[2] = t.z; v[3] = t.w; }
        else if constexpr (NW == 2) { uint2 t = *(const uint2*)p; v[0] = t.x; v[1] = t.y; }
        else                        { v[0] = *p; }
    };

    int j = 0;
    for (; j + 8 <= deg; j += 8) {
        int s[8];
        unsigned int v[8][NW];
#pragma unroll
        for (int u = 0; u < 8; ++u) s[u] = __builtin_amdgcn_readfirstlane((int)cs[j + u]);
#pragma unroll
        for (int u = 0; u < 8; ++u) loadrow(s[u], v[u]);
        __asm__ __volatile__("" ::: "memory");   // keep all 8 loads in flight
#pragma unroll
        for (int u = 0; u < 8; ++u) accum(v[u]);
    }
    for (; j + 4 <= deg; j += 4) {
        int s[4];
        unsigned int v[4][NW];
#pragma unroll
        for (int u = 0; u < 4; ++u) s[u] = __builtin_amdgcn_readfirstlane((int)cs[j + u]);
#pragma unroll
        for (int u = 0; u < 4; ++u) loadrow(s[u], v[u]);
        __asm__ __volatile__("" ::: "memory");
#pragma unroll
        for (int u = 0; u < 4; ++u) accum(v[u]);
    }
    for (; j < deg; ++j) {
        int s0 = __builtin_amdgcn_readfirstlane((int)cs[j]);
        unsigned int v0[NW];
        loadrow(s0, v0);
        accum(v0);
    }

    unsigned int o[NW];
#pragma unroll
    for (int q = 0; q < NW; ++q) {
        float a = acc[2 * q] * dinv;
        float b = acc[2 * q + 1] * dinv;
        if constexpr (BIAS) {
            a = fmaxf(a + bias[lbase + 2 * q], 0.f);
            b = fmaxf(b + bias[lbase + 2 * q + 1], 0.f);
        }
        o[q] = packbf(a, b);
    }
    unsigned int* po = (unsigned int*)(outp + (size_t)w * C + lbase);
    if constexpr (NW == 4)      { *(uint4*)po = make_uint4(o[0], o[1], o[2], o[3]); }
    else if constexpr (NW == 2) { *(uint2*)po = make_uint2(o[0], o[1]); }
    else                        { *po = o[0]; }
}

template <int C>
__global__ __launch_bounds__(256) void seg_edge_t(const unsigned short* __restrict__ xl,
                                                  const int* __restrict__ eoff,
                                                  const int* __restrict__ edeg_p,
                                                  const unsigned short* __restrict__ csr_src,
                                                  unsigned short* __restrict__ ef) {
    seg_body<C, false>(xl, eoff, edeg_p, csr_src, nullptr, ef, N_EDGES);
}

template <int C, bool BIAS>
__global__ __launch_bounds__(256) void seg_node_t(const unsigned short* __restrict__ ef,
                                                  const int* __restrict__ noff,
                                                  const int* __restrict__ ndeg_p,
                                                  const unsigned short* __restrict__ csr_src,
                                                  const float* __restrict__ bias,
                                                  unsigned short* __restrict__ hout) {
    seg_body<C, BIAS>(ef, noff, ndeg_p, csr_src, bias, hout, N_NODES);
}

// ---------------- fused mean pool + MLP head (one block per graph) ----------------
__global__ __launch_bounds__(256) void pool_head_kernel(const unsigned short* __restrict__ h,
                                                        const int* __restrict__ goff,
                                                        const float* __restrict__ Wl1,
                                                        const float* __restrict__ bl1,
                                                        const float* __restrict__ Wl2,
                                                        const float* __restrict__ bl2,
                                                        float* __restrict__ out) {
    __shared__ float xs[256];
    __shared__ float red[128];
    int g = blockIdx.x, t = threadIdx.x;
    int s = goff[g], cnt = goff[g + 1] - s;
    float acc = 0.f;
    for (int i = 0; i < cnt; ++i) {
        unsigned int u = h[(size_t)(s + i) * 256 + t];
        acc += __builtin_bit_cast(float, u << 16);
    }
    xs[t] = acc / (float)(cnt > 0 ? cnt : 1);
    __syncthreads();
    if (t < 128) {
        float s2 = 0.f;
        for (int f = 0; f < 256; ++f) s2 += xs[f] * Wl1[f * 128 + t];
        s2 = fmaxf(s2 + bl1[t], 0.f);
        red[t] = s2 * Wl2[t];
    }
    __syncthreads();
    for (int off = 64; off > 0; off >>= 1) {
        if (t < off) red[t] += red[t + off];
        __syncthreads();
    }
    if (t == 0) out[g] = red[0] + bl2[0];
}

extern "C" void kernel_launch(void* const* d_in, const int* in_sizes, int n_in,
                              void* d_out, int out_size, void* d_ws, size_t ws_size,
                              hipStream_t stream) {
    const float* x     = (const float*)d_in[0];
    const int* hei     = (const int*)d_in[1];
    const int* braw    = (const int*)d_in[2];
    const float* W1    = (const float*)d_in[3];
    const float* b1    = (const float*)d_in[4];
    const float* W2    = (const float*)d_in[5];
    const float* b2    = (const float*)d_in[6];
    const float* W3    = (const float*)d_in[7];
    const float* b3    = (const float*)d_in[8];
    const float* Wl1   = (const float*)d_in[9];
    const float* bl1   = (const float*)d_in[10];
    const float* Wl2   = (const float*)d_in[11];
    const float* bl2   = (const float*)d_in[12];
    float* out         = (float*)d_out;

    char* w = (char*)d_ws;
    size_t off = 0;
    auto alloc = [&](size_t bytes) { size_t p = off; off += (bytes + 255) & ~(size_t)255; return p; };
    // zeroed region: padded degree counters (1 int per 64B line)
    size_t o_edegp = alloc((size_t)SEG_CAP * 16 * 4);
    size_t o_ndegp = alloc((size_t)SEG_CAP * 16 * 4);
    size_t zero_end = off;
    size_t o_eoff = alloc((size_t)SEG_CAP * 4);
    size_t o_noff = alloc((size_t)SEG_CAP * 4);
    size_t o_goff = alloc((size_t)1025 * 4);
    size_t o_part = alloc(128 * 4);
    size_t o_nidx = alloc((size_t)N_INC * 4);
    size_t o_eidx = alloc((size_t)N_INC * 4);
    size_t o_rn   = alloc((size_t)N_INC * 2);
    size_t o_re   = alloc((size_t)N_INC * 2);
    size_t o_csre = alloc((size_t)N_INC * 2);
    size_t o_csrn = alloc((size_t)N_INC * 2);
    size_t o_wt1  = alloc((size_t)128 * 256 * 2);
    size_t o_wt2  = alloc((size_t)256 * 512 * 2);
    size_t o_wt3  = alloc((size_t)512 * 256 * 2);
    size_t o_xbf  = alloc((size_t)M_PAD * 128 * 2);
    size_t o_Y    = alloc((size_t)M_PAD * 256 * 2);
    size_t o_H1   = alloc((size_t)M_PAD * 256 * 2);
    size_t o_H2   = alloc((size_t)M_PAD * 512 * 2);
    size_t o_bufE = alloc((size_t)N_EDGES * 256 * 2);

    int* edeg_p = (int*)(w + o_edegp);
    int* ndeg_p = (int*)(w + o_ndegp);
    int* eoff = (int*)(w + o_eoff);
    int* noff = (int*)(w + o_noff);
    int* goff = (int*)(w + o_goff);
    int* part = (int*)(w + o_part);
    int* nidx = (int*)(w + o_nidx);
    int* eidx = (int*)(w + o_eidx);
    unsigned short* rn   = (unsigned short*)(w + o_rn);
    unsigned short* re   = (unsigned short*)(w + o_re);
    unsigned short* csre = (unsigned short*)(w + o_csre);
    unsigned short* csrn = (unsigned short*)(w + o_csrn);
    unsigned short* wt1  = (unsigned short*)(w + o_wt1);
    unsigned short* wt2  = (unsigned short*)(w + o_wt2);
    unsigned short* wt3  = (unsigned short*)(w + o_wt3);
    unsigned short* xbf  = (unsigned short*)(w + o_xbf);
    unsigned short* Y    = (unsigned short*)(w + o_Y);
    unsigned short* H1   = (unsigned short*)(w + o_H1);
    unsigned short* H2   = (unsigned short*)(w + o_H2);
    unsigned short* bufE = (unsigned short*)(w + o_bufE);

    hipMemsetAsync(w, 0, zero_end, stream);
    normhist_kernel<<<NB_INC + NB_CONV + NB_W1 + NB_W2 + NB_W3, 256, 0, stream>>>(
        hei, nidx, eidx, rn, re, ndeg_p, edeg_p, x, xbf, W1, wt1, W2, wt2, W3, wt3);
    scan_up_f<<<102, 256, 0, stream>>>(edeg_p, ndeg_p, hei, braw, eoff, noff, goff, part);
    scan_mid_f<<<1, 128, 0, stream>>>(part);
    scan_down_f<<<98, 256, 0, stream>>>(eoff, noff, part);
    prep_kernel<<<(N_INC + 255) / 256, 256, 0, stream>>>(nidx, eidx, rn, re, eoff, noff, csre, csrn);

    int segGrid = (N_NODES * 64 + 255) / 256;

    // ---- layer 1 (aggregate-first at 128)
    seg_edge_t<128><<<segGrid, 256, 0, stream>>>(xbf, eoff, edeg_p, csre, bufE);
    seg_node_t<128, false><<<segGrid, 256, 0, stream>>>(bufE, noff, ndeg_p, csrn, nullptr, Y);
    {
        dim3 grid(256 / 128, M_PAD / 128);
        gemm128_kernel<true><<<grid, 256, 0, stream>>>(Y, wt1, b1, H1, N_NODES, 128, 256);
    }
    // ---- layer 2 (aggregate-first at 256)
    seg_edge_t<256><<<segGrid, 256, 0, stream>>>(H1, eoff, edeg_p, csre, bufE);
    seg_node_t<256, false><<<segGrid, 256, 0, stream>>>(bufE, noff, ndeg_p, csrn, nullptr, Y);
    {
        dim3 grid(512 / 128, M_PAD / 128);
        gemm128_kernel<true><<<grid, 256, 0, stream>>>(Y, wt2, b2, H2, N_NODES, 256, 512);
    }
    // ---- layer 3 (gemm-first at 256)
    {
        dim3 grid(256 / 128, M_PAD / 128);
        gemm128_kernel<false><<<grid, 256, 0, stream>>>(H2, wt3, nullptr, Y, N_NODES, 512, 256);
    }
    seg_edge_t<256><<<segGrid, 256, 0, stream>>>(Y, eoff, edeg_p, csre, bufE);
    seg_node_t<256, true><<<segGrid, 256, 0, stream>>>(bufE, noff, ndeg_p, csrn, b3, H1);

    pool_head_kernel<<<N_GRAPHS, 256, 0, stream>>>(H1, goff, Wl1, bl1, Wl2, bl2, out);
}

// Round 11
// 413.625 us; speedup vs baseline: 2.6639x; 1.0377x over previous
//
#include <hip/hip_runtime.h>
#include <hip/hip_bf16.h>

#define N_NODES  50000
#define N_EDGES  50000
#define N_INC    400000
#define N_GRAPHS 1024
#define M_PAD    50048          // 391 * 128
#define SEG_CAP  50176          // 49 * 1024 (scan padding)

typedef __bf16 bf16x8 __attribute__((ext_vector_type(8)));
typedef float  f32x4  __attribute__((ext_vector_type(4)));

__device__ __forceinline__ unsigned short f2bf(float f) {
    __hip_bfloat16 h = __float2bfloat16(f);
    return __builtin_bit_cast(unsigned short, h);
}
__device__ __forceinline__ float bflo(unsigned int u) {
    return __builtin_bit_cast(float, u << 16);
}
__device__ __forceinline__ float bfhi(unsigned int u) {
    return __builtin_bit_cast(float, u & 0xffff0000u);
}
__device__ __forceinline__ unsigned int packbf(float a, float b) {
    return (unsigned int)f2bf(a) | ((unsigned int)f2bf(b) << 16);
}
__device__ __forceinline__ void load_lds16(const unsigned short* g, unsigned short* l) {
    __builtin_amdgcn_global_load_lds((const __attribute__((address_space(1))) void*)g,
                                     (__attribute__((address_space(3))) void*)l, 16, 0, 0);
}

// ---- mega normhist: incidence hist (padded counters) + x->bf16 + weight transposes
#define NB_INC  1563
#define NB_CONV 6250
#define NB_W1   128
#define NB_W2   512
#define NB_W3   512
__global__ __launch_bounds__(256) void normhist_kernel(const int* __restrict__ hei,
                                                       int* __restrict__ nidx, int* __restrict__ eidx,
                                                       unsigned short* __restrict__ rn,
                                                       unsigned short* __restrict__ re,
                                                       int* __restrict__ ndeg_p, int* __restrict__ edeg_p,
                                                       const float* __restrict__ x,
                                                       unsigned short* __restrict__ xbf,
                                                       const float* __restrict__ W1, unsigned short* __restrict__ wt1,
                                                       const float* __restrict__ W2, unsigned short* __restrict__ wt2,
                                                       const float* __restrict__ W3, unsigned short* __restrict__ wt3) {
    int b = blockIdx.x, t = threadIdx.x;
    if (b < NB_INC) {
        __shared__ int s32;
        if (t == 0) s32 = 0;
        __syncthreads();
        int probe = hei[4 * t + 1] | hei[4 * t + 3];   // int64 layout => odd words zero
        if (probe) s32 = 1;
        __syncthreads();
        int is32 = s32;
        int i = b * 256 + t;
        if (i < N_INC) {
            int n, e;
            if (is32) { n = hei[i];     e = hei[N_INC + i]; }
            else      { n = hei[2 * i]; e = hei[2 * N_INC + 2 * i]; }
            nidx[i] = n; eidx[i] = e;
            rn[i] = (unsigned short)atomicAdd(&ndeg_p[n << 4], 1);
            re[i] = (unsigned short)atomicAdd(&edeg_p[e << 4], 1);
        }
    } else if (b < NB_INC + NB_CONV) {
        int i = (b - NB_INC) * 256 + t;
        float4 v = *(const float4*)(x + 4 * (size_t)i);
        ushort4 o;
        o.x = f2bf(v.x); o.y = f2bf(v.y); o.z = f2bf(v.z); o.w = f2bf(v.w);
        *(ushort4*)(xbf + 4 * (size_t)i) = o;
    } else if (b < NB_INC + NB_CONV + NB_W1) {
        int i = (b - NB_INC - NB_CONV) * 256 + t;
        int k = i >> 8, n = i & 255;
        wt1[n * 128 + k] = f2bf(W1[i]);
    } else if (b < NB_INC + NB_CONV + NB_W1 + NB_W2) {
        int i = (b - NB_INC - NB_CONV - NB_W1) * 256 + t;
        int k = i >> 9, n = i & 511;
        wt2[n * 256 + k] = f2bf(W2[i]);
    } else {
        int i = (b - NB_INC - NB_CONV - NB_W1 - NB_W2) * 256 + t;
        int k = i >> 8, n = i & 255;
        wt3[n * 512 + k] = f2bf(W3[i]);
    }
}

// ---- scan_up over padded degree arrays + goff via binary search on sorted batch
__global__ __launch_bounds__(256) void scan_up_f(const int* __restrict__ edeg_p,
                                                 const int* __restrict__ ndeg_p,
                                                 const int* __restrict__ hei,
                                                 const int* __restrict__ braw,
                                                 int* __restrict__ eoff, int* __restrict__ noff,
                                                 int* __restrict__ goff,
                                                 int* __restrict__ partials) {
    int b = blockIdx.x, t = threadIdx.x;
    if (b >= 98) {
        __shared__ int s32;
        if (t == 0) s32 = 0;
        __syncthreads();
        int probe = hei[4 * t + 1] | hei[4 * t + 3];
        if (probe) s32 = 1;
        __syncthreads();
        int is32 = s32;
        int g = (b - 98) * 256 + t;
        int lo = 0, hi = N_NODES;
        while (lo < hi) {
            int mid = (lo + hi) >> 1;
            int v = is32 ? braw[mid] : braw[2 * mid];
            if (v < g) lo = mid + 1; else hi = mid;
        }
        goff[g] = lo;
        if (g == 1023) goff[1024] = N_NODES;
        return;
    }
    __shared__ int lds[256];
    const int* in; int* outp; int lb;
    if (b < 49) { in = edeg_p; outp = eoff; lb = b; }
    else        { in = ndeg_p; outp = noff; lb = b - 49; }
    int base = lb * 1024 + t * 4;
    int4 v;
    v.x = in[(size_t)(base + 0) << 4];
    v.y = in[(size_t)(base + 1) << 4];
    v.z = in[(size_t)(base + 2) << 4];
    v.w = in[(size_t)(base + 3) << 4];
    int s = v.x + v.y + v.z + v.w;
    lds[t] = s;
    __syncthreads();
    for (int off = 1; off < 256; off <<= 1) {
        int u = (t >= off) ? lds[t - off] : 0;
        __syncthreads();
        lds[t] += u;
        __syncthreads();
    }
    int excl = lds[t] - s;
    if (t == 255) partials[b] = lds[255];
    int4 o;
    o.x = excl;
    o.y = excl + v.x;
    o.z = o.y + v.y;
    o.w = o.z + v.z;
    *(int4*)(outp + base) = o;
}

// ---- scan_down with inlined mid: every block scans the 98 raw partials in LDS ----
__global__ __launch_bounds__(256) void scan_down_f(int* __restrict__ eoff,
                                                   int* __restrict__ noff,
                                                   const int* __restrict__ partials) {
    __shared__ int lds[98];
    int b = blockIdx.x, t = threadIdx.x;
    if (t < 98) lds[t] = partials[t];
    __syncthreads();
    if (t < 2) {
        int lo = t * 49, hi = lo + 49;
        int run = 0;
        for (int i = lo; i < hi; ++i) { int x = lds[i]; lds[i] = run; run += x; }
    }
    __syncthreads();
    int* outp; int lb;
    if (b < 49) { outp = eoff; lb = b; }
    else        { outp = noff; lb = b - 49; }
    int base = lb * 1024 + t * 4;
    int p = lds[b];
    int4 v = *(const int4*)(outp + base);
    v.x += p; v.y += p; v.z += p; v.w += p;
    *(int4*)(outp + base) = v;
}

// ---------------- prep: atomic-free CSR scatter only ----------------
__global__ __launch_bounds__(256) void prep_kernel(const int* __restrict__ nidx,
                                                   const int* __restrict__ eidx,
                                                   const unsigned short* __restrict__ rn,
                                                   const unsigned short* __restrict__ re,
                                                   const int* __restrict__ eoff,
                                                   const int* __restrict__ noff,
                                                   unsigned short* __restrict__ csre,
                                                   unsigned short* __restrict__ csrn) {
    int i = blockIdx.x * 256 + threadIdx.x;
    if (i >= N_INC) return;
    int n = nidx[i], e = eidx[i];
    csre[eoff[e] + re[i]] = (unsigned short)n;
    csrn[noff[n] + rn[i]] = (unsigned short)e;
}

// ---------------- 128x128 MFMA GEMM (m97 pattern) + LDS-staged epilogue ----------
template <bool EPI>
__global__ __launch_bounds__(256) void gemm128_kernel(const unsigned short* __restrict__ A,
                                                      const unsigned short* __restrict__ Bt,
                                                      const float* __restrict__ bias,
                                                      unsigned short* __restrict__ C,
                                                      int M, int K, int N) {
    __shared__ unsigned short As[128 * 32];
    __shared__ unsigned short Bs[128 * 32];
    __shared__ unsigned short Cs[32][140];
    int tid  = threadIdx.x;
    int wave = tid >> 6, lane = tid & 63;
    int n0 = blockIdx.x * 128, m0 = blockIdx.y * 128;
    int quad = lane >> 4, fr = lane & 15;
    int wr = wave >> 1, wc = wave & 1;
    int lrow16 = lane >> 2;
    int lchunk = (lane & 3) * 8;

    const unsigned short* gsrc;
    unsigned short* ldst;
    if (wave < 2) { gsrc = A  + (size_t)(m0 + wave * 64) * K;       ldst = As + wave * 64 * 32; }
    else          { gsrc = Bt + (size_t)(n0 + (wave - 2) * 64) * K; ldst = Bs + (wave - 2) * 64 * 32; }

    f32x4 acc[4][4];
#pragma unroll
    for (int s = 0; s < 4; ++s)
#pragma unroll
        for (int c = 0; c < 4; ++c) acc[s][c] = (f32x4){0.f, 0.f, 0.f, 0.f};

    for (int k0 = 0; k0 < K; k0 += 32) {
#pragma unroll
        for (int l = 0; l < 4; ++l) {
            const unsigned short* g = gsrc + (size_t)(l * 16 + lrow16) * K + k0 + lchunk;
            load_lds16(g, ldst + l * 16 * 32);
        }
        __syncthreads();
        bf16x8 af[4], bfr[4];
#pragma unroll
        for (int s = 0; s < 4; ++s)
            af[s] = *(const bf16x8*)&As[(wr * 64 + s * 16 + fr) * 32 + quad * 8];
#pragma unroll
        for (int c = 0; c < 4; ++c)
            bfr[c] = *(const bf16x8*)&Bs[(wc * 64 + c * 16 + fr) * 32 + quad * 8];
#pragma unroll
        for (int s = 0; s < 4; ++s)
#pragma unroll
            for (int c = 0; c < 4; ++c)
                acc[s][c] = __builtin_amdgcn_mfma_f32_16x16x32_bf16(af[s], bfr[c], acc[s][c], 0, 0, 0);
        __syncthreads();
    }

    float bv[4];
#pragma unroll
    for (int c = 0; c < 4; ++c) bv[c] = EPI ? bias[n0 + wc * 64 + c * 16 + fr] : 0.f;
#pragma unroll
    for (int s = 0; s < 4; ++s) {
#pragma unroll
        for (int c = 0; c < 4; ++c)
#pragma unroll
            for (int r = 0; r < 4; ++r) {
                float v = acc[s][c][r];
                if (EPI) v = fmaxf(v + bv[c], 0.f);
                Cs[wr * 16 + quad * 4 + r][wc * 64 + c * 16 + fr] = f2bf(v);
            }
        __syncthreads();
#pragma unroll
        for (int i = 0; i < 2; ++i) {
            int rl  = i * 16 + (tid >> 4);
            int col = (tid & 15) * 8;
            int gm  = m0 + (rl >> 4) * 64 + s * 16 + (rl & 15);
            if (gm < M) {
                uint4 v = *(const uint4*)&Cs[rl][col];
                *(uint4*)&C[(size_t)gm * N + n0 + col] = v;
            }
        }
        __syncthreads();
    }
}

// ---- segment-mean gather: TWO segments per wave (32 lanes each), 8x batch -------
// Divergent degrees handled by max-deg loop + clamped index + value mask.
template <int C, bool BIAS>
__device__ __forceinline__ void seg_body2(const unsigned short* __restrict__ in,
                                          const int* __restrict__ offs,
                                          const int* __restrict__ degs_p,
                                          const unsigned short* __restrict__ csr_src,
                                          const float* __restrict__ bias,
                                          unsigned short* __restrict__ outp,
                                          int nseg) {
    constexpr int VEC = C / 32;      // bf16 per lane: 8 (C=256) or 4 (C=128)
    constexpr int NW  = VEC / 2;     // 32-bit words: 4 or 2
    int wid  = (blockIdx.x * 256 + threadIdx.x) >> 6;
    int lane = threadIdx.x & 63;
    int half = lane >> 5, l2 = lane & 31;
    int seg = 2 * wid + half;
    if (2 * wid >= nseg) return;
    bool segvalid = seg < nseg;
    int deg   = segvalid ? degs_p[(size_t)seg << 4] : 0;
    int start = segvalid ? offs[seg] : 0;
    float dinv = (deg > 0) ? 1.0f / (float)deg : 0.0f;
    int maxdeg = max(deg, __shfl_xor(deg, 32, 64));
    const unsigned short* cs = csr_src + start;
    float acc[VEC];
#pragma unroll
    for (int q = 0; q < VEC; ++q) acc[q] = 0.f;
    size_t lbase = (size_t)l2 * VEC;

    auto loadrow = [&](int src, unsigned int* v) {
        src = min(src, nseg - 1);                    // clamp garbage (masked later)
        const unsigned int* p = (const unsigned int*)(in + (size_t)src * C + lbase);
        if constexpr (NW == 4) { uint4 t = *(const uint4*)p; v[0] = t.x; v[1] = t.y; v[2] = t.z; v[3] = t.w; }
        else                   { uint2 t = *(const uint2*)p; v[0] = t.x; v[1] = t.y; }
    };
    auto maccum = [&](unsigned int* v, unsigned int msk) {
#pragma unroll
        for (int q = 0; q < NW; ++q) {
            unsigned int x = v[q] & msk;
            acc[2 * q] += bflo(x); acc[2 * q + 1] += bfhi(x);
        }
    };

    int dc = (deg > 0) ? deg - 1 : 0;
    for (int j = 0; j < maxdeg; j += 8) {
        unsigned int v[8][NW];
        int row[8];
#pragma unroll
        for (int u = 0; u < 8; ++u) {
            int jj = min(j + u, dc);
            row[u] = (int)cs[jj];
        }
#pragma unroll
        for (int u = 0; u < 8; ++u) loadrow(row[u], v[u]);
        __asm__ __volatile__("" ::: "memory");       // keep batch in flight
#pragma unroll
        for (int u = 0; u < 8; ++u) {
            unsigned int msk = (j + u < deg) ? 0xffffffffu : 0u;
            maccum(v[u], msk);
        }
    }

    if (!segvalid) return;
    unsigned int o[NW];
#pragma unroll
    for (int q = 0; q < NW; ++q) {
        float a = acc[2 * q] * dinv;
        float b = acc[2 * q + 1] * dinv;
        if constexpr (BIAS) {
            a = fmaxf(a + bias[lbase + 2 * q], 0.f);
            b = fmaxf(b + bias[lbase + 2 * q + 1], 0.f);
        }
        o[q] = packbf(a, b);
    }
    unsigned int* po = (unsigned int*)(outp + (size_t)seg * C + lbase);
    if constexpr (NW == 4) { *(uint4*)po = make_uint4(o[0], o[1], o[2], o[3]); }
    else                   { *(uint2*)po = make_uint2(o[0], o[1]); }
}

template <int C>
__global__ __launch_bounds__(256) void seg_edge_t(const unsigned short* __restrict__ xl,
                                                  const int* __restrict__ eoff,
                                                  const int* __restrict__ edeg_p,
                                                  const unsigned short* __restrict__ csr_src,
                                                  unsigned short* __restrict__ ef) {
    seg_body2<C, false>(xl, eoff, edeg_p, csr_src, nullptr, ef, N_EDGES);
}

template <int C, bool BIAS>
__global__ __launch_bounds__(256) void seg_node_t(const unsigned short* __restrict__ ef,
                                                  const int* __restrict__ noff,
                                                  const int* __restrict__ ndeg_p,
                                                  const unsigned short* __restrict__ csr_src,
                                                  const float* __restrict__ bias,
                                                  unsigned short* __restrict__ hout) {
    seg_body2<C, BIAS>(ef, noff, ndeg_p, csr_src, bias, hout, N_NODES);
}

// ---------------- fused mean pool + MLP head (one block per graph) ----------------
__global__ __launch_bounds__(256) void pool_head_kernel(const unsigned short* __restrict__ h,
                                                        const int* __restrict__ goff,
                                                        const float* __restrict__ Wl1,
                                                        const float* __restrict__ bl1,
                                                        const float* __restrict__ Wl2,
                                                        const float* __restrict__ bl2,
                                                        float* __restrict__ out) {
    __shared__ float xs[256];
    __shared__ float red[128];
    int g = blockIdx.x, t = threadIdx.x;
    int s = goff[g], cnt = goff[g + 1] - s;
    float acc = 0.f;
    for (int i = 0; i < cnt; ++i) {
        unsigned int u = h[(size_t)(s + i) * 256 + t];
        acc += __builtin_bit_cast(float, u << 16);
    }
    xs[t] = acc / (float)(cnt > 0 ? cnt : 1);
    __syncthreads();
    if (t < 128) {
        float s2 = 0.f;
        for (int f = 0; f < 256; ++f) s2 += xs[f] * Wl1[f * 128 + t];
        s2 = fmaxf(s2 + bl1[t], 0.f);
        red[t] = s2 * Wl2[t];
    }
    __syncthreads();
    for (int off = 64; off > 0; off >>= 1) {
        if (t < off) red[t] += red[t + off];
        __syncthreads();
    }
    if (t == 0) out[g] = red[0] + bl2[0];
}

extern "C" void kernel_launch(void* const* d_in, const int* in_sizes, int n_in,
                              void* d_out, int out_size, void* d_ws, size_t ws_size,
                              hipStream_t stream) {
    const float* x     = (const float*)d_in[0];
    const int* hei     = (const int*)d_in[1];
    const int* braw    = (const int*)d_in[2];
    const float* W1    = (const float*)d_in[3];
    const float* b1    = (const float*)d_in[4];
    const float* W2    = (const float*)d_in[5];
    const float* b2    = (const float*)d_in[6];
    const float* W3    = (const float*)d_in[7];
    const float* b3    = (const float*)d_in[8];
    const float* Wl1   = (const float*)d_in[9];
    const float* bl1   = (const float*)d_in[10];
    const float* Wl2   = (const float*)d_in[11];
    const float* bl2   = (const float*)d_in[12];
    float* out         = (float*)d_out;

    char* w = (char*)d_ws;
    size_t off = 0;
    auto alloc = [&](size_t bytes) { size_t p = off; off += (bytes + 255) & ~(size_t)255; return p; };
    size_t o_edegp = alloc((size_t)SEG_CAP * 16 * 4);
    size_t o_ndegp = alloc((size_t)SEG_CAP * 16 * 4);
    size_t zero_end = off;
    size_t o_eoff = alloc((size_t)SEG_CAP * 4);
    size_t o_noff = alloc((size_t)SEG_CAP * 4);
    size_t o_goff = alloc((size_t)1025 * 4);
    size_t o_part = alloc(128 * 4);
    size_t o_nidx = alloc((size_t)N_INC * 4);
    size_t o_eidx = alloc((size_t)N_INC * 4);
    size_t o_rn   = alloc((size_t)N_INC * 2);
    size_t o_re   = alloc((size_t)N_INC * 2);
    size_t o_csre = alloc((size_t)N_INC * 2 + 64);   // +slack for clamped tail reads
    size_t o_csrn = alloc((size_t)N_INC * 2 + 64);
    size_t o_wt1  = alloc((size_t)128 * 256 * 2);
    size_t o_wt2  = alloc((size_t)256 * 512 * 2);
    size_t o_wt3  = alloc((size_t)512 * 256 * 2);
    size_t o_xbf  = alloc((size_t)M_PAD * 128 * 2);
    size_t o_Y    = alloc((size_t)M_PAD * 256 * 2);
    size_t o_H1   = alloc((size_t)M_PAD * 256 * 2);
    size_t o_H2   = alloc((size_t)M_PAD * 512 * 2);
    size_t o_bufE = alloc((size_t)N_EDGES * 256 * 2);

    int* edeg_p = (int*)(w + o_edegp);
    int* ndeg_p = (int*)(w + o_ndegp);
    int* eoff = (int*)(w + o_eoff);
    int* noff = (int*)(w + o_noff);
    int* goff = (int*)(w + o_goff);
    int* part = (int*)(w + o_part);
    int* nidx = (int*)(w + o_nidx);
    int* eidx = (int*)(w + o_eidx);
    unsigned short* rn   = (unsigned short*)(w + o_rn);
    unsigned short* re   = (unsigned short*)(w + o_re);
    unsigned short* csre = (unsigned short*)(w + o_csre);
    unsigned short* csrn = (unsigned short*)(w + o_csrn);
    unsigned short* wt1  = (unsigned short*)(w + o_wt1);
    unsigned short* wt2  = (unsigned short*)(w + o_wt2);
    unsigned short* wt3  = (unsigned short*)(w + o_wt3);
    unsigned short* xbf  = (unsigned short*)(w + o_xbf);
    unsigned short* Y    = (unsigned short*)(w + o_Y);
    unsigned short* H1   = (unsigned short*)(w + o_H1);
    unsigned short* H2   = (unsigned short*)(w + o_H2);
    unsigned short* bufE = (unsigned short*)(w + o_bufE);

    hipMemsetAsync(w, 0, zero_end, stream);
    normhist_kernel<<<NB_INC + NB_CONV + NB_W1 + NB_W2 + NB_W3, 256, 0, stream>>>(
        hei, nidx, eidx, rn, re, ndeg_p, edeg_p, x, xbf, W1, wt1, W2, wt2, W3, wt3);
    scan_up_f<<<102, 256, 0, stream>>>(edeg_p, ndeg_p, hei, braw, eoff, noff, goff, part);
    scan_down_f<<<98, 256, 0, stream>>>(eoff, noff, part);
    prep_kernel<<<(N_INC + 255) / 256, 256, 0, stream>>>(nidx, eidx, rn, re, eoff, noff, csre, csrn);

    int segGrid2 = ((N_NODES + 1) / 2 * 64 + 255) / 256;   // two segments per wave

    // ---- layer 1 (aggregate-first at 128)
    seg_edge_t<128><<<segGrid2, 256, 0, stream>>>(xbf, eoff, edeg_p, csre, bufE);
    seg_node_t<128, false><<<segGrid2, 256, 0, stream>>>(bufE, noff, ndeg_p, csrn, nullptr, Y);
    {
        dim3 grid(256 / 128, M_PAD / 128);
        gemm128_kernel<true><<<grid, 256, 0, stream>>>(Y, wt1, b1, H1, N_NODES, 128, 256);
    }
    // ---- layer 2 (aggregate-first at 256)
    seg_edge_t<256><<<segGrid2, 256, 0, stream>>>(H1, eoff, edeg_p, csre, bufE);
    seg_node_t<256, false><<<segGrid2, 256, 0, stream>>>(bufE, noff, ndeg_p, csrn, nullptr, Y);
    {
        dim3 grid(512 / 128, M_PAD / 128);
        gemm128_kernel<true><<<grid, 256, 0, stream>>>(Y, wt2, b2, H2, N_NODES, 256, 512);
    }
    // ---- layer 3 (gemm-first at 256)
    {
        dim3 grid(256 / 128, M_PAD / 128);
        gemm128_kernel<false><<<grid, 256, 0, stream>>>(H2, wt3, nullptr, Y, N_NODES, 512, 256);
    }
    seg_edge_t<256><<<segGrid2, 256, 0, stream>>>(Y, eoff, edeg_p, csre, bufE);
    seg_node_t<256, true><<<segGrid2, 256, 0, stream>>>(bufE, noff, ndeg_p, csrn, b3, H1);

    pool_head_kernel<<<N_GRAPHS, 256, 0, stream>>>(H1, goff, Wl1, bl1, Wl2, bl2, out);
}

// Round 12
// 411.418 us; speedup vs baseline: 2.6782x; 1.0054x over previous
//
#include <hip/hip_runtime.h>
#include <hip/hip_bf16.h>

#define N_NODES  50000
#define N_EDGES  50000
#define N_INC    400000
#define N_GRAPHS 1024
#define M_PAD    50048          // 391 * 128
#define SEG_CAP  50176          // 49 * 1024 (scan padding)

typedef __bf16 bf16x8 __attribute__((ext_vector_type(8)));
typedef float  f32x4  __attribute__((ext_vector_type(4)));

__device__ __forceinline__ unsigned short f2bf(float f) {
    __hip_bfloat16 h = __float2bfloat16(f);
    return __builtin_bit_cast(unsigned short, h);
}
__device__ __forceinline__ float bflo(unsigned int u) {
    return __builtin_bit_cast(float, u << 16);
}
__device__ __forceinline__ float bfhi(unsigned int u) {
    return __builtin_bit_cast(float, u & 0xffff0000u);
}
__device__ __forceinline__ unsigned int packbf(float a, float b) {
    return (unsigned int)f2bf(a) | ((unsigned int)f2bf(b) << 16);
}
__device__ __forceinline__ void load_lds16(const unsigned short* g, unsigned short* l) {
    __builtin_amdgcn_global_load_lds((const __attribute__((address_space(1))) void*)g,
                                     (__attribute__((address_space(3))) void*)l, 16, 0, 0);
}

// ---- normhist: incidence histogram only (padded counters, atomic returns = rank) --
#define NB_INC  1563
__global__ __launch_bounds__(256) void normhist_kernel(const int* __restrict__ hei,
                                                       int* __restrict__ nidx, int* __restrict__ eidx,
                                                       unsigned short* __restrict__ rn,
                                                       unsigned short* __restrict__ re,
                                                       int* __restrict__ ndeg_p, int* __restrict__ edeg_p) {
    __shared__ int s32;
    int t = threadIdx.x;
    if (t == 0) s32 = 0;
    __syncthreads();
    int probe = hei[4 * t + 1] | hei[4 * t + 3];   // int64 layout => odd words zero
    if (probe) s32 = 1;
    __syncthreads();
    int is32 = s32;
    int i = blockIdx.x * 256 + t;
    if (i < N_INC) {
        int n, e;
        if (is32) { n = hei[i];     e = hei[N_INC + i]; }
        else      { n = hei[2 * i]; e = hei[2 * N_INC + 2 * i]; }
        nidx[i] = n; eidx[i] = e;
        rn[i] = (unsigned short)atomicAdd(&ndeg_p[n << 4], 1);
        re[i] = (unsigned short)atomicAdd(&edeg_p[e << 4], 1);
    }
}

// ---- scan_up over padded degree arrays + goff via binary search on sorted batch
__global__ __launch_bounds__(256) void scan_up_f(const int* __restrict__ edeg_p,
                                                 const int* __restrict__ ndeg_p,
                                                 const int* __restrict__ hei,
                                                 const int* __restrict__ braw,
                                                 int* __restrict__ eoff, int* __restrict__ noff,
                                                 int* __restrict__ goff,
                                                 int* __restrict__ partials) {
    int b = blockIdx.x, t = threadIdx.x;
    if (b >= 98) {
        __shared__ int s32;
        if (t == 0) s32 = 0;
        __syncthreads();
        int probe = hei[4 * t + 1] | hei[4 * t + 3];
        if (probe) s32 = 1;
        __syncthreads();
        int is32 = s32;
        int g = (b - 98) * 256 + t;
        int lo = 0, hi = N_NODES;
        while (lo < hi) {
            int mid = (lo + hi) >> 1;
            int v = is32 ? braw[mid] : braw[2 * mid];
            if (v < g) lo = mid + 1; else hi = mid;
        }
        goff[g] = lo;
        if (g == 1023) goff[1024] = N_NODES;
        return;
    }
    __shared__ int lds[256];
    const int* in; int* outp; int lb;
    if (b < 49) { in = edeg_p; outp = eoff; lb = b; }
    else        { in = ndeg_p; outp = noff; lb = b - 49; }
    int base = lb * 1024 + t * 4;
    int4 v;
    v.x = in[(size_t)(base + 0) << 4];
    v.y = in[(size_t)(base + 1) << 4];
    v.z = in[(size_t)(base + 2) << 4];
    v.w = in[(size_t)(base + 3) << 4];
    int s = v.x + v.y + v.z + v.w;
    lds[t] = s;
    __syncthreads();
    for (int off = 1; off < 256; off <<= 1) {
        int u = (t >= off) ? lds[t - off] : 0;
        __syncthreads();
        lds[t] += u;
        __syncthreads();
    }
    int excl = lds[t] - s;
    if (t == 255) partials[b] = lds[255];
    int4 o;
    o.x = excl;
    o.y = excl + v.x;
    o.z = o.y + v.y;
    o.w = o.z + v.z;
    *(int4*)(outp + base) = o;
}

// ---- scan_down with inlined mid: every block scans the 98 raw partials in LDS ----
__global__ __launch_bounds__(256) void scan_down_f(int* __restrict__ eoff,
                                                   int* __restrict__ noff,
                                                   const int* __restrict__ partials) {
    __shared__ int lds[98];
    int b = blockIdx.x, t = threadIdx.x;
    if (t < 98) lds[t] = partials[t];
    __syncthreads();
    if (t < 2) {
        int lo = t * 49, hi = lo + 49;
        int run = 0;
        for (int i = lo; i < hi; ++i) { int x = lds[i]; lds[i] = run; run += x; }
    }
    __syncthreads();
    int* outp; int lb;
    if (b < 49) { outp = eoff; lb = b; }
    else        { outp = noff; lb = b - 49; }
    int base = lb * 1024 + t * 4;
    int p = lds[b];
    int4 v = *(const int4*)(outp + base);
    v.x += p; v.y += p; v.z += p; v.w += p;
    *(int4*)(outp + base) = v;
}

// ---- prep: atomic-free CSR scatter + streamed x->bf16 + 3 weight transposes ------
#define NB_CSR  1563
#define NB_CONV 6250
#define NB_W1   128
#define NB_W2   512
#define NB_W3   512
__global__ __launch_bounds__(256) void prep_kernel(const int* __restrict__ nidx,
                                                   const int* __restrict__ eidx,
                                                   const unsigned short* __restrict__ rn,
                                                   const unsigned short* __restrict__ re,
                                                   const int* __restrict__ eoff,
                                                   const int* __restrict__ noff,
                                                   unsigned short* __restrict__ csre,
                                                   unsigned short* __restrict__ csrn,
                                                   const float* __restrict__ x,
                                                   unsigned short* __restrict__ xbf,
                                                   const float* __restrict__ W1, unsigned short* __restrict__ wt1,
                                                   const float* __restrict__ W2, unsigned short* __restrict__ wt2,
                                                   const float* __restrict__ W3, unsigned short* __restrict__ wt3) {
    int b = blockIdx.x, t = threadIdx.x;
    if (b < NB_CSR) {
        int i = b * 256 + t;
        if (i < N_INC) {
            int n = nidx[i], e = eidx[i];
            csre[eoff[e] + re[i]] = (unsigned short)n;
            csrn[noff[n] + rn[i]] = (unsigned short)e;
        }
    } else if (b < NB_CSR + NB_CONV) {
        int i = (b - NB_CSR) * 256 + t;
        float4 v = *(const float4*)(x + 4 * (size_t)i);
        ushort4 o;
        o.x = f2bf(v.x); o.y = f2bf(v.y); o.z = f2bf(v.z); o.w = f2bf(v.w);
        *(ushort4*)(xbf + 4 * (size_t)i) = o;
    } else if (b < NB_CSR + NB_CONV + NB_W1) {
        int i = (b - NB_CSR - NB_CONV) * 256 + t;
        int k = i >> 8, n = i & 255;
        wt1[n * 128 + k] = f2bf(W1[i]);
    } else if (b < NB_CSR + NB_CONV + NB_W1 + NB_W2) {
        int i = (b - NB_CSR - NB_CONV - NB_W1) * 256 + t;
        int k = i >> 9, n = i & 511;
        wt2[n * 256 + k] = f2bf(W2[i]);
    } else {
        int i = (b - NB_CSR - NB_CONV - NB_W1 - NB_W2) * 256 + t;
        int k = i >> 8, n = i & 255;
        wt3[n * 512 + k] = f2bf(W3[i]);
    }
}

// ---------------- 128x128 MFMA GEMM (m97 pattern, BK=32) + LDS-staged epilogue ----
// BK stays 32: 64B LDS row stride -> free 2-way bank aliasing on ds_read_b128;
// BK=64 would put all 16 fragment rows on the same banks (16-way conflict).
template <bool EPI>
__global__ __launch_bounds__(256) void gemm128_kernel(const unsigned short* __restrict__ A,
                                                      const unsigned short* __restrict__ Bt,
                                                      const float* __restrict__ bias,
                                                      unsigned short* __restrict__ C,
                                                      int M, int K, int N) {
    __shared__ unsigned short As[128 * 32];
    __shared__ unsigned short Bs[128 * 32];
    __shared__ unsigned short Cs[32][140];
    int tid  = threadIdx.x;
    int wave = tid >> 6, lane = tid & 63;
    int n0 = blockIdx.x * 128, m0 = blockIdx.y * 128;
    int quad = lane >> 4, fr = lane & 15;
    int wr = wave >> 1, wc = wave & 1;
    int lrow16 = lane >> 2;
    int lchunk = (lane & 3) * 8;

    const unsigned short* gsrc;
    unsigned short* ldst;
    if (wave < 2) { gsrc = A  + (size_t)(m0 + wave * 64) * K;       ldst = As + wave * 64 * 32; }
    else          { gsrc = Bt + (size_t)(n0 + (wave - 2) * 64) * K; ldst = Bs + (wave - 2) * 64 * 32; }

    f32x4 acc[4][4];
#pragma unroll
    for (int s = 0; s < 4; ++s)
#pragma unroll
        for (int c = 0; c < 4; ++c) acc[s][c] = (f32x4){0.f, 0.f, 0.f, 0.f};

    for (int k0 = 0; k0 < K; k0 += 32) {
#pragma unroll
        for (int l = 0; l < 4; ++l) {
            const unsigned short* g = gsrc + (size_t)(l * 16 + lrow16) * K + k0 + lchunk;
            load_lds16(g, ldst + l * 16 * 32);
        }
        __syncthreads();
        bf16x8 af[4], bfr[4];
#pragma unroll
        for (int s = 0; s < 4; ++s)
            af[s] = *(const bf16x8*)&As[(wr * 64 + s * 16 + fr) * 32 + quad * 8];
#pragma unroll
        for (int c = 0; c < 4; ++c)
            bfr[c] = *(const bf16x8*)&Bs[(wc * 64 + c * 16 + fr) * 32 + quad * 8];
#pragma unroll
        for (int s = 0; s < 4; ++s)
#pragma unroll
            for (int c = 0; c < 4; ++c)
                acc[s][c] = __builtin_amdgcn_mfma_f32_16x16x32_bf16(af[s], bfr[c], acc[s][c], 0, 0, 0);
        __syncthreads();
    }

    float bv[4];
#pragma unroll
    for (int c = 0; c < 4; ++c) bv[c] = EPI ? bias[n0 + wc * 64 + c * 16 + fr] : 0.f;
#pragma unroll
    for (int s = 0; s < 4; ++s) {
#pragma unroll
        for (int c = 0; c < 4; ++c)
#pragma unroll
            for (int r = 0; r < 4; ++r) {
                float v = acc[s][c][r];
                if (EPI) v = fmaxf(v + bv[c], 0.f);
                Cs[wr * 16 + quad * 4 + r][wc * 64 + c * 16 + fr] = f2bf(v);
            }
        __syncthreads();
#pragma unroll
        for (int i = 0; i < 2; ++i) {
            int rl  = i * 16 + (tid >> 4);
            int col = (tid & 15) * 8;
            int gm  = m0 + (rl >> 4) * 64 + s * 16 + (rl & 15);
            if (gm < M) {
                uint4 v = *(const uint4*)&Cs[rl][col];
                *(uint4*)&C[(size_t)gm * N + n0 + col] = v;
            }
        }
        __syncthreads();
    }
}

// ---- segment-mean gather: C/8 lanes per segment (SPW=64/(C/8) segs per wave) ----
// uint4 (16B) per lane covers the full row; divergent degrees via clamp+mask
// (clamped re-loads hit the same row -> L1/L2, negligible service cost).
template <int C, bool BIAS>
__device__ __forceinline__ void seg_bodyN(const unsigned short* __restrict__ in,
                                          const int* __restrict__ offs,
                                          const int* __restrict__ degs_p,
                                          const unsigned short* __restrict__ csr_src,
                                          const float* __restrict__ bias,
                                          unsigned short* __restrict__ outp,
                                          int nseg) {
    constexpr int LPG = C / 8;       // lanes per segment group (32 for C=256, 16 for C=128)
    constexpr int SPW = 64 / LPG;    // segments per wave
    int wid  = (blockIdx.x * 256 + threadIdx.x) >> 6;
    int lane = threadIdx.x & 63;
    int grp = lane / LPG, lg = lane % LPG;
    int seg = SPW * wid + grp;
    if (SPW * wid >= nseg) return;
    bool segvalid = seg < nseg;
    int deg   = segvalid ? degs_p[(size_t)seg << 4] : 0;
    int start = segvalid ? offs[seg] : 0;
    float dinv = (deg > 0) ? 1.0f / (float)deg : 0.0f;
    int maxdeg = deg;
#pragma unroll
    for (int m = LPG; m < 64; m <<= 1) maxdeg = max(maxdeg, __shfl_xor(maxdeg, m, 64));
    const unsigned short* cs = csr_src + start;
    float acc[8];
#pragma unroll
    for (int q = 0; q < 8; ++q) acc[q] = 0.f;
    size_t lbase = (size_t)lg * 8;

    auto loadrow = [&](int src, unsigned int* v) {
        src = min(src, nseg - 1);                    // clamp garbage (masked later)
        const unsigned int* p = (const unsigned int*)(in + (size_t)src * C + lbase);
        uint4 t = *(const uint4*)p; v[0] = t.x; v[1] = t.y; v[2] = t.z; v[3] = t.w;
    };
    auto maccum = [&](unsigned int* v, unsigned int msk) {
#pragma unroll
        for (int q = 0; q < 4; ++q) {
            unsigned int x = v[q] & msk;
            acc[2 * q] += bflo(x); acc[2 * q + 1] += bfhi(x);
        }
    };

    int dc = (deg > 0) ? deg - 1 : 0;
    for (int j = 0; j < maxdeg; j += 8) {
        unsigned int v[8][4];
        int row[8];
#pragma unroll
        for (int u = 0; u < 8; ++u) {
            int jj = min(j + u, dc);
            row[u] = (int)cs[jj];
        }
#pragma unroll
        for (int u = 0; u < 8; ++u) loadrow(row[u], v[u]);
        __asm__ __volatile__("" ::: "memory");       // keep batch in flight
#pragma unroll
        for (int u = 0; u < 8; ++u) {
            unsigned int msk = (j + u < deg) ? 0xffffffffu : 0u;
            maccum(v[u], msk);
        }
    }

    if (!segvalid) return;
    unsigned int o[4];
#pragma unroll
    for (int q = 0; q < 4; ++q) {
        float a = acc[2 * q] * dinv;
        float b = acc[2 * q + 1] * dinv;
        if constexpr (BIAS) {
            a = fmaxf(a + bias[lbase + 2 * q], 0.f);
            b = fmaxf(b + bias[lbase + 2 * q + 1], 0.f);
        }
        o[q] = packbf(a, b);
    }
    *(uint4*)(outp + (size_t)seg * C + lbase) = make_uint4(o[0], o[1], o[2], o[3]);
}

template <int C>
__global__ __launch_bounds__(256) void seg_edge_t(const unsigned short* __restrict__ xl,
                                                  const int* __restrict__ eoff,
                                                  const int* __restrict__ edeg_p,
                                                  const unsigned short* __restrict__ csr_src,
                                                  unsigned short* __restrict__ ef) {
    seg_bodyN<C, false>(xl, eoff, edeg_p, csr_src, nullptr, ef, N_EDGES);
}

template <int C, bool BIAS>
__global__ __launch_bounds__(256) void seg_node_t(const unsigned short* __restrict__ ef,
                                                  const int* __restrict__ noff,
                                                  const int* __restrict__ ndeg_p,
                                                  const unsigned short* __restrict__ csr_src,
                                                  const float* __restrict__ bias,
                                                  unsigned short* __restrict__ hout) {
    seg_bodyN<C, BIAS>(ef, noff, ndeg_p, csr_src, bias, hout, N_NODES);
}

// ---------------- fused mean pool + MLP head (one block per graph) ----------------
__global__ __launch_bounds__(256) void pool_head_kernel(const unsigned short* __restrict__ h,
                                                        const int* __restrict__ goff,
                                                        const float* __restrict__ Wl1,
                                                        const float* __restrict__ bl1,
                                                        const float* __restrict__ Wl2,
                                                        const float* __restrict__ bl2,
                                                        float* __restrict__ out) {
    __shared__ float xs[256];
    __shared__ float red[128];
    int g = blockIdx.x, t = threadIdx.x;
    int s = goff[g], cnt = goff[g + 1] - s;
    float acc = 0.f;
    for (int i = 0; i < cnt; ++i) {
        unsigned int u = h[(size_t)(s + i) * 256 + t];
        acc += __builtin_bit_cast(float, u << 16);
    }
    xs[t] = acc / (float)(cnt > 0 ? cnt : 1);
    __syncthreads();
    if (t < 128) {
        float s2 = 0.f;
        for (int f = 0; f < 256; ++f) s2 += xs[f] * Wl1[f * 128 + t];
        s2 = fmaxf(s2 + bl1[t], 0.f);
        red[t] = s2 * Wl2[t];
    }
    __syncthreads();
    for (int off = 64; off > 0; off >>= 1) {
        if (t < off) red[t] += red[t + off];
        __syncthreads();
    }
    if (t == 0) out[g] = red[0] + bl2[0];
}

extern "C" void kernel_launch(void* const* d_in, const int* in_sizes, int n_in,
                              void* d_out, int out_size, void* d_ws, size_t ws_size,
                              hipStream_t stream) {
    const float* x     = (const float*)d_in[0];
    const int* hei     = (const int*)d_in[1];
    const int* braw    = (const int*)d_in[2];
    const float* W1    = (const float*)d_in[3];
    const float* b1    = (const float*)d_in[4];
    const float* W2    = (const float*)d_in[5];
    const float* b2    = (const float*)d_in[6];
    const float* W3    = (const float*)d_in[7];
    const float* b3    = (const float*)d_in[8];
    const float* Wl1   = (const float*)d_in[9];
    const float* bl1   = (const float*)d_in[10];
    const float* Wl2   = (const float*)d_in[11];
    const float* bl2   = (const float*)d_in[12];
    float* out         = (float*)d_out;

    char* w = (char*)d_ws;
    size_t off = 0;
    auto alloc = [&](size_t bytes) { size_t p = off; off += (bytes + 255) & ~(size_t)255; return p; };
    size_t o_edegp = alloc((size_t)SEG_CAP * 16 * 4);
    size_t o_ndegp = alloc((size_t)SEG_CAP * 16 * 4);
    size_t zero_end = off;
    size_t o_eoff = alloc((size_t)SEG_CAP * 4);
    size_t o_noff = alloc((size_t)SEG_CAP * 4);
    size_t o_goff = alloc((size_t)1025 * 4);
    size_t o_part = alloc(128 * 4);
    size_t o_nidx = alloc((size_t)N_INC * 4);
    size_t o_eidx = alloc((size_t)N_INC * 4);
    size_t o_rn   = alloc((size_t)N_INC * 2);
    size_t o_re   = alloc((size_t)N_INC * 2);
    size_t o_csre = alloc((size_t)N_INC * 2 + 64);   // +slack for clamped tail reads
    size_t o_csrn = alloc((size_t)N_INC * 2 + 64);
    size_t o_wt1  = alloc((size_t)128 * 256 * 2);
    size_t o_wt2  = alloc((size_t)256 * 512 * 2);
    size_t o_wt3  = alloc((size_t)512 * 256 * 2);
    size_t o_xbf  = alloc((size_t)M_PAD * 128 * 2);
    size_t o_Y    = alloc((size_t)M_PAD * 256 * 2);
    size_t o_H1   = alloc((size_t)M_PAD * 256 * 2);
    size_t o_H2   = alloc((size_t)M_PAD * 512 * 2);
    size_t o_bufE = alloc((size_t)N_EDGES * 256 * 2);

    int* edeg_p = (int*)(w + o_edegp);
    int* ndeg_p = (int*)(w + o_ndegp);
    int* eoff = (int*)(w + o_eoff);
    int* noff = (int*)(w + o_noff);
    int* goff = (int*)(w + o_goff);
    int* part = (int*)(w + o_part);
    int* nidx = (int*)(w + o_nidx);
    int* eidx = (int*)(w + o_eidx);
    unsigned short* rn   = (unsigned short*)(w + o_rn);
    unsigned short* re   = (unsigned short*)(w + o_re);
    unsigned short* csre = (unsigned short*)(w + o_csre);
    unsigned short* csrn = (unsigned short*)(w + o_csrn);
    unsigned short* wt1  = (unsigned short*)(w + o_wt1);
    unsigned short* wt2  = (unsigned short*)(w + o_wt2);
    unsigned short* wt3  = (unsigned short*)(w + o_wt3);
    unsigned short* xbf  = (unsigned short*)(w + o_xbf);
    unsigned short* Y    = (unsigned short*)(w + o_Y);
    unsigned short* H1   = (unsigned short*)(w + o_H1);
    unsigned short* H2   = (unsigned short*)(w + o_H2);
    unsigned short* bufE = (unsigned short*)(w + o_bufE);

    hipMemsetAsync(w, 0, zero_end, stream);
    normhist_kernel<<<NB_INC, 256, 0, stream>>>(hei, nidx, eidx, rn, re, ndeg_p, edeg_p);
    scan_up_f<<<102, 256, 0, stream>>>(edeg_p, ndeg_p, hei, braw, eoff, noff, goff, part);
    scan_down_f<<<98, 256, 0, stream>>>(eoff, noff, part);
    prep_kernel<<<NB_CSR + NB_CONV + NB_W1 + NB_W2 + NB_W3, 256, 0, stream>>>(
        nidx, eidx, rn, re, eoff, noff, csre, csrn, x, xbf, W1, wt1, W2, wt2, W3, wt3);

    int segGrid2 = ((N_NODES + 1) / 2 * 64 + 255) / 256;   // SPW=2 (C=256)
    int segGrid4 = ((N_NODES + 3) / 4 * 64 + 255) / 256;   // SPW=4 (C=128)

    // ---- layer 1 (aggregate-first at 128)
    seg_edge_t<128><<<segGrid4, 256, 0, stream>>>(xbf, eoff, edeg_p, csre, bufE);
    seg_node_t<128, false><<<segGrid4, 256, 0, stream>>>(bufE, noff, ndeg_p, csrn, nullptr, Y);
    {
        dim3 grid(256 / 128, M_PAD / 128);
        gemm128_kernel<true><<<grid, 256, 0, stream>>>(Y, wt1, b1, H1, N_NODES, 128, 256);
    }
    // ---- layer 2 (aggregate-first at 256)
    seg_edge_t<256><<<segGrid2, 256, 0, stream>>>(H1, eoff, edeg_p, csre, bufE);
    seg_node_t<256, false><<<segGrid2, 256, 0, stream>>>(bufE, noff, ndeg_p, csrn, nullptr, Y);
    {
        dim3 grid(512 / 128, M_PAD / 128);
        gemm128_kernel<true><<<grid, 256, 0, stream>>>(Y, wt2, b2, H2, N_NODES, 256, 512);
    }
    // ---- layer 3 (gemm-first at 256)
    {
        dim3 grid(256 / 128, M_PAD / 128);
        gemm128_kernel<false><<<grid, 256, 0, stream>>>(H2, wt3, nullptr, Y, N_NODES, 512, 256);
    }
    seg_edge_t<256><<<segGrid2, 256, 0, stream>>>(Y, eoff, edeg_p, csre, bufE);
    seg_node_t<256, true><<<segGrid2, 256, 0, stream>>>(bufE, noff, ndeg_p, csrn, b3, H1);

    pool_head_kernel<<<N_GRAPHS, 256, 0, stream>>>(H1, goff, Wl1, bl1, Wl2, bl2, out);
}